// Round 1
// baseline (15724.051 us; speedup 1.0000x reference)
//
#include <hip/hip_runtime.h>
#include <math.h>

// ============================================================================
// PureTriXButterfly: fourier-encode -> encoder(24->1024)+LN+GELU ->
// 2 routers (1024->1024->8, argmax) -> top-1 expert dispatch (8 experts,
// 1024->2048) -> scalar heads via precomputed v = We2@w (folds 2nd GEMM).
//
// ROUND 1: all-fp32 correctness baseline. Routing argmax must match a fp32
// numpy reference (top-2 logit gaps ~0.1, threshold 2% of absmax), so the
// encoder+router chain is computed in fp32 with deterministic reduction
// order. Experts only need ~2% accuracy (future: fp16/bf16 MFMA).
// 4 passes of 16384 tokens to cap workspace at ~76 MB.
// ============================================================================

#define BT 65536     // total batch
#define QN 16384     // tokens per pass
#define NPASS 4
#define D 1024
#define NT 8         // experts / tiles
#define DH 2048

__device__ __forceinline__ float gelu_f(float v) {
    return 0.5f * v * (1.0f + erff(v * 0.70710678118654752440f));
}

// ---------------------------------------------------------------------------
// Precompute v_sum[t][j] = We2[t][j,:] . w_sum   (8*2048 rows), plus scalar
// c_sum[t] = be2[t].w_sum + bs (same for diff). One wave per row.
// ---------------------------------------------------------------------------
__global__ __launch_bounds__(256) void k_prev(
    const float* __restrict__ We2, const float* __restrict__ w_sum,
    const float* __restrict__ w_diff, const float* __restrict__ be2,
    const float* __restrict__ bs, const float* __restrict__ bd,
    float* __restrict__ v_sum, float* __restrict__ v_diff,
    float* __restrict__ c_sum, float* __restrict__ c_diff)
{
    int bid = blockIdx.x;
    if (bid < 4096) {
        int row  = bid * 4 + (threadIdx.x >> 6);   // 0..16383 = t*2048+j
        int lane = threadIdx.x & 63;
        const float* r = We2 + (size_t)row * D;
        float s1 = 0.f, s2 = 0.f;
        #pragma unroll
        for (int i = 0; i < 4; i++) {
            int o4 = (lane + 64 * i) * 4;
            float4 w = *(const float4*)(r + o4);
            float4 u = *(const float4*)(w_sum + o4);
            float4 v = *(const float4*)(w_diff + o4);
            s1 += w.x*u.x + w.y*u.y + w.z*u.z + w.w*u.w;
            s2 += w.x*v.x + w.y*v.y + w.z*v.z + w.w*v.w;
        }
        #pragma unroll
        for (int m = 32; m >= 1; m >>= 1) {
            s1 += __shfl_xor(s1, m, 64);
            s2 += __shfl_xor(s2, m, 64);
        }
        if (lane == 0) { v_sum[row] = s1; v_diff[row] = s2; }
    } else {
        int t = threadIdx.x;
        if (t < 8) {
            float s = 0.f; const float* r = be2 + t * D;
            for (int k = 0; k < D; k++) s += r[k] * w_sum[k];
            c_sum[t] = s + bs[0];
        } else if (t < 16) {
            int tt = t - 8;
            float s = 0.f; const float* r = be2 + tt * D;
            for (int k = 0; k < D; k++) s += r[k] * w_diff[k];
            c_diff[tt] = s + bd[0];
        }
    }
}

// ---------------------------------------------------------------------------
// Encoder: 64 tokens/block. W_in columns cached in registers (each thread
// owns 4 consecutive output cols). Fourier features -> GEMM(K=24) -> LN ->
// GELU -> x (fp32). Matches jax fp32 op order: ang = (x*fp32(2pi/16))*2^f.
// ---------------------------------------------------------------------------
__global__ __launch_bounds__(256) void k_enc(
    const float* __restrict__ a, const float* __restrict__ b,
    const float* __restrict__ W_in, const float* __restrict__ b_in,
    const float* __restrict__ ln_g, const float* __restrict__ ln_b,
    float* __restrict__ x, int tok0)
{
    __shared__ float x0[64][24];
    __shared__ float red[8];
    int tid = threadIdx.x;
    float4 Wc[24];
    #pragma unroll
    for (int f = 0; f < 24; f++) Wc[f] = *(const float4*)(W_in + f * D + tid * 4);
    float4 bi = *(const float4*)(b_in + tid * 4);
    float4 gg = *(const float4*)(ln_g + tid * 4);
    float4 bb = *(const float4*)(ln_b + tid * 4);
    int base = tok0 + blockIdx.x * 64;

    for (int idx = tid; idx < 64 * 12; idx += 256) {
        int t = idx / 12, q = idx - t * 12;
        int fr = q % 6;
        float in = (q < 6) ? a[base + t] : b[base + t];
        float ang = (in * 0.39269908169872414f) * (float)(1 << fr);
        int off = (q < 6) ? 0 : 12;
        x0[t][off + fr]     = sinf(ang);
        x0[t][off + 6 + fr] = cosf(ang);
    }
    __syncthreads();

    int lane = tid & 63, wid = tid >> 6;
    for (int t = 0; t < 64; t++) {
        float4 p = bi;
        #pragma unroll
        for (int f = 0; f < 24; f++) {
            float xv = x0[t][f];
            p.x += xv * Wc[f].x; p.y += xv * Wc[f].y;
            p.z += xv * Wc[f].z; p.w += xv * Wc[f].w;
        }
        float s1 = p.x + p.y + p.z + p.w;
        float s2 = p.x*p.x + p.y*p.y + p.z*p.z + p.w*p.w;
        #pragma unroll
        for (int m = 32; m >= 1; m >>= 1) {
            s1 += __shfl_xor(s1, m, 64);
            s2 += __shfl_xor(s2, m, 64);
        }
        if (lane == 0) { red[wid] = s1; red[4 + wid] = s2; }
        __syncthreads();
        float mean = (red[0] + red[1] + red[2] + red[3]) * (1.f / 1024.f);
        float ms   = (red[4] + red[5] + red[6] + red[7]) * (1.f / 1024.f);
        float inv  = 1.f / sqrtf(ms - mean * mean + 1e-5f);
        float4 o;
        o.x = gelu_f((p.x - mean) * inv * gg.x + bb.x);
        o.y = gelu_f((p.y - mean) * inv * gg.y + bb.y);
        o.z = gelu_f((p.z - mean) * inv * gg.z + bb.z);
        o.w = gelu_f((p.w - mean) * inv * gg.w + bb.w);
        *(float4*)(x + (size_t)(blockIdx.x * 64 + t) * D + tid * 4) = o;
        __syncthreads();
    }
}

// ---------------------------------------------------------------------------
// Router GEMM: h = gelu(x @ Wr1 + br1); fused epilogue computes partial
// logits h_tile @ Wr2 per 128-col N-tile -> deterministic partials buffer
// part[token][nt][8]. Tile: BM=64 x BN=128 x BK=64, fp32, A transposed in LDS.
// ---------------------------------------------------------------------------
__global__ __launch_bounds__(256) void k_rtr(
    const float* __restrict__ x, const float* __restrict__ Wr1,
    const float* __restrict__ br1, const float* __restrict__ Wr2,
    float* __restrict__ part)
{
    __shared__ float As[64][72];    // [k][row], stride 72 keeps 16B alignment
    __shared__ float Bs[64][132];   // [k][n]
    int tid = threadIdx.x;
    int bm = blockIdx.x, bn = blockIdx.y;
    int tr = tid >> 5, tc = tid & 31;
    float acc[8][4] = {};
    const float* xb = x + (size_t)bm * 64 * D;
    const float* wb = Wr1 + bn * 128;

    for (int k0 = 0; k0 < D; k0 += 64) {
        __syncthreads();
        {   // A: 64 rows x 64 k, transposed store
            int row = tid >> 2, q = tid & 3;
            const float* xr = xb + (size_t)row * D + k0;
            #pragma unroll
            for (int i = 0; i < 4; i++) {
                int f4i = q + 4 * i;
                float4 v = *(const float4*)(xr + f4i * 4);
                int k = f4i * 4;
                As[k][row] = v.x; As[k+1][row] = v.y;
                As[k+2][row] = v.z; As[k+3][row] = v.w;
            }
        }
        {   // B: 64 k x 128 n
            #pragma unroll
            for (int i = 0; i < 8; i++) {
                int idx = tid + 256 * i;
                int k = idx >> 5, nq = idx & 31;
                float4 v = *(const float4*)(wb + (size_t)(k0 + k) * D + nq * 4);
                *(float4*)&Bs[k][nq * 4] = v;
            }
        }
        __syncthreads();
        #pragma unroll 4
        for (int kk = 0; kk < 64; kk++) {
            float4 a0 = *(const float4*)&As[kk][tr * 8];
            float4 a1 = *(const float4*)&As[kk][tr * 8 + 4];
            float4 bv = *(const float4*)&Bs[kk][tc * 4];
            float ar[8] = {a0.x,a0.y,a0.z,a0.w,a1.x,a1.y,a1.z,a1.w};
            #pragma unroll
            for (int i = 0; i < 8; i++) {
                acc[i][0] += ar[i] * bv.x;
                acc[i][1] += ar[i] * bv.y;
                acc[i][2] += ar[i] * bv.z;
                acc[i][3] += ar[i] * bv.w;
            }
        }
    }
    // epilogue: gelu + partial logits (h @ Wr2 slice)
    float lp[8][8] = {};
    #pragma unroll
    for (int j = 0; j < 4; j++) {
        int col = bn * 128 + tc * 4 + j;
        float b1 = br1[col];
        float w2[8];
        #pragma unroll
        for (int o = 0; o < 8; o++) w2[o] = Wr2[col * 8 + o];
        #pragma unroll
        for (int i = 0; i < 8; i++) {
            float h = gelu_f(acc[i][j] + b1);
            #pragma unroll
            for (int o = 0; o < 8; o++) lp[i][o] += h * w2[o];
        }
    }
    #pragma unroll
    for (int m = 16; m >= 1; m >>= 1) {
        #pragma unroll
        for (int i = 0; i < 8; i++) {
            #pragma unroll
            for (int o = 0; o < 8; o++)
                lp[i][o] += __shfl_xor(lp[i][o], m, 64);
        }
    }
    if (tc == 0) {
        #pragma unroll
        for (int i = 0; i < 8; i++) {
            int token = bm * 64 + tr * 8 + i;
            float* p = part + ((size_t)token * 8 + bn) * 8;
            #pragma unroll
            for (int o = 0; o < 8; o++) p[o] = lp[i][o];
        }
    }
}

// ---------------------------------------------------------------------------
// Argmax both routers (fixed summation order over N-tiles -> deterministic),
// build merged per-expert task lists: flag bit17=sum, bit18=diff.
// ---------------------------------------------------------------------------
__global__ __launch_bounds__(256) void k_amx(
    const float* __restrict__ ps, const float* __restrict__ pd,
    const float* __restrict__ b2s, const float* __restrict__ b2d,
    int* __restrict__ tasks, int* __restrict__ counts)
{
    int i = blockIdx.x * 256 + threadIdx.x;
    float L[8];
    const float* p = ps + (size_t)i * 64;
    #pragma unroll
    for (int o = 0; o < 8; o++) L[o] = b2s[o];
    #pragma unroll
    for (int nt = 0; nt < 8; nt++) {
        #pragma unroll
        for (int o = 0; o < 8; o++) L[o] += p[nt * 8 + o];
    }
    int ts = 0; float bestv = L[0];
    #pragma unroll
    for (int o = 1; o < 8; o++) if (L[o] > bestv) { bestv = L[o]; ts = o; }

    p = pd + (size_t)i * 64;
    #pragma unroll
    for (int o = 0; o < 8; o++) L[o] = b2d[o];
    #pragma unroll
    for (int nt = 0; nt < 8; nt++) {
        #pragma unroll
        for (int o = 0; o < 8; o++) L[o] += p[nt * 8 + o];
    }
    int td = 0; bestv = L[0];
    #pragma unroll
    for (int o = 1; o < 8; o++) if (L[o] > bestv) { bestv = L[o]; td = o; }

    if (ts == td) {
        int s = atomicAdd(&counts[ts], 1);
        tasks[ts * QN + s] = i | (3 << 17);
    } else {
        int s1 = atomicAdd(&counts[ts], 1);
        tasks[ts * QN + s1] = i | (1 << 17);
        int s2 = atomicAdd(&counts[td], 1);
        tasks[td * QN + s2] = i | (2 << 17);
    }
}

// ---------------------------------------------------------------------------
// Expert: gathered rows (64 tasks/block), h2 = gelu(x @ We1[e] + be1[e]),
// fused epilogue: out scalars += h2 . v_sum / v_diff per flag.
// Tile: BM=64 x BN=512-chunk (x4) x BK=16.
// ---------------------------------------------------------------------------
__global__ __launch_bounds__(256) void k_exp(
    const float* __restrict__ x, const float* __restrict__ We1,
    const float* __restrict__ be1, const float* __restrict__ v_sum,
    const float* __restrict__ v_diff, const float* __restrict__ c_sum,
    const float* __restrict__ c_diff, const int* __restrict__ tasks,
    const int* __restrict__ counts, float* __restrict__ out, int tok0)
{
    int e = blockIdx.y;
    int cnt = counts[e];
    int r0 = blockIdx.x * 64;
    if (r0 >= cnt) return;
    __shared__ float As[16][72];
    __shared__ float Bs[16][516];
    __shared__ int tokL[64];
    __shared__ int flgL[64];
    int tid = threadIdx.x;
    if (tid < 64) {
        int idx = r0 + tid;
        int tv = tasks[e * QN + min(idx, cnt - 1)];
        tokL[tid] = tv & 0xFFFF;
        flgL[tid] = (idx < cnt) ? ((tv >> 17) & 3) : 0;
    }
    __syncthreads();
    int tr = tid >> 5, tc = tid & 31;
    float ssum[8] = {}, sdif[8] = {};
    const float* wbase = We1 + (size_t)e * D * DH;

    for (int c0 = 0; c0 < DH; c0 += 512) {
        float acc[8][16] = {};
        for (int k0 = 0; k0 < D; k0 += 16) {
            __syncthreads();
            {   // A: 64 rows x 16 k (gathered), transposed
                int row = tid >> 2, q = tid & 3;
                const float* xr = x + (size_t)tokL[row] * D + k0 + q * 4;
                float4 v = *(const float4*)xr;
                int k = q * 4;
                As[k][row] = v.x; As[k+1][row] = v.y;
                As[k+2][row] = v.z; As[k+3][row] = v.w;
            }
            {   // B: 16 k x 512 n
                const float* wb = wbase + (size_t)k0 * DH + c0;
                #pragma unroll
                for (int i = 0; i < 8; i++) {
                    int idx = tid + 256 * i;
                    int k = idx >> 7, nq = idx & 127;
                    float4 v = *(const float4*)(wb + (size_t)k * DH + nq * 4);
                    *(float4*)&Bs[k][nq * 4] = v;
                }
            }
            __syncthreads();
            #pragma unroll
            for (int kk = 0; kk < 16; kk++) {
                float4 a0 = *(const float4*)&As[kk][tr * 8];
                float4 a1 = *(const float4*)&As[kk][tr * 8 + 4];
                float ar[8] = {a0.x,a0.y,a0.z,a0.w,a1.x,a1.y,a1.z,a1.w};
                #pragma unroll
                for (int g = 0; g < 4; g++) {
                    float4 bv = *(const float4*)&Bs[kk][g * 128 + tc * 4];
                    #pragma unroll
                    for (int i = 0; i < 8; i++) {
                        acc[i][g*4+0] += ar[i] * bv.x;
                        acc[i][g*4+1] += ar[i] * bv.y;
                        acc[i][g*4+2] += ar[i] * bv.z;
                        acc[i][g*4+3] += ar[i] * bv.w;
                    }
                }
            }
        }
        // epilogue: gelu + v-dot accumulate
        #pragma unroll
        for (int g = 0; g < 4; g++) {
            #pragma unroll
            for (int j = 0; j < 4; j++) {
                int col = c0 + g * 128 + tc * 4 + j;
                float b1 = be1[e * DH + col];
                float vs = v_sum[(size_t)e * DH + col];
                float vd = v_diff[(size_t)e * DH + col];
                #pragma unroll
                for (int i = 0; i < 8; i++) {
                    float h = gelu_f(acc[i][g*4+j] + b1);
                    ssum[i] += h * vs;
                    sdif[i] += h * vd;
                }
            }
        }
    }
    #pragma unroll
    for (int m = 16; m >= 1; m >>= 1) {
        #pragma unroll
        for (int i = 0; i < 8; i++) {
            ssum[i] += __shfl_xor(ssum[i], m, 64);
            sdif[i] += __shfl_xor(sdif[i], m, 64);
        }
    }
    if (tc == 0) {
        float cs = c_sum[e], cd = c_diff[e];
        #pragma unroll
        for (int i = 0; i < 8; i++) {
            int r = tr * 8 + i;
            int fl = flgL[r];
            int gt = tok0 + tokL[r];
            if (fl & 1) out[gt]      = ssum[i] + cs;
            if (fl & 2) out[BT + gt] = sdif[i] + cd;
        }
    }
}

// ---------------------------------------------------------------------------
extern "C" void kernel_launch(void* const* d_in, const int* in_sizes, int n_in,
                              void* d_out, int out_size, void* d_ws, size_t ws_size,
                              hipStream_t stream)
{
    const float* a      = (const float*)d_in[0];
    const float* b      = (const float*)d_in[1];
    const float* W_in   = (const float*)d_in[2];
    const float* b_in   = (const float*)d_in[3];
    const float* ln_g   = (const float*)d_in[4];
    const float* ln_b   = (const float*)d_in[5];
    const float* Wr1s   = (const float*)d_in[6];
    const float* br1s   = (const float*)d_in[7];
    const float* Wr2s   = (const float*)d_in[8];
    const float* br2s   = (const float*)d_in[9];
    const float* Wr1d   = (const float*)d_in[10];
    const float* br1d   = (const float*)d_in[11];
    const float* Wr2d   = (const float*)d_in[12];
    const float* br2d   = (const float*)d_in[13];
    const float* We1    = (const float*)d_in[14];
    const float* be1    = (const float*)d_in[15];
    const float* We2    = (const float*)d_in[16];
    const float* be2    = (const float*)d_in[17];
    const float* w_sum  = (const float*)d_in[18];
    const float* bs     = (const float*)d_in[19];
    const float* w_diff = (const float*)d_in[20];
    const float* bd     = (const float*)d_in[21];
    float* out = (float*)d_out;

    char* w = (char*)d_ws;
    size_t off = 0;
    auto alloc = [&](size_t bytes) -> char* {
        char* p = w + off;
        off = (off + bytes + 255) & ~(size_t)255;
        return p;
    };
    float* v_sum  = (float*)alloc((size_t)NT * DH * 4);
    float* v_diff = (float*)alloc((size_t)NT * DH * 4);
    float* c_sum  = (float*)alloc(64);
    float* c_diff = (float*)alloc(64);
    float* x      = (float*)alloc((size_t)QN * D * 4);
    float* ps     = (float*)alloc((size_t)QN * 64 * 4);
    float* pd     = (float*)alloc((size_t)QN * 64 * 4);
    int*   tasks  = (int*)alloc((size_t)NT * QN * 4);
    int*   counts = (int*)alloc(64);
    if (off > ws_size) {
        // workspace too small: leave output wrong but visibly so (all ~zero)
        hipMemsetAsync(d_out, 0, (size_t)out_size * 4, stream);
        return;
    }

    k_prev<<<dim3(4097), dim3(256), 0, stream>>>(We2, w_sum, w_diff, be2, bs, bd,
                                                 v_sum, v_diff, c_sum, c_diff);
    for (int q = 0; q < NPASS; q++) {
        int tok0 = q * QN;
        k_enc<<<dim3(QN / 64), dim3(256), 0, stream>>>(a, b, W_in, b_in, ln_g, ln_b, x, tok0);
        k_rtr<<<dim3(QN / 64, 8), dim3(256), 0, stream>>>(x, Wr1s, br1s, Wr2s, ps);
        k_rtr<<<dim3(QN / 64, 8), dim3(256), 0, stream>>>(x, Wr1d, br1d, Wr2d, pd);
        hipMemsetAsync(counts, 0, 64, stream);
        k_amx<<<dim3(QN / 256), dim3(256), 0, stream>>>(ps, pd, br2s, br2d, tasks, counts);
        k_exp<<<dim3(QN / 64, 8), dim3(256), 0, stream>>>(x, We1, be1, v_sum, v_diff,
                                                          c_sum, c_diff, tasks, counts, out, tok0);
    }
}

// Round 2
// 6245.265 us; speedup vs baseline: 2.5178x; 2.5178x over previous
//
#include <hip/hip_runtime.h>
#include <math.h>

// ============================================================================
// PureTriXButterfly.
// R2: expert path moved to fp16 MFMA (32x32x16), fused gelu+v-dot epilogue.
// Encoder/router/argmax chain kept bit-identical to R1 (fp32, passed with
// absmax 1.95e-3; routing argmax must not flip).
// ============================================================================

#define BT 65536     // total batch
#define QN 16384     // tokens per pass
#define NPASS 4
#define D 1024
#define NT 8
#define DH 2048
#define TSTR (2*QN)  // task-list stride per expert (max 2 entries/token)

typedef _Float16 f16;
typedef _Float16 f16x8 __attribute__((ext_vector_type(8)));
typedef _Float16 f16x4 __attribute__((ext_vector_type(4)));
typedef float f32x16 __attribute__((ext_vector_type(16)));

__device__ __forceinline__ float gelu_f(float v) {
    return 0.5f * v * (1.0f + erff(v * 0.70710678118654752440f));
}

// fast exact-GELU via A&S 7.1.26 erf (|eps| <= 1.5e-7) — expert path only
__device__ __forceinline__ float gelu_fast(float x) {
    float ax = fabsf(x) * 0.70710678118654752440f;
    float t = __builtin_amdgcn_rcpf(1.0f + 0.3275911f * ax);
    float p = t * (0.254829592f + t * (-0.284496736f + t * (1.421413741f +
              t * (-1.453152027f + t * 1.061405429f))));
    float er = 1.0f - p * __expf(-ax * ax);
    er = copysignf(er, x);
    return 0.5f * x * (1.0f + er);
}

// ---------------------------------------------------------------------------
// v_sum[t][j] = We2[t][j,:].w_sum ; c_sum[t] = be2[t].w_sum + bs (same diff)
// ---------------------------------------------------------------------------
__global__ __launch_bounds__(256) void k_prev(
    const float* __restrict__ We2, const float* __restrict__ w_sum,
    const float* __restrict__ w_diff, const float* __restrict__ be2,
    const float* __restrict__ bs, const float* __restrict__ bd,
    float* __restrict__ v_sum, float* __restrict__ v_diff,
    float* __restrict__ c_sum, float* __restrict__ c_diff)
{
    int bid = blockIdx.x;
    if (bid < 4096) {
        int row  = bid * 4 + (threadIdx.x >> 6);
        int lane = threadIdx.x & 63;
        const float* r = We2 + (size_t)row * D;
        float s1 = 0.f, s2 = 0.f;
        #pragma unroll
        for (int i = 0; i < 4; i++) {
            int o4 = (lane + 64 * i) * 4;
            float4 w = *(const float4*)(r + o4);
            float4 u = *(const float4*)(w_sum + o4);
            float4 v = *(const float4*)(w_diff + o4);
            s1 += w.x*u.x + w.y*u.y + w.z*u.z + w.w*u.w;
            s2 += w.x*v.x + w.y*v.y + w.z*v.z + w.w*v.w;
        }
        #pragma unroll
        for (int m = 32; m >= 1; m >>= 1) {
            s1 += __shfl_xor(s1, m, 64);
            s2 += __shfl_xor(s2, m, 64);
        }
        if (lane == 0) { v_sum[row] = s1; v_diff[row] = s2; }
    } else {
        int t = threadIdx.x;
        if (t < 8) {
            float s = 0.f; const float* r = be2 + t * D;
            for (int k = 0; k < D; k++) s += r[k] * w_sum[k];
            c_sum[t] = s + bs[0];
        } else if (t < 16) {
            int tt = t - 8;
            float s = 0.f; const float* r = be2 + tt * D;
            for (int k = 0; k < D; k++) s += r[k] * w_diff[k];
            c_diff[tt] = s + bd[0];
        }
    }
}

// ---------------------------------------------------------------------------
// We1 [e][k=1024][n=2048] fp32  ->  We1T [e][n][k] fp16 (LDS tile transpose)
// ---------------------------------------------------------------------------
__global__ __launch_bounds__(256) void k_cvt(
    const float* __restrict__ We1, f16* __restrict__ We1T)
{
    __shared__ float tile[64][65];
    int b = blockIdx.x;
    int e = b >> 9, rem = b & 511;
    int kt = rem >> 5, nt = rem & 31;
    int tid = threadIdx.x;
    const float* src = We1 + ((size_t)e * D + kt * 64) * DH + nt * 64;
    #pragma unroll
    for (int i = 0; i < 16; i++) {
        int idx = tid + 256 * i;
        int kk = idx >> 6, nn = idx & 63;
        tile[kk][nn] = src[(size_t)kk * DH + nn];
    }
    __syncthreads();
    f16* dst = We1T + ((size_t)e * DH + nt * 64) * D + kt * 64;
    #pragma unroll
    for (int i = 0; i < 16; i++) {
        int idx = tid + 256 * i;
        int nn = idx >> 6, kk = idx & 63;
        dst[(size_t)nn * D + kk] = (f16)tile[kk][nn];
    }
}

// ---------------------------------------------------------------------------
// Encoder (unchanged math) + fp16 copy of x for the expert path.
// ---------------------------------------------------------------------------
__global__ __launch_bounds__(256) void k_enc(
    const float* __restrict__ a, const float* __restrict__ b,
    const float* __restrict__ W_in, const float* __restrict__ b_in,
    const float* __restrict__ ln_g, const float* __restrict__ ln_b,
    float* __restrict__ x, f16* __restrict__ xh, int tok0)
{
    __shared__ float x0[64][24];
    __shared__ float red[8];
    int tid = threadIdx.x;
    float4 Wc[24];
    #pragma unroll
    for (int f = 0; f < 24; f++) Wc[f] = *(const float4*)(W_in + f * D + tid * 4);
    float4 bi = *(const float4*)(b_in + tid * 4);
    float4 gg = *(const float4*)(ln_g + tid * 4);
    float4 bb = *(const float4*)(ln_b + tid * 4);
    int base = tok0 + blockIdx.x * 64;

    for (int idx = tid; idx < 64 * 12; idx += 256) {
        int t = idx / 12, q = idx - t * 12;
        int fr = q % 6;
        float in = (q < 6) ? a[base + t] : b[base + t];
        float ang = (in * 0.39269908169872414f) * (float)(1 << fr);
        int off = (q < 6) ? 0 : 12;
        x0[t][off + fr]     = sinf(ang);
        x0[t][off + 6 + fr] = cosf(ang);
    }
    __syncthreads();

    int lane = tid & 63, wid = tid >> 6;
    for (int t = 0; t < 64; t++) {
        float4 p = bi;
        #pragma unroll
        for (int f = 0; f < 24; f++) {
            float xv = x0[t][f];
            p.x += xv * Wc[f].x; p.y += xv * Wc[f].y;
            p.z += xv * Wc[f].z; p.w += xv * Wc[f].w;
        }
        float s1 = p.x + p.y + p.z + p.w;
        float s2 = p.x*p.x + p.y*p.y + p.z*p.z + p.w*p.w;
        #pragma unroll
        for (int m = 32; m >= 1; m >>= 1) {
            s1 += __shfl_xor(s1, m, 64);
            s2 += __shfl_xor(s2, m, 64);
        }
        if (lane == 0) { red[wid] = s1; red[4 + wid] = s2; }
        __syncthreads();
        float mean = (red[0] + red[1] + red[2] + red[3]) * (1.f / 1024.f);
        float ms   = (red[4] + red[5] + red[6] + red[7]) * (1.f / 1024.f);
        float inv  = 1.f / sqrtf(ms - mean * mean + 1e-5f);
        float4 o;
        o.x = gelu_f((p.x - mean) * inv * gg.x + bb.x);
        o.y = gelu_f((p.y - mean) * inv * gg.y + bb.y);
        o.z = gelu_f((p.z - mean) * inv * gg.z + bb.z);
        o.w = gelu_f((p.w - mean) * inv * gg.w + bb.w);
        size_t row = (size_t)(blockIdx.x * 64 + t);
        *(float4*)(x + row * D + tid * 4) = o;
        f16x4 h; h[0] = (f16)o.x; h[1] = (f16)o.y; h[2] = (f16)o.z; h[3] = (f16)o.w;
        *(f16x4*)(xh + row * D + tid * 4) = h;
        __syncthreads();
    }
}

// ---------------------------------------------------------------------------
// Router GEMM (unchanged — fp32 routing chain must stay bit-identical).
// ---------------------------------------------------------------------------
__global__ __launch_bounds__(256) void k_rtr(
    const float* __restrict__ x, const float* __restrict__ Wr1,
    const float* __restrict__ br1, const float* __restrict__ Wr2,
    float* __restrict__ part)
{
    __shared__ float As[64][72];
    __shared__ float Bs[64][132];
    int tid = threadIdx.x;
    int bm = blockIdx.x, bn = blockIdx.y;
    int tr = tid >> 5, tc = tid & 31;
    float acc[8][4] = {};
    const float* xb = x + (size_t)bm * 64 * D;
    const float* wb = Wr1 + bn * 128;

    for (int k0 = 0; k0 < D; k0 += 64) {
        __syncthreads();
        {
            int row = tid >> 2, q = tid & 3;
            const float* xr = xb + (size_t)row * D + k0;
            #pragma unroll
            for (int i = 0; i < 4; i++) {
                int f4i = q + 4 * i;
                float4 v = *(const float4*)(xr + f4i * 4);
                int k = f4i * 4;
                As[k][row] = v.x; As[k+1][row] = v.y;
                As[k+2][row] = v.z; As[k+3][row] = v.w;
            }
        }
        {
            #pragma unroll
            for (int i = 0; i < 8; i++) {
                int idx = tid + 256 * i;
                int k = idx >> 5, nq = idx & 31;
                float4 v = *(const float4*)(wb + (size_t)(k0 + k) * D + nq * 4);
                *(float4*)&Bs[k][nq * 4] = v;
            }
        }
        __syncthreads();
        #pragma unroll 4
        for (int kk = 0; kk < 64; kk++) {
            float4 a0 = *(const float4*)&As[kk][tr * 8];
            float4 a1 = *(const float4*)&As[kk][tr * 8 + 4];
            float4 bv = *(const float4*)&Bs[kk][tc * 4];
            float ar[8] = {a0.x,a0.y,a0.z,a0.w,a1.x,a1.y,a1.z,a1.w};
            #pragma unroll
            for (int i = 0; i < 8; i++) {
                acc[i][0] += ar[i] * bv.x;
                acc[i][1] += ar[i] * bv.y;
                acc[i][2] += ar[i] * bv.z;
                acc[i][3] += ar[i] * bv.w;
            }
        }
    }
    float lp[8][8] = {};
    #pragma unroll
    for (int j = 0; j < 4; j++) {
        int col = bn * 128 + tc * 4 + j;
        float b1 = br1[col];
        float w2[8];
        #pragma unroll
        for (int o = 0; o < 8; o++) w2[o] = Wr2[col * 8 + o];
        #pragma unroll
        for (int i = 0; i < 8; i++) {
            float h = gelu_f(acc[i][j] + b1);
            #pragma unroll
            for (int o = 0; o < 8; o++) lp[i][o] += h * w2[o];
        }
    }
    #pragma unroll
    for (int m = 16; m >= 1; m >>= 1) {
        #pragma unroll
        for (int i = 0; i < 8; i++) {
            #pragma unroll
            for (int o = 0; o < 8; o++)
                lp[i][o] += __shfl_xor(lp[i][o], m, 64);
        }
    }
    if (tc == 0) {
        #pragma unroll
        for (int i = 0; i < 8; i++) {
            int token = bm * 64 + tr * 8 + i;
            float* p = part + ((size_t)token * 8 + bn) * 8;
            #pragma unroll
            for (int o = 0; o < 8; o++) p[o] = lp[i][o];
        }
    }
}

// ---------------------------------------------------------------------------
// Argmax + merged task lists (stride TSTR).
// ---------------------------------------------------------------------------
__global__ __launch_bounds__(256) void k_amx(
    const float* __restrict__ ps, const float* __restrict__ pd,
    const float* __restrict__ b2s, const float* __restrict__ b2d,
    int* __restrict__ tasks, int* __restrict__ counts)
{
    int i = blockIdx.x * 256 + threadIdx.x;
    float L[8];
    const float* p = ps + (size_t)i * 64;
    #pragma unroll
    for (int o = 0; o < 8; o++) L[o] = b2s[o];
    #pragma unroll
    for (int nt = 0; nt < 8; nt++) {
        #pragma unroll
        for (int o = 0; o < 8; o++) L[o] += p[nt * 8 + o];
    }
    int ts = 0; float bestv = L[0];
    #pragma unroll
    for (int o = 1; o < 8; o++) if (L[o] > bestv) { bestv = L[o]; ts = o; }

    p = pd + (size_t)i * 64;
    #pragma unroll
    for (int o = 0; o < 8; o++) L[o] = b2d[o];
    #pragma unroll
    for (int nt = 0; nt < 8; nt++) {
        #pragma unroll
        for (int o = 0; o < 8; o++) L[o] += p[nt * 8 + o];
    }
    int td = 0; bestv = L[0];
    #pragma unroll
    for (int o = 1; o < 8; o++) if (L[o] > bestv) { bestv = L[o]; td = o; }

    if (ts == td) {
        int s = atomicAdd(&counts[ts], 1);
        tasks[ts * TSTR + s] = i | (3 << 17);
    } else {
        int s1 = atomicAdd(&counts[ts], 1);
        tasks[ts * TSTR + s1] = i | (1 << 17);
        int s2 = atomicAdd(&counts[td], 1);
        tasks[td * TSTR + s2] = i | (2 << 17);
    }
}

// ---------------------------------------------------------------------------
// Expert GEMM, fp16 MFMA 32x32x16.
// BM=128 gathered rows, BN=256 (loop n0 over DH), BK=64 staged in LDS.
// 4 waves: wave (wr,wc) computes rows wr*64..+63 (2 M-frags) x cols
// wc*128..+127 (4 N-frags). XOR-swizzled LDS (byte ^= (row&7)<<4) for
// conflict-free ds_read_b128. Fused epilogue: gelu + dot(v_sum/v_diff),
// deterministic reduction (shfl over 32 col-lanes, then LDS cross-wave).
// ---------------------------------------------------------------------------
__global__ __launch_bounds__(256) void k_expm(
    const f16* __restrict__ xh, const f16* __restrict__ We1T,
    const float* __restrict__ be1, const float* __restrict__ v_sum,
    const float* __restrict__ v_diff, const float* __restrict__ c_sum,
    const float* __restrict__ c_diff, const int* __restrict__ tasks,
    const int* __restrict__ counts, float* __restrict__ out, int tok0)
{
    int e = blockIdx.y;
    int cnt = counts[e];
    int r0 = blockIdx.x * 128;
    if (r0 >= cnt) return;

    __shared__ char smem[49152] __attribute__((aligned(16)));  // A 16K | B 32K
    __shared__ int tokL[128];
    __shared__ int flgL[128];
    __shared__ float redS[2][128];
    __shared__ float redD[2][128];

    int tid = threadIdx.x;
    if (tid < 128) {
        int idx = r0 + tid;
        int tv = tasks[e * TSTR + min(idx, cnt - 1)];
        tokL[tid] = tv & 0xFFFF;
        flgL[tid] = (idx < cnt) ? ((tv >> 17) & 3) : 0;
    }
    __syncthreads();

    int lane = tid & 63;
    int wid  = tid >> 6;
    int wr = wid >> 1, wc = wid & 1;
    int hi = lane >> 5, l31 = lane & 31;

    // ---- staging geometry (constant per thread) ----
    int sg = tid >> 3;                       // 0..31 : row/n sub-index
    int sc = tid & 7;                        // 0..7  : 16B chunk in 128B row
    int stoff = sg * 128 + ((sc * 16) ^ ((sg & 7) << 4));   // swizzled dst
    size_t asrc_off[4];
    #pragma unroll
    for (int i = 0; i < 4; i++)
        asrc_off[i] = (size_t)tokL[i * 32 + sg] * (D * 2) + sc * 16;
    const char* xh_b   = (const char*)xh;
    const char* we1t_e = (const char*)(We1T + (size_t)e * DH * D);
    size_t bs_off = (size_t)sg * (D * 2) + sc * 16;

    // ---- fragment read offsets ----
    int axor = (l31 & 7) << 4;
    int kx[4];
    #pragma unroll
    for (int ks = 0; ks < 4; ks++) kx[ks] = (ks * 32 + hi * 16) ^ axor;
    int arow[2], nrow[4];
    #pragma unroll
    for (int mi = 0; mi < 2; mi++) arow[mi] = (wr * 64 + mi * 32 + l31) * 128;
    #pragma unroll
    for (int ni = 0; ni < 4; ni++) nrow[ni] = 16384 + (wc * 128 + ni * 32 + l31) * 128;

    float ss[2][16] = {}, sd[2][16] = {};

    for (int n0 = 0; n0 < DH; n0 += 256) {
        f32x16 acc[2][4];
        #pragma unroll
        for (int mi = 0; mi < 2; mi++)
            #pragma unroll
            for (int ni = 0; ni < 4; ni++)
                acc[mi][ni] = (f32x16)(0.0f);

        const char* bsrc0 = we1t_e + (size_t)n0 * (D * 2) + bs_off;

        for (int k0 = 0; k0 < D; k0 += 64) {
            __syncthreads();
            #pragma unroll
            for (int i = 0; i < 4; i++) {
                int4 v = *(const int4*)(xh_b + asrc_off[i] + k0 * 2);
                *(int4*)(smem + i * 4096 + stoff) = v;
            }
            #pragma unroll
            for (int i = 0; i < 8; i++) {
                int4 v = *(const int4*)(bsrc0 + (size_t)i * 32 * (D * 2) + k0 * 2);
                *(int4*)(smem + 16384 + i * 4096 + stoff) = v;
            }
            __syncthreads();
            #pragma unroll
            for (int ks = 0; ks < 4; ks++) {
                f16x8 a0 = *(const f16x8*)(smem + arow[0] + kx[ks]);
                f16x8 a1 = *(const f16x8*)(smem + arow[1] + kx[ks]);
                #pragma unroll
                for (int ni = 0; ni < 4; ni++) {
                    f16x8 bf = *(const f16x8*)(smem + nrow[ni] + kx[ks]);
                    acc[0][ni] = __builtin_amdgcn_mfma_f32_32x32x16_f16(a0, bf, acc[0][ni], 0, 0, 0);
                    acc[1][ni] = __builtin_amdgcn_mfma_f32_32x32x16_f16(a1, bf, acc[1][ni], 0, 0, 0);
                }
            }
        }
        // epilogue for this n0: gelu + dot with v
        #pragma unroll
        for (int ni = 0; ni < 4; ni++) {
            int col = n0 + wc * 128 + ni * 32 + l31;
            float b1 = be1[e * DH + col];
            float vs = v_sum[e * DH + col];
            float vd = v_diff[e * DH + col];
            #pragma unroll
            for (int mi = 0; mi < 2; mi++) {
                #pragma unroll
                for (int r = 0; r < 16; r++) {
                    float h = gelu_fast(acc[mi][ni][r] + b1);
                    ss[mi][r] += h * vs;
                    sd[mi][r] += h * vd;
                }
            }
        }
    }

    // reduce over the 32 col-lanes (row-preserving: all masks keep lane>>5)
    #pragma unroll
    for (int m = 16; m >= 1; m >>= 1) {
        #pragma unroll
        for (int mi = 0; mi < 2; mi++)
            #pragma unroll
            for (int r = 0; r < 16; r++) {
                ss[mi][r] += __shfl_xor(ss[mi][r], m, 64);
                sd[mi][r] += __shfl_xor(sd[mi][r], m, 64);
            }
    }
    if (l31 == 0) {
        #pragma unroll
        for (int mi = 0; mi < 2; mi++)
            #pragma unroll
            for (int r = 0; r < 16; r++) {
                int row = wr * 64 + mi * 32 + (r & 3) + 8 * (r >> 2) + 4 * hi;
                redS[wc][row] = ss[mi][r];
                redD[wc][row] = sd[mi][r];
            }
    }
    __syncthreads();
    if (tid < 128) {
        float s = (redS[0][tid] + redS[1][tid]) + c_sum[e];
        float d = (redD[0][tid] + redD[1][tid]) + c_diff[e];
        int fl = flgL[tid];
        int gt = tok0 + tokL[tid];
        if (fl & 1) out[gt]      = s;
        if (fl & 2) out[BT + gt] = d;
    }
}

// ---------------------------------------------------------------------------
extern "C" void kernel_launch(void* const* d_in, const int* in_sizes, int n_in,
                              void* d_out, int out_size, void* d_ws, size_t ws_size,
                              hipStream_t stream)
{
    const float* a      = (const float*)d_in[0];
    const float* b      = (const float*)d_in[1];
    const float* W_in   = (const float*)d_in[2];
    const float* b_in   = (const float*)d_in[3];
    const float* ln_g   = (const float*)d_in[4];
    const float* ln_b   = (const float*)d_in[5];
    const float* Wr1s   = (const float*)d_in[6];
    const float* br1s   = (const float*)d_in[7];
    const float* Wr2s   = (const float*)d_in[8];
    const float* br2s   = (const float*)d_in[9];
    const float* Wr1d   = (const float*)d_in[10];
    const float* br1d   = (const float*)d_in[11];
    const float* Wr2d   = (const float*)d_in[12];
    const float* br2d   = (const float*)d_in[13];
    const float* We1    = (const float*)d_in[14];
    const float* be1    = (const float*)d_in[15];
    const float* We2    = (const float*)d_in[16];
    const float* be2    = (const float*)d_in[17];
    const float* w_sum  = (const float*)d_in[18];
    const float* bs     = (const float*)d_in[19];
    const float* w_diff = (const float*)d_in[20];
    const float* bd     = (const float*)d_in[21];
    float* out = (float*)d_out;

    char* w = (char*)d_ws;
    size_t off = 0;
    auto alloc = [&](size_t bytes) -> char* {
        char* p = w + off;
        off = (off + bytes + 255) & ~(size_t)255;
        return p;
    };
    float* v_sum  = (float*)alloc((size_t)NT * DH * 4);
    float* v_diff = (float*)alloc((size_t)NT * DH * 4);
    float* c_sum  = (float*)alloc(64);
    float* c_diff = (float*)alloc(64);
    float* x      = (float*)alloc((size_t)QN * D * 4);
    f16*   xh     = (f16*)alloc((size_t)QN * D * 2);
    float* ps     = (float*)alloc((size_t)QN * 64 * 4);
    float* pd     = (float*)alloc((size_t)QN * 64 * 4);
    int*   tasks  = (int*)alloc((size_t)NT * TSTR * 4);
    int*   counts = (int*)alloc(64);
    f16*   We1T   = (f16*)alloc((size_t)NT * DH * D * 2);
    if (off > ws_size) {
        hipMemsetAsync(d_out, 0, (size_t)out_size * 4, stream);
        return;
    }

    k_cvt<<<dim3(4096), dim3(256), 0, stream>>>(We1, We1T);
    k_prev<<<dim3(4097), dim3(256), 0, stream>>>(We2, w_sum, w_diff, be2, bs, bd,
                                                 v_sum, v_diff, c_sum, c_diff);
    for (int q = 0; q < NPASS; q++) {
        int tok0 = q * QN;
        k_enc<<<dim3(QN / 64), dim3(256), 0, stream>>>(a, b, W_in, b_in, ln_g, ln_b, x, xh, tok0);
        k_rtr<<<dim3(QN / 64, 8), dim3(256), 0, stream>>>(x, Wr1s, br1s, Wr2s, ps);
        k_rtr<<<dim3(QN / 64, 8), dim3(256), 0, stream>>>(x, Wr1d, br1d, Wr2d, pd);
        hipMemsetAsync(counts, 0, 64, stream);
        k_amx<<<dim3(QN / 256), dim3(256), 0, stream>>>(ps, pd, br2s, br2d, tasks, counts);
        k_expm<<<dim3(QN / 64, 8), dim3(256), 0, stream>>>(xh, We1T, be1, v_sum, v_diff,
                                                           c_sum, c_diff, tasks, counts, out, tok0);
    }
}

// Round 3
// 5892.369 us; speedup vs baseline: 2.6685x; 1.0599x over previous
//
#include <hip/hip_runtime.h>
#include <math.h>

// ============================================================================
// PureTriXButterfly — R3.
// - k_expm: XCD-pinned experts (e = blockIdx.x & 7) so each expert's 4MB
//   weight set lives in one XCD's L2 (was: 337MB HBM refetch/dispatch).
// - Routers: fused fp16 MFMA GEMM (both routers, N=2048) computed as
//   C[n][token] so logit partials accumulate in-register per lane; tokens
//   with top-2 margin < DELTA (~5%) get exact fp32 recompute (k_redo).
// - Encoder/argmax semantics unchanged vs R1/R2 (passed, absmax 7.8e-3).
// ============================================================================

#define BT 65536
#define QN 16384
#define NPASS 4
#define D 1024
#define NT 8
#define DH 2048
#define TSTR (2*QN)
#define RCAP 4096
#define DELTA 0.025f

typedef _Float16 f16;
typedef _Float16 f16x8 __attribute__((ext_vector_type(8)));
typedef _Float16 f16x4 __attribute__((ext_vector_type(4)));
typedef float f32x16 __attribute__((ext_vector_type(16)));

__device__ __forceinline__ float gelu_f(float v) {
    return 0.5f * v * (1.0f + erff(v * 0.70710678118654752440f));
}

// fast exact-GELU via A&S 7.1.26 erf (|eps| <= 1.5e-7)
__device__ __forceinline__ float gelu_fast(float x) {
    float ax = fabsf(x) * 0.70710678118654752440f;
    float t = __builtin_amdgcn_rcpf(1.0f + 0.3275911f * ax);
    float p = t * (0.254829592f + t * (-0.284496736f + t * (1.421413741f +
              t * (-1.453152027f + t * 1.061405429f))));
    float er = 1.0f - p * __expf(-ax * ax);
    er = copysignf(er, x);
    return 0.5f * x * (1.0f + er);
}

// ---------------------------------------------------------------------------
// v_sum[t][j] = We2[t][j,:].w_sum ; c_sum[t] = be2[t].w_sum + bs (same diff)
// ---------------------------------------------------------------------------
__global__ __launch_bounds__(256) void k_prev(
    const float* __restrict__ We2, const float* __restrict__ w_sum,
    const float* __restrict__ w_diff, const float* __restrict__ be2,
    const float* __restrict__ bs, const float* __restrict__ bd,
    float* __restrict__ v_sum, float* __restrict__ v_diff,
    float* __restrict__ c_sum, float* __restrict__ c_diff)
{
    int bid = blockIdx.x;
    if (bid < 4096) {
        int row  = bid * 4 + (threadIdx.x >> 6);
        int lane = threadIdx.x & 63;
        const float* r = We2 + (size_t)row * D;
        float s1 = 0.f, s2 = 0.f;
        #pragma unroll
        for (int i = 0; i < 4; i++) {
            int o4 = (lane + 64 * i) * 4;
            float4 w = *(const float4*)(r + o4);
            float4 u = *(const float4*)(w_sum + o4);
            float4 v = *(const float4*)(w_diff + o4);
            s1 += w.x*u.x + w.y*u.y + w.z*u.z + w.w*u.w;
            s2 += w.x*v.x + w.y*v.y + w.z*v.z + w.w*v.w;
        }
        #pragma unroll
        for (int m = 32; m >= 1; m >>= 1) {
            s1 += __shfl_xor(s1, m, 64);
            s2 += __shfl_xor(s2, m, 64);
        }
        if (lane == 0) { v_sum[row] = s1; v_diff[row] = s2; }
    } else {
        int t = threadIdx.x;
        if (t < 8) {
            float s = 0.f; const float* r = be2 + t * D;
            for (int k = 0; k < D; k++) s += r[k] * w_sum[k];
            c_sum[t] = s + bs[0];
        } else if (t < 16) {
            int tt = t - 8;
            float s = 0.f; const float* r = be2 + tt * D;
            for (int k = 0; k < D; k++) s += r[k] * w_diff[k];
            c_diff[tt] = s + bd[0];
        }
    }
}

// ---------------------------------------------------------------------------
// We1 [e][k][n] fp32 -> We1T [e][n][k] fp16
// ---------------------------------------------------------------------------
__global__ __launch_bounds__(256) void k_cvt(
    const float* __restrict__ We1, f16* __restrict__ We1T)
{
    __shared__ float tile[64][65];
    int b = blockIdx.x;
    int e = b >> 9, rem = b & 511;
    int kt = rem >> 5, nt = rem & 31;
    int tid = threadIdx.x;
    const float* src = We1 + ((size_t)e * D + kt * 64) * DH + nt * 64;
    #pragma unroll
    for (int i = 0; i < 16; i++) {
        int idx = tid + 256 * i;
        int kk = idx >> 6, nn = idx & 63;
        tile[kk][nn] = src[(size_t)kk * DH + nn];
    }
    __syncthreads();
    f16* dst = We1T + ((size_t)e * DH + nt * 64) * D + kt * 64;
    #pragma unroll
    for (int i = 0; i < 16; i++) {
        int idx = tid + 256 * i;
        int nn = idx >> 6, kk = idx & 63;
        dst[(size_t)nn * D + kk] = (f16)tile[kk][nn];
    }
}

// ---------------------------------------------------------------------------
// Wr1{s,d} [k][n] fp32 -> fused Wr1Tf [2048 n][1024 k] fp16
// ---------------------------------------------------------------------------
__global__ __launch_bounds__(256) void k_cvtR(
    const float* __restrict__ Wr1s, const float* __restrict__ Wr1d,
    f16* __restrict__ Wr1Tf)
{
    __shared__ float tile[64][65];
    int b = blockIdx.x;                  // 512
    int z = b >> 8, rem = b & 255;
    int kt = rem >> 4, nt2 = rem & 15;
    int tid = threadIdx.x;
    const float* W = z ? Wr1d : Wr1s;
    const float* src = W + (size_t)(kt * 64) * 1024 + nt2 * 64;
    #pragma unroll
    for (int i = 0; i < 16; i++) {
        int idx = tid + 256 * i;
        int kk = idx >> 6, nn = idx & 63;
        tile[kk][nn] = src[(size_t)kk * 1024 + nn];
    }
    __syncthreads();
    f16* dst = Wr1Tf + (size_t)(z * 1024 + nt2 * 64) * 1024 + kt * 64;
    #pragma unroll
    for (int i = 0; i < 16; i++) {
        int idx = tid + 256 * i;
        int nn = idx >> 6, kk = idx & 63;
        dst[(size_t)nn * 1024 + kk] = (f16)tile[kk][nn];
    }
}

// ---------------------------------------------------------------------------
// Fused router aux: br1f[2048], w2f[2048][8]
// ---------------------------------------------------------------------------
__global__ __launch_bounds__(256) void k_fuse(
    const float* __restrict__ br1s, const float* __restrict__ br1d,
    const float* __restrict__ Wr2s, const float* __restrict__ Wr2d,
    float* __restrict__ br1f, float* __restrict__ w2f)
{
    int tid = threadIdx.x;
    for (int n = tid; n < 2048; n += 256) {
        br1f[n] = (n < 1024) ? br1s[n] : br1d[n - 1024];
        const float* src = (n < 1024) ? (Wr2s + (size_t)n * 8)
                                      : (Wr2d + (size_t)(n - 1024) * 8);
        #pragma unroll
        for (int o = 0; o < 8; o++) w2f[(size_t)n * 8 + o] = src[o];
    }
}

// ---------------------------------------------------------------------------
// Encoder (unchanged math) + fp16 copy of x.
// ---------------------------------------------------------------------------
__global__ __launch_bounds__(256) void k_enc(
    const float* __restrict__ a, const float* __restrict__ b,
    const float* __restrict__ W_in, const float* __restrict__ b_in,
    const float* __restrict__ ln_g, const float* __restrict__ ln_b,
    float* __restrict__ x, f16* __restrict__ xh, int tok0)
{
    __shared__ float x0[64][24];
    __shared__ float red[8];
    int tid = threadIdx.x;
    float4 Wc[24];
    #pragma unroll
    for (int f = 0; f < 24; f++) Wc[f] = *(const float4*)(W_in + f * D + tid * 4);
    float4 bi = *(const float4*)(b_in + tid * 4);
    float4 gg = *(const float4*)(ln_g + tid * 4);
    float4 bb = *(const float4*)(ln_b + tid * 4);
    int base = tok0 + blockIdx.x * 64;

    for (int idx = tid; idx < 64 * 12; idx += 256) {
        int t = idx / 12, q = idx - t * 12;
        int fr = q % 6;
        float in = (q < 6) ? a[base + t] : b[base + t];
        float ang = (in * 0.39269908169872414f) * (float)(1 << fr);
        int off = (q < 6) ? 0 : 12;
        x0[t][off + fr]     = sinf(ang);
        x0[t][off + 6 + fr] = cosf(ang);
    }
    __syncthreads();

    int lane = tid & 63, wid = tid >> 6;
    for (int t = 0; t < 64; t++) {
        float4 p = bi;
        #pragma unroll
        for (int f = 0; f < 24; f++) {
            float xv = x0[t][f];
            p.x += xv * Wc[f].x; p.y += xv * Wc[f].y;
            p.z += xv * Wc[f].z; p.w += xv * Wc[f].w;
        }
        float s1 = p.x + p.y + p.z + p.w;
        float s2 = p.x*p.x + p.y*p.y + p.z*p.z + p.w*p.w;
        #pragma unroll
        for (int m = 32; m >= 1; m >>= 1) {
            s1 += __shfl_xor(s1, m, 64);
            s2 += __shfl_xor(s2, m, 64);
        }
        if (lane == 0) { red[wid] = s1; red[4 + wid] = s2; }
        __syncthreads();
        float mean = (red[0] + red[1] + red[2] + red[3]) * (1.f / 1024.f);
        float ms   = (red[4] + red[5] + red[6] + red[7]) * (1.f / 1024.f);
        float inv  = 1.f / sqrtf(ms - mean * mean + 1e-5f);
        float4 o;
        o.x = gelu_f((p.x - mean) * inv * gg.x + bb.x);
        o.y = gelu_f((p.y - mean) * inv * gg.y + bb.y);
        o.z = gelu_f((p.z - mean) * inv * gg.z + bb.z);
        o.w = gelu_f((p.w - mean) * inv * gg.w + bb.w);
        size_t row = (size_t)(blockIdx.x * 64 + t);
        *(float4*)(x + row * D + tid * 4) = o;
        f16x4 h; h[0] = (f16)o.x; h[1] = (f16)o.y; h[2] = (f16)o.z; h[3] = (f16)o.w;
        *(f16x4*)(xh + row * D + tid * 4) = h;
        __syncthreads();
    }
}

// ---------------------------------------------------------------------------
// Fused router, fp16 MFMA. C[m=n][col=token]: each lane owns a token column,
// accumulates logit partials lp[16] in-register. Block: 64 tokens x 2048 n
// (chunks of 256), K=1024. Waves: wr owns 64 n-rows (2 M-frags) x 2 N-frags.
// ---------------------------------------------------------------------------
__global__ __launch_bounds__(256) void k_rtrm(
    const f16* __restrict__ xh, const f16* __restrict__ Wr1Tf,
    const float* __restrict__ br1f, const float* __restrict__ w2f,
    float* __restrict__ logits16)
{
    __shared__ char smem[50176] __attribute__((aligned(16)));
    // [0,32768) Aw (256n x 128B) | [32768,40960) Bx (64tok x 128B)
    // [40960,49152) w2L 256x8 f32 | [49152,50176) br1L 256 f32
    float* w2L  = (float*)(smem + 40960);
    float* br1L = (float*)(smem + 49152);
    int tid = threadIdx.x;
    int bm = blockIdx.x;
    int lane = tid & 63, wid = tid >> 6;
    int hi = lane >> 5, l31 = lane & 31;
    int sg = tid >> 3, sc = tid & 7;

    const char* xb = (const char*)xh + (size_t)(bm * 64) * 2048;
    const char* wb = (const char*)Wr1Tf;

    int axor = (l31 & 7) << 4;
    int kx[4];
    #pragma unroll
    for (int ks = 0; ks < 4; ks++) kx[ks] = (ks * 32 + hi * 16) ^ axor;
    int arow[2], brow[2];
    #pragma unroll
    for (int mi = 0; mi < 2; mi++) arow[mi] = (wid * 64 + mi * 32 + l31) * 128;
    #pragma unroll
    for (int ni = 0; ni < 2; ni++) brow[ni] = 32768 + (ni * 32 + l31) * 128;

    float lp[2][16] = {};

    for (int n0 = 0; n0 < 2048; n0 += 256) {
        f32x16 acc[2][2];
        #pragma unroll
        for (int mi = 0; mi < 2; mi++)
            #pragma unroll
            for (int ni = 0; ni < 2; ni++) acc[mi][ni] = (f32x16)(0.0f);

        for (int k0 = 0; k0 < 1024; k0 += 64) {
            __syncthreads();
            #pragma unroll
            for (int i = 0; i < 8; i++) {      // Aw: 256 n-rows
                int row = i * 32 + sg;
                int4 v = *(const int4*)(wb + (size_t)(n0 + row) * 2048 + k0 * 2 + sc * 16);
                *(int4*)(smem + row * 128 + ((sc * 16) ^ ((row & 7) << 4))) = v;
            }
            #pragma unroll
            for (int i = 0; i < 2; i++) {      // Bx: 64 token-rows
                int row = i * 32 + sg;
                int4 v = *(const int4*)(xb + (size_t)row * 2048 + k0 * 2 + sc * 16);
                *(int4*)(smem + 32768 + row * 128 + ((sc * 16) ^ ((row & 7) << 4))) = v;
            }
            if (k0 == 0) {
                float4 wv0 = *(const float4*)(w2f + (size_t)(n0 + tid) * 8);
                float4 wv1 = *(const float4*)(w2f + (size_t)(n0 + tid) * 8 + 4);
                *(float4*)&w2L[tid * 8] = wv0;
                *(float4*)&w2L[tid * 8 + 4] = wv1;
                br1L[tid] = br1f[n0 + tid];
            }
            __syncthreads();
            #pragma unroll
            for (int ks = 0; ks < 4; ks++) {
                f16x8 a0 = *(const f16x8*)(smem + arow[0] + kx[ks]);
                f16x8 a1 = *(const f16x8*)(smem + arow[1] + kx[ks]);
                f16x8 b0 = *(const f16x8*)(smem + brow[0] + kx[ks]);
                f16x8 b1 = *(const f16x8*)(smem + brow[1] + kx[ks]);
                acc[0][0] = __builtin_amdgcn_mfma_f32_32x32x16_f16(a0, b0, acc[0][0], 0, 0, 0);
                acc[0][1] = __builtin_amdgcn_mfma_f32_32x32x16_f16(a0, b1, acc[0][1], 0, 0, 0);
                acc[1][0] = __builtin_amdgcn_mfma_f32_32x32x16_f16(a1, b0, acc[1][0], 0, 0, 0);
                acc[1][1] = __builtin_amdgcn_mfma_f32_32x32x16_f16(a1, b1, acc[1][1], 0, 0, 0);
            }
        }
        int lo = (n0 < 1024) ? 0 : 8;
        #pragma unroll
        for (int mi = 0; mi < 2; mi++) {
            #pragma unroll
            for (int r = 0; r < 16; r++) {
                int nl = wid * 64 + mi * 32 + (r & 3) + 8 * (r >> 2) + 4 * hi;
                float b1 = br1L[nl];
                float4 wa = *(const float4*)&w2L[nl * 8];
                float4 wc = *(const float4*)&w2L[nl * 8 + 4];
                float h0 = gelu_fast(acc[mi][0][r] + b1);
                float h1 = gelu_fast(acc[mi][1][r] + b1);
                lp[0][lo+0] += h0*wa.x; lp[0][lo+1] += h0*wa.y;
                lp[0][lo+2] += h0*wa.z; lp[0][lo+3] += h0*wa.w;
                lp[0][lo+4] += h0*wc.x; lp[0][lo+5] += h0*wc.y;
                lp[0][lo+6] += h0*wc.z; lp[0][lo+7] += h0*wc.w;
                lp[1][lo+0] += h1*wa.x; lp[1][lo+1] += h1*wa.y;
                lp[1][lo+2] += h1*wa.z; lp[1][lo+3] += h1*wa.w;
                lp[1][lo+4] += h1*wc.x; lp[1][lo+5] += h1*wc.y;
                lp[1][lo+6] += h1*wc.z; lp[1][lo+7] += h1*wc.w;
            }
        }
    }
    // reduce hi-halves (same token col), then cross-wave via LDS
    #pragma unroll
    for (int ni = 0; ni < 2; ni++)
        #pragma unroll
        for (int o = 0; o < 16; o++)
            lp[ni][o] += __shfl_xor(lp[ni][o], 32, 64);
    __syncthreads();
    float* redf = (float*)smem;   // [4][64][16]
    if (hi == 0) {
        #pragma unroll
        for (int ni = 0; ni < 2; ni++) {
            #pragma unroll
            for (int o = 0; o < 16; o++)
                redf[((wid * 64) + (ni * 32 + l31)) * 16 + o] = lp[ni][o];
        }
    }
    __syncthreads();
    if (tid < 64) {
        float L[16];
        #pragma unroll
        for (int o = 0; o < 16; o++)
            L[o] = ((redf[(0 * 64 + tid) * 16 + o]  + redf[(1 * 64 + tid) * 16 + o])
                  +  redf[(2 * 64 + tid) * 16 + o]) + redf[(3 * 64 + tid) * 16 + o];
        float* dst = logits16 + (size_t)(bm * 64 + tid) * 16;
        #pragma unroll
        for (int o = 0; o < 16; o++) dst[o] = L[o];
    }
}

// ---------------------------------------------------------------------------
// Argmax + margin. Confident -> emit tasks; marginal -> redo list.
// ctrl[0..7]=per-expert counts, ctrl[8]=redo count.
// ---------------------------------------------------------------------------
__device__ __forceinline__ void emit_tasks(int tok, int ts, int td,
                                           int* tasks, int* cnts)
{
    if (ts == td) {
        int s = atomicAdd(&cnts[ts], 1);
        tasks[ts * TSTR + s] = tok | (3 << 17);
    } else {
        int s1 = atomicAdd(&cnts[ts], 1);
        tasks[ts * TSTR + s1] = tok | (1 << 17);
        int s2 = atomicAdd(&cnts[td], 1);
        tasks[td * TSTR + s2] = tok | (2 << 17);
    }
}

__global__ __launch_bounds__(256) void k_amx2(
    const float* __restrict__ logits16, const float* __restrict__ b2s,
    const float* __restrict__ b2d, int* __restrict__ tasks,
    int* __restrict__ ctrl, int* __restrict__ redo)
{
    int i = blockIdx.x * 256 + threadIdx.x;
    const float* Lg = logits16 + (size_t)i * 16;
    float Ls[8], Ld[8];
    #pragma unroll
    for (int o = 0; o < 8; o++) { Ls[o] = Lg[o] + b2s[o]; Ld[o] = Lg[8 + o] + b2d[o]; }
    int as = 0; float m1s = Ls[0];
    #pragma unroll
    for (int o = 1; o < 8; o++) if (Ls[o] > m1s) { m1s = Ls[o]; as = o; }
    float m2s = -1e30f;
    #pragma unroll
    for (int o = 0; o < 8; o++) if (o != as && Ls[o] > m2s) m2s = Ls[o];
    int ad = 0; float m1d = Ld[0];
    #pragma unroll
    for (int o = 1; o < 8; o++) if (Ld[o] > m1d) { m1d = Ld[o]; ad = o; }
    float m2d = -1e30f;
    #pragma unroll
    for (int o = 0; o < 8; o++) if (o != ad && Ld[o] > m2d) m2d = Ld[o];

    if ((m1s - m2s) < DELTA || (m1d - m2d) < DELTA) {
        int s = atomicAdd(&ctrl[8], 1);
        if (s < RCAP) { redo[s] = i; return; }
        // capacity overflow (never expected): fall through with fp16 argmax
    }
    emit_tasks(i, as, ad, tasks, ctrl);
}

// ---------------------------------------------------------------------------
// Exact fp32 router recompute for redo tokens (gathered R1-style GEMM).
// Block (mc-stride, nt, z): 64 tokens x 128 cols of router z.
// ---------------------------------------------------------------------------
__global__ __launch_bounds__(256) void k_redo(
    const float* __restrict__ x,
    const float* __restrict__ Wr1s, const float* __restrict__ br1s,
    const float* __restrict__ Wr2s,
    const float* __restrict__ Wr1d, const float* __restrict__ br1d,
    const float* __restrict__ Wr2d,
    const int* __restrict__ redo, const int* __restrict__ ctrl,
    float* __restrict__ rlogp)
{
    int rcnt = min(ctrl[8], RCAP);
    int nt = blockIdx.y, z = blockIdx.z;
    const float* Wr1 = z ? Wr1d : Wr1s;
    const float* br1 = z ? br1d : br1s;
    const float* Wr2 = z ? Wr2d : Wr2s;
    __shared__ float As[64][72];
    __shared__ float Bs[64][132];
    __shared__ int tokR[64];
    int tid = threadIdx.x;
    int tr = tid >> 5, tc = tid & 31;

    for (int mc = blockIdx.x; mc * 64 < rcnt; mc += gridDim.x) {
        __syncthreads();
        if (tid < 64) tokR[tid] = redo[min(mc * 64 + tid, rcnt - 1)];
        __syncthreads();
        float acc[8][4] = {};
        const float* wb = Wr1 + nt * 128;
        for (int k0 = 0; k0 < D; k0 += 64) {
            __syncthreads();
            {
                int row = tid >> 2, q = tid & 3;
                const float* xr = x + (size_t)tokR[row] * D + k0;
                #pragma unroll
                for (int i = 0; i < 4; i++) {
                    int f4i = q + 4 * i;
                    float4 v = *(const float4*)(xr + f4i * 4);
                    int k = f4i * 4;
                    As[k][row] = v.x; As[k+1][row] = v.y;
                    As[k+2][row] = v.z; As[k+3][row] = v.w;
                }
            }
            {
                #pragma unroll
                for (int i = 0; i < 8; i++) {
                    int idx = tid + 256 * i;
                    int k = idx >> 5, nq = idx & 31;
                    float4 v = *(const float4*)(wb + (size_t)(k0 + k) * D + nq * 4);
                    *(float4*)&Bs[k][nq * 4] = v;
                }
            }
            __syncthreads();
            #pragma unroll 4
            for (int kk = 0; kk < 64; kk++) {
                float4 a0 = *(const float4*)&As[kk][tr * 8];
                float4 a1 = *(const float4*)&As[kk][tr * 8 + 4];
                float4 bv = *(const float4*)&Bs[kk][tc * 4];
                float ar[8] = {a0.x,a0.y,a0.z,a0.w,a1.x,a1.y,a1.z,a1.w};
                #pragma unroll
                for (int i = 0; i < 8; i++) {
                    acc[i][0] += ar[i] * bv.x;
                    acc[i][1] += ar[i] * bv.y;
                    acc[i][2] += ar[i] * bv.z;
                    acc[i][3] += ar[i] * bv.w;
                }
            }
        }
        float lp[8][8] = {};
        #pragma unroll
        for (int j = 0; j < 4; j++) {
            int col = nt * 128 + tc * 4 + j;
            float b1 = br1[col];
            float w2[8];
            #pragma unroll
            for (int o = 0; o < 8; o++) w2[o] = Wr2[col * 8 + o];
            #pragma unroll
            for (int i = 0; i < 8; i++) {
                float h = gelu_f(acc[i][j] + b1);
                #pragma unroll
                for (int o = 0; o < 8; o++) lp[i][o] += h * w2[o];
            }
        }
        #pragma unroll
        for (int m = 16; m >= 1; m >>= 1) {
            #pragma unroll
            for (int i = 0; i < 8; i++)
                #pragma unroll
                for (int o = 0; o < 8; o++)
                    lp[i][o] += __shfl_xor(lp[i][o], m, 64);
        }
        if (tc == 0) {
            #pragma unroll
            for (int i = 0; i < 8; i++) {
                int slot = mc * 64 + tr * 8 + i;
                if (slot < rcnt) {
                    float* p = rlogp + ((size_t)slot * 8 + nt) * 16 + z * 8;
                    #pragma unroll
                    for (int o = 0; o < 8; o++) p[o] = lp[i][o];
                }
            }
        }
    }
}

// ---------------------------------------------------------------------------
// Redo argmax (fixed nt order) -> emit tasks.
// ---------------------------------------------------------------------------
__global__ __launch_bounds__(256) void k_amx3(
    const float* __restrict__ rlogp, const int* __restrict__ redo,
    const float* __restrict__ b2s, const float* __restrict__ b2d,
    int* __restrict__ tasks, int* __restrict__ ctrl)
{
    int rcnt = min(ctrl[8], RCAP);
    for (int s = blockIdx.x * 256 + threadIdx.x; s < rcnt; s += gridDim.x * 256) {
        int tok = redo[s];
        float L[16] = {};
        for (int nt = 0; nt < 8; nt++) {
            const float* p = rlogp + ((size_t)s * 8 + nt) * 16;
            #pragma unroll
            for (int o = 0; o < 16; o++) L[o] += p[o];
        }
        float Ls[8], Ld[8];
        #pragma unroll
        for (int o = 0; o < 8; o++) { Ls[o] = L[o] + b2s[o]; Ld[o] = L[8 + o] + b2d[o]; }
        int ts = 0; float bv = Ls[0];
        #pragma unroll
        for (int o = 1; o < 8; o++) if (Ls[o] > bv) { bv = Ls[o]; ts = o; }
        int td = 0; bv = Ld[0];
        #pragma unroll
        for (int o = 1; o < 8; o++) if (Ld[o] > bv) { bv = Ld[o]; td = o; }
        emit_tasks(tok, ts, td, tasks, ctrl);
    }
}

// ---------------------------------------------------------------------------
// Expert GEMM, fp16 MFMA, XCD-pinned: e = blockIdx.x & 7 so all blocks of an
// expert land on one XCD (weights stay resident in its 4MB L2).
// ---------------------------------------------------------------------------
__global__ __launch_bounds__(256) void k_expm(
    const f16* __restrict__ xh, const f16* __restrict__ We1T,
    const float* __restrict__ be1, const float* __restrict__ v_sum,
    const float* __restrict__ v_diff, const float* __restrict__ c_sum,
    const float* __restrict__ c_diff, const int* __restrict__ tasks,
    const int* __restrict__ counts, float* __restrict__ out, int tok0)
{
    int e = blockIdx.x & 7;
    int cnt = counts[e];
    int r0 = (blockIdx.x >> 3) * 128;
    if (r0 >= cnt) return;

    __shared__ char smem[49152] __attribute__((aligned(16)));
    __shared__ int tokL[128];
    __shared__ int flgL[128];
    __shared__ float redS[2][128];
    __shared__ float redD[2][128];

    int tid = threadIdx.x;
    if (tid < 128) {
        int idx = r0 + tid;
        int tv = tasks[e * TSTR + min(idx, cnt - 1)];
        tokL[tid] = tv & 0xFFFF;
        flgL[tid] = (idx < cnt) ? ((tv >> 17) & 3) : 0;
    }
    __syncthreads();

    int lane = tid & 63;
    int wid  = tid >> 6;
    int wr = wid >> 1, wc = wid & 1;
    int hi = lane >> 5, l31 = lane & 31;

    int sg = tid >> 3;
    int sc = tid & 7;
    int stoff = sg * 128 + ((sc * 16) ^ ((sg & 7) << 4));
    size_t asrc_off[4];
    #pragma unroll
    for (int i = 0; i < 4; i++)
        asrc_off[i] = (size_t)tokL[i * 32 + sg] * (D * 2) + sc * 16;
    const char* xh_b   = (const char*)xh;
    const char* we1t_e = (const char*)(We1T + (size_t)e * DH * D);
    size_t bs_off = (size_t)sg * (D * 2) + sc * 16;

    int axor = (l31 & 7) << 4;
    int kx[4];
    #pragma unroll
    for (int ks = 0; ks < 4; ks++) kx[ks] = (ks * 32 + hi * 16) ^ axor;
    int arow[2], nrow[4];
    #pragma unroll
    for (int mi = 0; mi < 2; mi++) arow[mi] = (wr * 64 + mi * 32 + l31) * 128;
    #pragma unroll
    for (int ni = 0; ni < 4; ni++) nrow[ni] = 16384 + (wc * 128 + ni * 32 + l31) * 128;

    float ss[2][16] = {}, sd[2][16] = {};

    for (int n0 = 0; n0 < DH; n0 += 256) {
        f32x16 acc[2][4];
        #pragma unroll
        for (int mi = 0; mi < 2; mi++)
            #pragma unroll
            for (int ni = 0; ni < 4; ni++)
                acc[mi][ni] = (f32x16)(0.0f);

        const char* bsrc0 = we1t_e + (size_t)n0 * (D * 2) + bs_off;

        for (int k0 = 0; k0 < D; k0 += 64) {
            __syncthreads();
            #pragma unroll
            for (int i = 0; i < 4; i++) {
                int4 v = *(const int4*)(xh_b + asrc_off[i] + k0 * 2);
                *(int4*)(smem + i * 4096 + stoff) = v;
            }
            #pragma unroll
            for (int i = 0; i < 8; i++) {
                int4 v = *(const int4*)(bsrc0 + (size_t)i * 32 * (D * 2) + k0 * 2);
                *(int4*)(smem + 16384 + i * 4096 + stoff) = v;
            }
            __syncthreads();
            #pragma unroll
            for (int ks = 0; ks < 4; ks++) {
                f16x8 a0 = *(const f16x8*)(smem + arow[0] + kx[ks]);
                f16x8 a1 = *(const f16x8*)(smem + arow[1] + kx[ks]);
                #pragma unroll
                for (int ni = 0; ni < 4; ni++) {
                    f16x8 bf = *(const f16x8*)(smem + nrow[ni] + kx[ks]);
                    acc[0][ni] = __builtin_amdgcn_mfma_f32_32x32x16_f16(a0, bf, acc[0][ni], 0, 0, 0);
                    acc[1][ni] = __builtin_amdgcn_mfma_f32_32x32x16_f16(a1, bf, acc[1][ni], 0, 0, 0);
                }
            }
        }
        #pragma unroll
        for (int ni = 0; ni < 4; ni++) {
            int col = n0 + wc * 128 + ni * 32 + l31;
            float b1 = be1[e * DH + col];
            float vs = v_sum[e * DH + col];
            float vd = v_diff[e * DH + col];
            #pragma unroll
            for (int mi = 0; mi < 2; mi++) {
                #pragma unroll
                for (int r = 0; r < 16; r++) {
                    float h = gelu_fast(acc[mi][ni][r] + b1);
                    ss[mi][r] += h * vs;
                    sd[mi][r] += h * vd;
                }
            }
        }
    }

    #pragma unroll
    for (int m = 16; m >= 1; m >>= 1) {
        #pragma unroll
        for (int mi = 0; mi < 2; mi++)
            #pragma unroll
            for (int r = 0; r < 16; r++) {
                ss[mi][r] += __shfl_xor(ss[mi][r], m, 64);
                sd[mi][r] += __shfl_xor(sd[mi][r], m, 64);
            }
    }
    if (l31 == 0) {
        #pragma unroll
        for (int mi = 0; mi < 2; mi++)
            #pragma unroll
            for (int r = 0; r < 16; r++) {
                int row = wr * 64 + mi * 32 + (r & 3) + 8 * (r >> 2) + 4 * hi;
                redS[wc][row] = ss[mi][r];
                redD[wc][row] = sd[mi][r];
            }
    }
    __syncthreads();
    if (tid < 128) {
        float s = (redS[0][tid] + redS[1][tid]) + c_sum[e];
        float d = (redD[0][tid] + redD[1][tid]) + c_diff[e];
        int fl = flgL[tid];
        int gt = tok0 + tokL[tid];
        if (fl & 1) out[gt]      = s;
        if (fl & 2) out[BT + gt] = d;
    }
}

// ---------------------------------------------------------------------------
extern "C" void kernel_launch(void* const* d_in, const int* in_sizes, int n_in,
                              void* d_out, int out_size, void* d_ws, size_t ws_size,
                              hipStream_t stream)
{
    const float* a      = (const float*)d_in[0];
    const float* b      = (const float*)d_in[1];
    const float* W_in   = (const float*)d_in[2];
    const float* b_in   = (const float*)d_in[3];
    const float* ln_g   = (const float*)d_in[4];
    const float* ln_b   = (const float*)d_in[5];
    const float* Wr1s   = (const float*)d_in[6];
    const float* br1s   = (const float*)d_in[7];
    const float* Wr2s   = (const float*)d_in[8];
    const float* br2s   = (const float*)d_in[9];
    const float* Wr1d   = (const float*)d_in[10];
    const float* br1d   = (const float*)d_in[11];
    const float* Wr2d   = (const float*)d_in[12];
    const float* br2d   = (const float*)d_in[13];
    const float* We1    = (const float*)d_in[14];
    const float* be1    = (const float*)d_in[15];
    const float* We2    = (const float*)d_in[16];
    const float* be2    = (const float*)d_in[17];
    const float* w_sum  = (const float*)d_in[18];
    const float* bs     = (const float*)d_in[19];
    const float* w_diff = (const float*)d_in[20];
    const float* bd     = (const float*)d_in[21];
    float* out = (float*)d_out;

    char* w = (char*)d_ws;
    size_t off = 0;
    auto alloc = [&](size_t bytes) -> char* {
        char* p = w + off;
        off = (off + bytes + 255) & ~(size_t)255;
        return p;
    };
    float* v_sum   = (float*)alloc((size_t)NT * DH * 4);
    float* v_diff  = (float*)alloc((size_t)NT * DH * 4);
    float* c_sum   = (float*)alloc(64);
    float* c_diff  = (float*)alloc(64);
    float* x       = (float*)alloc((size_t)QN * D * 4);
    f16*   xh      = (f16*)alloc((size_t)QN * D * 2);
    float* logits16= (float*)alloc((size_t)QN * 16 * 4);
    float* rlogp   = (float*)alloc((size_t)RCAP * 8 * 16 * 4);
    int*   redo    = (int*)alloc((size_t)QN * 4);
    int*   tasks   = (int*)alloc((size_t)NT * TSTR * 4);
    int*   ctrl    = (int*)alloc(64);
    f16*   We1T    = (f16*)alloc((size_t)NT * DH * D * 2);
    f16*   Wr1Tf   = (f16*)alloc((size_t)2048 * 1024 * 2);
    float* br1f    = (float*)alloc((size_t)2048 * 4);
    float* w2f     = (float*)alloc((size_t)2048 * 8 * 4);
    if (off > ws_size) {
        hipMemsetAsync(d_out, 0, (size_t)out_size * 4, stream);
        return;
    }

    k_cvt <<<dim3(4096), dim3(256), 0, stream>>>(We1, We1T);
    k_cvtR<<<dim3(512),  dim3(256), 0, stream>>>(Wr1s, Wr1d, Wr1Tf);
    k_fuse<<<dim3(1),    dim3(256), 0, stream>>>(br1s, br1d, Wr2s, Wr2d, br1f, w2f);
    k_prev<<<dim3(4097), dim3(256), 0, stream>>>(We2, w_sum, w_diff, be2, bs, bd,
                                                 v_sum, v_diff, c_sum, c_diff);
    for (int q = 0; q < NPASS; q++) {
        int tok0 = q * QN;
        k_enc<<<dim3(QN / 64), dim3(256), 0, stream>>>(a, b, W_in, b_in, ln_g, ln_b, x, xh, tok0);
        k_rtrm<<<dim3(QN / 64), dim3(256), 0, stream>>>(xh, Wr1Tf, br1f, w2f, logits16);
        hipMemsetAsync(ctrl, 0, 64, stream);
        k_amx2<<<dim3(QN / 256), dim3(256), 0, stream>>>(logits16, br2s, br2d, tasks, ctrl, redo);
        k_redo<<<dim3(32, 8, 2), dim3(256), 0, stream>>>(x, Wr1s, br1s, Wr2s, Wr1d, br1d, Wr2d,
                                                         redo, ctrl, rlogp);
        k_amx3<<<dim3(16), dim3(256), 0, stream>>>(rlogp, redo, br2s, br2d, tasks, ctrl);
        k_expm<<<dim3(2048), dim3(256), 0, stream>>>(xh, We1T, be1, v_sum, v_diff,
                                                     c_sum, c_diff, tasks, ctrl, out, tok0);
    }
}

// Round 4
// 4194.853 us; speedup vs baseline: 3.7484x; 1.4047x over previous
//
#include <hip/hip_runtime.h>
#include <math.h>

// ============================================================================
// PureTriXButterfly — R4.
// - k_rtrm: re-tiled (64tok x 256n x K=1024 per block, 2048 blocks,
//   ntile=bid&7 XCD-pinned weights) -> partial logits part[tok][8][8];
//   fixed-order sum in k_amx2. Was 1 block/CU latency-bound (551us).
// - k_expm: 2 N-chunk split x 32 rt-stride -> 64 blocks/expert (was 30);
//   token-indexed partials ppS/ppD (unique writer), summed in k_fin.
// - Routing chain semantics unchanged (fp16 logits + margin redo, fp32 exact
//   recompute for marginal tokens; passed R3 absmax 7.8e-3).
// ============================================================================

#define BT 65536
#define QN 16384
#define NPASS 4
#define D 1024
#define NT 8
#define DH 2048
#define TSTR (2*QN)
#define RCAP 4096
#define DELTA 0.025f

typedef _Float16 f16;
typedef _Float16 f16x8 __attribute__((ext_vector_type(8)));
typedef _Float16 f16x4 __attribute__((ext_vector_type(4)));
typedef float f32x16 __attribute__((ext_vector_type(16)));

__device__ __forceinline__ float gelu_f(float v) {
    return 0.5f * v * (1.0f + erff(v * 0.70710678118654752440f));
}

// fast exact-GELU via A&S 7.1.26 erf (|eps| <= 1.5e-7)
__device__ __forceinline__ float gelu_fast(float x) {
    float ax = fabsf(x) * 0.70710678118654752440f;
    float t = __builtin_amdgcn_rcpf(1.0f + 0.3275911f * ax);
    float p = t * (0.254829592f + t * (-0.284496736f + t * (1.421413741f +
              t * (-1.453152027f + t * 1.061405429f))));
    float er = 1.0f - p * __expf(-ax * ax);
    er = copysignf(er, x);
    return 0.5f * x * (1.0f + er);
}

// ---------------------------------------------------------------------------
__global__ __launch_bounds__(256) void k_prev(
    const float* __restrict__ We2, const float* __restrict__ w_sum,
    const float* __restrict__ w_diff, const float* __restrict__ be2,
    const float* __restrict__ bs, const float* __restrict__ bd,
    float* __restrict__ v_sum, float* __restrict__ v_diff,
    float* __restrict__ c_sum, float* __restrict__ c_diff)
{
    int bid = blockIdx.x;
    if (bid < 4096) {
        int row  = bid * 4 + (threadIdx.x >> 6);
        int lane = threadIdx.x & 63;
        const float* r = We2 + (size_t)row * D;
        float s1 = 0.f, s2 = 0.f;
        #pragma unroll
        for (int i = 0; i < 4; i++) {
            int o4 = (lane + 64 * i) * 4;
            float4 w = *(const float4*)(r + o4);
            float4 u = *(const float4*)(w_sum + o4);
            float4 v = *(const float4*)(w_diff + o4);
            s1 += w.x*u.x + w.y*u.y + w.z*u.z + w.w*u.w;
            s2 += w.x*v.x + w.y*v.y + w.z*v.z + w.w*v.w;
        }
        #pragma unroll
        for (int m = 32; m >= 1; m >>= 1) {
            s1 += __shfl_xor(s1, m, 64);
            s2 += __shfl_xor(s2, m, 64);
        }
        if (lane == 0) { v_sum[row] = s1; v_diff[row] = s2; }
    } else {
        int t = threadIdx.x;
        if (t < 8) {
            float s = 0.f; const float* r = be2 + t * D;
            for (int k = 0; k < D; k++) s += r[k] * w_sum[k];
            c_sum[t] = s + bs[0];
        } else if (t < 16) {
            int tt = t - 8;
            float s = 0.f; const float* r = be2 + tt * D;
            for (int k = 0; k < D; k++) s += r[k] * w_diff[k];
            c_diff[tt] = s + bd[0];
        }
    }
}

// ---------------------------------------------------------------------------
__global__ __launch_bounds__(256) void k_cvt(
    const float* __restrict__ We1, f16* __restrict__ We1T)
{
    __shared__ float tile[64][65];
    int b = blockIdx.x;
    int e = b >> 9, rem = b & 511;
    int kt = rem >> 5, nt = rem & 31;
    int tid = threadIdx.x;
    const float* src = We1 + ((size_t)e * D + kt * 64) * DH + nt * 64;
    #pragma unroll
    for (int i = 0; i < 16; i++) {
        int idx = tid + 256 * i;
        int kk = idx >> 6, nn = idx & 63;
        tile[kk][nn] = src[(size_t)kk * DH + nn];
    }
    __syncthreads();
    f16* dst = We1T + ((size_t)e * DH + nt * 64) * D + kt * 64;
    #pragma unroll
    for (int i = 0; i < 16; i++) {
        int idx = tid + 256 * i;
        int nn = idx >> 6, kk = idx & 63;
        dst[(size_t)nn * D + kk] = (f16)tile[kk][nn];
    }
}

// ---------------------------------------------------------------------------
__global__ __launch_bounds__(256) void k_cvtR(
    const float* __restrict__ Wr1s, const float* __restrict__ Wr1d,
    f16* __restrict__ Wr1Tf)
{
    __shared__ float tile[64][65];
    int b = blockIdx.x;                  // 512
    int z = b >> 8, rem = b & 255;
    int kt = rem >> 4, nt2 = rem & 15;
    int tid = threadIdx.x;
    const float* W = z ? Wr1d : Wr1s;
    const float* src = W + (size_t)(kt * 64) * 1024 + nt2 * 64;
    #pragma unroll
    for (int i = 0; i < 16; i++) {
        int idx = tid + 256 * i;
        int kk = idx >> 6, nn = idx & 63;
        tile[kk][nn] = src[(size_t)kk * 1024 + nn];
    }
    __syncthreads();
    f16* dst = Wr1Tf + (size_t)(z * 1024 + nt2 * 64) * 1024 + kt * 64;
    #pragma unroll
    for (int i = 0; i < 16; i++) {
        int idx = tid + 256 * i;
        int nn = idx >> 6, kk = idx & 63;
        dst[(size_t)nn * 1024 + kk] = (f16)tile[kk][nn];
    }
}

// ---------------------------------------------------------------------------
__global__ __launch_bounds__(256) void k_fuse(
    const float* __restrict__ br1s, const float* __restrict__ br1d,
    const float* __restrict__ Wr2s, const float* __restrict__ Wr2d,
    float* __restrict__ br1f, float* __restrict__ w2f)
{
    int tid = threadIdx.x;
    for (int n = tid; n < 2048; n += 256) {
        br1f[n] = (n < 1024) ? br1s[n] : br1d[n - 1024];
        const float* src = (n < 1024) ? (Wr2s + (size_t)n * 8)
                                      : (Wr2d + (size_t)(n - 1024) * 8);
        #pragma unroll
        for (int o = 0; o < 8; o++) w2f[(size_t)n * 8 + o] = src[o];
    }
}

// ---------------------------------------------------------------------------
__global__ __launch_bounds__(256) void k_enc(
    const float* __restrict__ a, const float* __restrict__ b,
    const float* __restrict__ W_in, const float* __restrict__ b_in,
    const float* __restrict__ ln_g, const float* __restrict__ ln_b,
    float* __restrict__ x, f16* __restrict__ xh, int tok0)
{
    __shared__ float x0[64][24];
    __shared__ float red[8];
    int tid = threadIdx.x;
    float4 Wc[24];
    #pragma unroll
    for (int f = 0; f < 24; f++) Wc[f] = *(const float4*)(W_in + f * D + tid * 4);
    float4 bi = *(const float4*)(b_in + tid * 4);
    float4 gg = *(const float4*)(ln_g + tid * 4);
    float4 bb = *(const float4*)(ln_b + tid * 4);
    int base = tok0 + blockIdx.x * 64;

    for (int idx = tid; idx < 64 * 12; idx += 256) {
        int t = idx / 12, q = idx - t * 12;
        int fr = q % 6;
        float in = (q < 6) ? a[base + t] : b[base + t];
        float ang = (in * 0.39269908169872414f) * (float)(1 << fr);
        int off = (q < 6) ? 0 : 12;
        x0[t][off + fr]     = sinf(ang);
        x0[t][off + 6 + fr] = cosf(ang);
    }
    __syncthreads();

    int lane = tid & 63, wid = tid >> 6;
    for (int t = 0; t < 64; t++) {
        float4 p = bi;
        #pragma unroll
        for (int f = 0; f < 24; f++) {
            float xv = x0[t][f];
            p.x += xv * Wc[f].x; p.y += xv * Wc[f].y;
            p.z += xv * Wc[f].z; p.w += xv * Wc[f].w;
        }
        float s1 = p.x + p.y + p.z + p.w;
        float s2 = p.x*p.x + p.y*p.y + p.z*p.z + p.w*p.w;
        #pragma unroll
        for (int m = 32; m >= 1; m >>= 1) {
            s1 += __shfl_xor(s1, m, 64);
            s2 += __shfl_xor(s2, m, 64);
        }
        if (lane == 0) { red[wid] = s1; red[4 + wid] = s2; }
        __syncthreads();
        float mean = (red[0] + red[1] + red[2] + red[3]) * (1.f / 1024.f);
        float ms   = (red[4] + red[5] + red[6] + red[7]) * (1.f / 1024.f);
        float inv  = 1.f / sqrtf(ms - mean * mean + 1e-5f);
        float4 o;
        o.x = gelu_f((p.x - mean) * inv * gg.x + bb.x);
        o.y = gelu_f((p.y - mean) * inv * gg.y + bb.y);
        o.z = gelu_f((p.z - mean) * inv * gg.z + bb.z);
        o.w = gelu_f((p.w - mean) * inv * gg.w + bb.w);
        size_t row = (size_t)(blockIdx.x * 64 + t);
        *(float4*)(x + row * D + tid * 4) = o;
        f16x4 h; h[0] = (f16)o.x; h[1] = (f16)o.y; h[2] = (f16)o.z; h[3] = (f16)o.w;
        *(f16x4*)(xh + row * D + tid * 4) = h;
        __syncthreads();
    }
}

// ---------------------------------------------------------------------------
// Fused router, fp16 MFMA, re-tiled. Block = 64 tokens x 256 n, K=1024.
// ntile = bid&7 (XCD-pinned: each XCD's 0.5MB weight slice stays in its L2).
// C[n][token] orientation: lane owns a token column; gelu+w2 partials
// accumulate in-register -> part[token][ntile][8]. 4 blocks/CU (40KB LDS).
// ---------------------------------------------------------------------------
__global__ __launch_bounds__(256) void k_rtrm(
    const f16* __restrict__ xh, const f16* __restrict__ Wr1Tf,
    const float* __restrict__ br1f, const float* __restrict__ w2f,
    float* __restrict__ part)
{
    __shared__ char smem[40960] __attribute__((aligned(16)));
    // [0,32768) Aw: 256 n-rows x 128B | [32768,40960) Bx: 64 tok-rows x 128B
    int bid = blockIdx.x;
    int ntile = bid & 7;            // n range [ntile*256, +256)
    int ttile = bid >> 3;           // token range [ttile*64, +64)
    int tid = threadIdx.x;
    int lane = tid & 63, wid = tid >> 6;
    int hi = lane >> 5, l31 = lane & 31;
    int sg = tid >> 3, sc = tid & 7;

    const char* xb = (const char*)xh + (size_t)(ttile * 64) * 2048;
    const char* wb = (const char*)Wr1Tf + (size_t)(ntile * 256) * 2048;

    int axor = (l31 & 7) << 4;
    int kx[4];
    #pragma unroll
    for (int ks = 0; ks < 4; ks++) kx[ks] = (ks * 32 + hi * 16) ^ axor;
    int arow[2], brow[2];
    #pragma unroll
    for (int mi = 0; mi < 2; mi++) arow[mi] = (wid * 64 + mi * 32 + l31) * 128;
    #pragma unroll
    for (int ni = 0; ni < 2; ni++) brow[ni] = 32768 + (ni * 32 + l31) * 128;

    f32x16 acc[2][2];
    #pragma unroll
    for (int mi = 0; mi < 2; mi++)
        #pragma unroll
        for (int ni = 0; ni < 2; ni++) acc[mi][ni] = (f32x16)(0.0f);

    int swz = (sc * 16) ^ ((sg & 7) << 4);
    for (int k0 = 0; k0 < 1024; k0 += 64) {
        __syncthreads();
        #pragma unroll
        for (int i = 0; i < 8; i++) {          // Aw: 256 n-rows
            int row = i * 32 + sg;
            int4 v = *(const int4*)(wb + (size_t)row * 2048 + k0 * 2 + sc * 16);
            *(int4*)(smem + row * 128 + swz) = v;
        }
        #pragma unroll
        for (int i = 0; i < 2; i++) {          // Bx: 64 token-rows
            int row = i * 32 + sg;
            int4 v = *(const int4*)(xb + (size_t)row * 2048 + k0 * 2 + sc * 16);
            *(int4*)(smem + 32768 + row * 128 + swz) = v;
        }
        __syncthreads();
        #pragma unroll
        for (int ks = 0; ks < 4; ks++) {
            f16x8 a0 = *(const f16x8*)(smem + arow[0] + kx[ks]);
            f16x8 a1 = *(const f16x8*)(smem + arow[1] + kx[ks]);
            f16x8 b0 = *(const f16x8*)(smem + brow[0] + kx[ks]);
            f16x8 b1 = *(const f16x8*)(smem + brow[1] + kx[ks]);
            acc[0][0] = __builtin_amdgcn_mfma_f32_32x32x16_f16(a0, b0, acc[0][0], 0, 0, 0);
            acc[0][1] = __builtin_amdgcn_mfma_f32_32x32x16_f16(a0, b1, acc[0][1], 0, 0, 0);
            acc[1][0] = __builtin_amdgcn_mfma_f32_32x32x16_f16(a1, b0, acc[1][0], 0, 0, 0);
            acc[1][1] = __builtin_amdgcn_mfma_f32_32x32x16_f16(a1, b1, acc[1][1], 0, 0, 0);
        }
    }

    // epilogue: gelu + w2 partials, in-register per token column
    float lp[2][8] = {};
    #pragma unroll
    for (int mi = 0; mi < 2; mi++) {
        #pragma unroll
        for (int r = 0; r < 16; r++) {
            int nl = wid * 64 + mi * 32 + (r & 3) + 8 * (r >> 2) + 4 * hi;
            int gn = ntile * 256 + nl;
            float b1 = br1f[gn];
            float4 wa = *(const float4*)(w2f + (size_t)gn * 8);
            float4 wc = *(const float4*)(w2f + (size_t)gn * 8 + 4);
            float h0 = gelu_fast(acc[mi][0][r] + b1);
            float h1 = gelu_fast(acc[mi][1][r] + b1);
            lp[0][0] += h0*wa.x; lp[0][1] += h0*wa.y;
            lp[0][2] += h0*wa.z; lp[0][3] += h0*wa.w;
            lp[0][4] += h0*wc.x; lp[0][5] += h0*wc.y;
            lp[0][6] += h0*wc.z; lp[0][7] += h0*wc.w;
            lp[1][0] += h1*wa.x; lp[1][1] += h1*wa.y;
            lp[1][2] += h1*wa.z; lp[1][3] += h1*wa.w;
            lp[1][4] += h1*wc.x; lp[1][5] += h1*wc.y;
            lp[1][6] += h1*wc.z; lp[1][7] += h1*wc.w;
        }
    }
    // hi-half fold (same token column)
    #pragma unroll
    for (int ni = 0; ni < 2; ni++)
        #pragma unroll
        for (int o = 0; o < 8; o++)
            lp[ni][o] += __shfl_xor(lp[ni][o], 32, 64);
    __syncthreads();
    float* redf = (float*)smem;       // [4 wave][64 tok][8]
    if (hi == 0) {
        #pragma unroll
        for (int ni = 0; ni < 2; ni++)
            #pragma unroll
            for (int o = 0; o < 8; o++)
                redf[(wid * 64 + ni * 32 + l31) * 8 + o] = lp[ni][o];
    }
    __syncthreads();
    for (int idx = tid; idx < 512; idx += 256) {
        int tok = idx >> 3, o = idx & 7;
        float s = ((redf[(0 * 64 + tok) * 8 + o]  + redf[(1 * 64 + tok) * 8 + o])
                 +  redf[(2 * 64 + tok) * 8 + o]) + redf[(3 * 64 + tok) * 8 + o];
        part[((size_t)(ttile * 64 + tok) * 8 + ntile) * 8 + o] = s;
    }
}

// ---------------------------------------------------------------------------
// Argmax + margin from part[tok][8][8] (fixed ntile order). ctrl[0..7]=counts,
// ctrl[8]=redo count.
// ---------------------------------------------------------------------------
__device__ __forceinline__ void emit_tasks(int tok, int ts, int td,
                                           int* tasks, int* cnts)
{
    if (ts == td) {
        int s = atomicAdd(&cnts[ts], 1);
        tasks[ts * TSTR + s] = tok | (3 << 17);
    } else {
        int s1 = atomicAdd(&cnts[ts], 1);
        tasks[ts * TSTR + s1] = tok | (1 << 17);
        int s2 = atomicAdd(&cnts[td], 1);
        tasks[td * TSTR + s2] = tok | (2 << 17);
    }
}

__global__ __launch_bounds__(256) void k_amx2(
    const float* __restrict__ part, const float* __restrict__ b2s,
    const float* __restrict__ b2d, int* __restrict__ tasks,
    int* __restrict__ ctrl, int* __restrict__ redo)
{
    int i = blockIdx.x * 256 + threadIdx.x;
    const float* p = part + (size_t)i * 64;
    float Ls[8], Ld[8];
    #pragma unroll
    for (int o = 0; o < 8; o++) { Ls[o] = b2s[o]; Ld[o] = b2d[o]; }
    #pragma unroll
    for (int nt = 0; nt < 4; nt++)
        #pragma unroll
        for (int o = 0; o < 8; o++) Ls[o] += p[nt * 8 + o];
    #pragma unroll
    for (int nt = 4; nt < 8; nt++)
        #pragma unroll
        for (int o = 0; o < 8; o++) Ld[o] += p[nt * 8 + o];

    int as = 0; float m1s = Ls[0];
    #pragma unroll
    for (int o = 1; o < 8; o++) if (Ls[o] > m1s) { m1s = Ls[o]; as = o; }
    float m2s = -1e30f;
    #pragma unroll
    for (int o = 0; o < 8; o++) if (o != as && Ls[o] > m2s) m2s = Ls[o];
    int ad = 0; float m1d = Ld[0];
    #pragma unroll
    for (int o = 1; o < 8; o++) if (Ld[o] > m1d) { m1d = Ld[o]; ad = o; }
    float m2d = -1e30f;
    #pragma unroll
    for (int o = 0; o < 8; o++) if (o != ad && Ld[o] > m2d) m2d = Ld[o];

    if ((m1s - m2s) < DELTA || (m1d - m2d) < DELTA) {
        int s = atomicAdd(&ctrl[8], 1);
        if (s < RCAP) { redo[s] = i; return; }
    }
    emit_tasks(i, as, ad, tasks, ctrl);
}

// ---------------------------------------------------------------------------
// Exact fp32 router recompute for redo tokens.
// ---------------------------------------------------------------------------
__global__ __launch_bounds__(256) void k_redo(
    const float* __restrict__ x,
    const float* __restrict__ Wr1s, const float* __restrict__ br1s,
    const float* __restrict__ Wr2s,
    const float* __restrict__ Wr1d, const float* __restrict__ br1d,
    const float* __restrict__ Wr2d,
    const int* __restrict__ redo, const int* __restrict__ ctrl,
    float* __restrict__ rlogp)
{
    int rcnt = min(ctrl[8], RCAP);
    int nt = blockIdx.y, z = blockIdx.z;
    const float* Wr1 = z ? Wr1d : Wr1s;
    const float* br1 = z ? br1d : br1s;
    const float* Wr2 = z ? Wr2d : Wr2s;
    __shared__ float As[64][72];
    __shared__ float Bs[64][132];
    __shared__ int tokR[64];
    int tid = threadIdx.x;
    int tr = tid >> 5, tc = tid & 31;

    for (int mc = blockIdx.x; mc * 64 < rcnt; mc += gridDim.x) {
        __syncthreads();
        if (tid < 64) tokR[tid] = redo[min(mc * 64 + tid, rcnt - 1)];
        __syncthreads();
        float acc[8][4] = {};
        const float* wb = Wr1 + nt * 128;
        for (int k0 = 0; k0 < D; k0 += 64) {
            __syncthreads();
            {
                int row = tid >> 2, q = tid & 3;
                const float* xr = x + (size_t)tokR[row] * D + k0;
                #pragma unroll
                for (int i = 0; i < 4; i++) {
                    int f4i = q + 4 * i;
                    float4 v = *(const float4*)(xr + f4i * 4);
                    int k = f4i * 4;
                    As[k][row] = v.x; As[k+1][row] = v.y;
                    As[k+2][row] = v.z; As[k+3][row] = v.w;
                }
            }
            {
                #pragma unroll
                for (int i = 0; i < 8; i++) {
                    int idx = tid + 256 * i;
                    int k = idx >> 5, nq = idx & 31;
                    float4 v = *(const float4*)(wb + (size_t)(k0 + k) * D + nq * 4);
                    *(float4*)&Bs[k][nq * 4] = v;
                }
            }
            __syncthreads();
            #pragma unroll 4
            for (int kk = 0; kk < 64; kk++) {
                float4 a0 = *(const float4*)&As[kk][tr * 8];
                float4 a1 = *(const float4*)&As[kk][tr * 8 + 4];
                float4 bv = *(const float4*)&Bs[kk][tc * 4];
                float ar[8] = {a0.x,a0.y,a0.z,a0.w,a1.x,a1.y,a1.z,a1.w};
                #pragma unroll
                for (int i = 0; i < 8; i++) {
                    acc[i][0] += ar[i] * bv.x;
                    acc[i][1] += ar[i] * bv.y;
                    acc[i][2] += ar[i] * bv.z;
                    acc[i][3] += ar[i] * bv.w;
                }
            }
        }
        float lp[8][8] = {};
        #pragma unroll
        for (int j = 0; j < 4; j++) {
            int col = nt * 128 + tc * 4 + j;
            float b1 = br1[col];
            float w2[8];
            #pragma unroll
            for (int o = 0; o < 8; o++) w2[o] = Wr2[col * 8 + o];
            #pragma unroll
            for (int i = 0; i < 8; i++) {
                float h = gelu_f(acc[i][j] + b1);
                #pragma unroll
                for (int o = 0; o < 8; o++) lp[i][o] += h * w2[o];
            }
        }
        #pragma unroll
        for (int m = 16; m >= 1; m >>= 1) {
            #pragma unroll
            for (int i = 0; i < 8; i++)
                #pragma unroll
                for (int o = 0; o < 8; o++)
                    lp[i][o] += __shfl_xor(lp[i][o], m, 64);
        }
        if (tc == 0) {
            #pragma unroll
            for (int i = 0; i < 8; i++) {
                int slot = mc * 64 + tr * 8 + i;
                if (slot < rcnt) {
                    float* p = rlogp + ((size_t)slot * 8 + nt) * 16 + z * 8;
                    #pragma unroll
                    for (int o = 0; o < 8; o++) p[o] = lp[i][o];
                }
            }
        }
    }
}

// ---------------------------------------------------------------------------
__global__ __launch_bounds__(256) void k_amx3(
    const float* __restrict__ rlogp, const int* __restrict__ redo,
    const float* __restrict__ b2s, const float* __restrict__ b2d,
    int* __restrict__ tasks, int* __restrict__ ctrl)
{
    int rcnt = min(ctrl[8], RCAP);
    for (int s = blockIdx.x * 256 + threadIdx.x; s < rcnt; s += gridDim.x * 256) {
        int tok = redo[s];
        float L[16] = {};
        for (int nt = 0; nt < 8; nt++) {
            const float* p = rlogp + ((size_t)s * 8 + nt) * 16;
            #pragma unroll
            for (int o = 0; o < 16; o++) L[o] += p[o];
        }
        float Ls[8], Ld[8];
        #pragma unroll
        for (int o = 0; o < 8; o++) { Ls[o] = L[o] + b2s[o]; Ld[o] = L[8 + o] + b2d[o]; }
        int ts = 0; float bv = Ls[0];
        #pragma unroll
        for (int o = 1; o < 8; o++) if (Ls[o] > bv) { bv = Ls[o]; ts = o; }
        int td = 0; bv = Ld[0];
        #pragma unroll
        for (int o = 1; o < 8; o++) if (Ld[o] > bv) { bv = Ld[o]; td = o; }
        emit_tasks(tok, ts, td, tasks, ctrl);
    }
}

// ---------------------------------------------------------------------------
// Expert GEMM, fp16 MFMA, XCD-pinned + N-chunk split.
// bid: e = bid&7, ch = (bid>>3)&1 (n half), rt0 = bid>>4 (stride 32).
// Writes token-indexed chunk partials ppS/ppD[ch][token] (unique writer).
// ---------------------------------------------------------------------------
__global__ __launch_bounds__(256) void k_expm(
    const f16* __restrict__ xh, const f16* __restrict__ We1T,
    const float* __restrict__ be1, const float* __restrict__ v_sum,
    const float* __restrict__ v_diff, const float* __restrict__ c_sum,
    const float* __restrict__ c_diff, const int* __restrict__ tasks,
    const int* __restrict__ counts,
    float* __restrict__ ppS, float* __restrict__ ppD)
{
    int e  = blockIdx.x & 7;
    int ch = (blockIdx.x >> 3) & 1;
    int rt0 = blockIdx.x >> 4;          // 0..31
    int cnt = counts[e];

    __shared__ char smem[49152] __attribute__((aligned(16)));
    __shared__ int tokL[128];
    __shared__ int flgL[128];
    __shared__ float redS[2][128];
    __shared__ float redD[2][128];

    int tid = threadIdx.x;
    int lane = tid & 63;
    int wid  = tid >> 6;
    int wr = wid >> 1, wc = wid & 1;
    int hi = lane >> 5, l31 = lane & 31;
    int sg = tid >> 3, sc = tid & 7;
    int stoff = sg * 128 + ((sc * 16) ^ ((sg & 7) << 4));

    const char* xh_b   = (const char*)xh;
    const char* we1t_e = (const char*)(We1T + (size_t)e * DH * D);
    size_t bs_off = (size_t)sg * (D * 2) + sc * 16;

    int axor = (l31 & 7) << 4;
    int kx[4];
    #pragma unroll
    for (int ks = 0; ks < 4; ks++) kx[ks] = (ks * 32 + hi * 16) ^ axor;
    int arow[2], nrow[4];
    #pragma unroll
    for (int mi = 0; mi < 2; mi++) arow[mi] = (wr * 64 + mi * 32 + l31) * 128;
    #pragma unroll
    for (int ni = 0; ni < 4; ni++) nrow[ni] = 16384 + (wc * 128 + ni * 32 + l31) * 128;

    for (int rt = rt0; rt * 128 < cnt; rt += 32) {
        int r0 = rt * 128;
        __syncthreads();
        if (tid < 128) {
            int idx = r0 + tid;
            int tv = tasks[e * TSTR + min(idx, cnt - 1)];
            tokL[tid] = tv & 0xFFFF;
            flgL[tid] = (idx < cnt) ? ((tv >> 17) & 3) : 0;
        }
        __syncthreads();
        size_t asrc_off[4];
        #pragma unroll
        for (int i = 0; i < 4; i++)
            asrc_off[i] = (size_t)tokL[i * 32 + sg] * (D * 2) + sc * 16;

        float ss[2][16] = {}, sd[2][16] = {};

        for (int n0 = ch * 1024; n0 < ch * 1024 + 1024; n0 += 256) {
            f32x16 acc[2][4];
            #pragma unroll
            for (int mi = 0; mi < 2; mi++)
                #pragma unroll
                for (int ni = 0; ni < 4; ni++)
                    acc[mi][ni] = (f32x16)(0.0f);

            const char* bsrc0 = we1t_e + (size_t)n0 * (D * 2) + bs_off;

            for (int k0 = 0; k0 < D; k0 += 64) {
                __syncthreads();
                #pragma unroll
                for (int i = 0; i < 4; i++) {
                    int4 v = *(const int4*)(xh_b + asrc_off[i] + k0 * 2);
                    *(int4*)(smem + i * 4096 + stoff) = v;
                }
                #pragma unroll
                for (int i = 0; i < 8; i++) {
                    int4 v = *(const int4*)(bsrc0 + (size_t)i * 32 * (D * 2) + k0 * 2);
                    *(int4*)(smem + 16384 + i * 4096 + stoff) = v;
                }
                __syncthreads();
                #pragma unroll
                for (int ks = 0; ks < 4; ks++) {
                    f16x8 a0 = *(const f16x8*)(smem + arow[0] + kx[ks]);
                    f16x8 a1 = *(const f16x8*)(smem + arow[1] + kx[ks]);
                    #pragma unroll
                    for (int ni = 0; ni < 4; ni++) {
                        f16x8 bf = *(const f16x8*)(smem + nrow[ni] + kx[ks]);
                        acc[0][ni] = __builtin_amdgcn_mfma_f32_32x32x16_f16(a0, bf, acc[0][ni], 0, 0, 0);
                        acc[1][ni] = __builtin_amdgcn_mfma_f32_32x32x16_f16(a1, bf, acc[1][ni], 0, 0, 0);
                    }
                }
            }
            #pragma unroll
            for (int ni = 0; ni < 4; ni++) {
                int col = n0 + wc * 128 + ni * 32 + l31;
                float b1 = be1[e * DH + col];
                float vs = v_sum[(size_t)e * DH + col];
                float vd = v_diff[(size_t)e * DH + col];
                #pragma unroll
                for (int mi = 0; mi < 2; mi++) {
                    #pragma unroll
                    for (int r = 0; r < 16; r++) {
                        float h = gelu_fast(acc[mi][ni][r] + b1);
                        ss[mi][r] += h * vs;
                        sd[mi][r] += h * vd;
                    }
                }
            }
        }

        #pragma unroll
        for (int m = 16; m >= 1; m >>= 1) {
            #pragma unroll
            for (int mi = 0; mi < 2; mi++)
                #pragma unroll
                for (int r = 0; r < 16; r++) {
                    ss[mi][r] += __shfl_xor(ss[mi][r], m, 64);
                    sd[mi][r] += __shfl_xor(sd[mi][r], m, 64);
                }
        }
        if (l31 == 0) {
            #pragma unroll
            for (int mi = 0; mi < 2; mi++)
                #pragma unroll
                for (int r = 0; r < 16; r++) {
                    int row = wr * 64 + mi * 32 + (r & 3) + 8 * (r >> 2) + 4 * hi;
                    redS[wc][row] = ss[mi][r];
                    redD[wc][row] = sd[mi][r];
                }
        }
        __syncthreads();
        if (tid < 128) {
            int idx = r0 + tid;
            if (idx < cnt) {
                int fl = flgL[tid];
                int tok = tokL[tid];
                float s = redS[0][tid] + redS[1][tid];
                float d = redD[0][tid] + redD[1][tid];
                if (ch == 0) { s += c_sum[e]; d += c_diff[e]; }
                if (fl & 1) ppS[ch * QN + tok] = s;
                if (fl & 2) ppD[ch * QN + tok] = d;
            }
        }
    }
}

// ---------------------------------------------------------------------------
// Final combine: out = ppS[0]+ppS[1] (c folded into ch0).
// ---------------------------------------------------------------------------
__global__ __launch_bounds__(256) void k_fin(
    const float* __restrict__ ppS, const float* __restrict__ ppD,
    float* __restrict__ out, int tok0)
{
    int i = blockIdx.x * 256 + threadIdx.x;
    out[tok0 + i]      = ppS[i] + ppS[QN + i];
    out[BT + tok0 + i] = ppD[i] + ppD[QN + i];
}

// ---------------------------------------------------------------------------
extern "C" void kernel_launch(void* const* d_in, const int* in_sizes, int n_in,
                              void* d_out, int out_size, void* d_ws, size_t ws_size,
                              hipStream_t stream)
{
    const float* a      = (const float*)d_in[0];
    const float* b      = (const float*)d_in[1];
    const float* W_in   = (const float*)d_in[2];
    const float* b_in   = (const float*)d_in[3];
    const float* ln_g   = (const float*)d_in[4];
    const float* ln_b   = (const float*)d_in[5];
    const float* Wr1s   = (const float*)d_in[6];
    const float* br1s   = (const float*)d_in[7];
    const float* Wr2s   = (const float*)d_in[8];
    const float* br2s   = (const float*)d_in[9];
    const float* Wr1d   = (const float*)d_in[10];
    const float* br1d   = (const float*)d_in[11];
    const float* Wr2d   = (const float*)d_in[12];
    const float* br2d   = (const float*)d_in[13];
    const float* We1    = (const float*)d_in[14];
    const float* be1    = (const float*)d_in[15];
    const float* We2    = (const float*)d_in[16];
    const float* be2    = (const float*)d_in[17];
    const float* w_sum  = (const float*)d_in[18];
    const float* bs     = (const float*)d_in[19];
    const float* w_diff = (const float*)d_in[20];
    const float* bd     = (const float*)d_in[21];
    float* out = (float*)d_out;

    char* w = (char*)d_ws;
    size_t off = 0;
    auto alloc = [&](size_t bytes) -> char* {
        char* p = w + off;
        off = (off + bytes + 255) & ~(size_t)255;
        return p;
    };
    float* v_sum   = (float*)alloc((size_t)NT * DH * 4);
    float* v_diff  = (float*)alloc((size_t)NT * DH * 4);
    float* c_sum   = (float*)alloc(64);
    float* c_diff  = (float*)alloc(64);
    float* x       = (float*)alloc((size_t)QN * D * 4);
    f16*   xh      = (f16*)alloc((size_t)QN * D * 2);
    float* part    = (float*)alloc((size_t)QN * 64 * 4);
    float* rlogp   = (float*)alloc((size_t)RCAP * 8 * 16 * 4);
    int*   redo    = (int*)alloc((size_t)QN * 4);
    int*   tasks   = (int*)alloc((size_t)NT * TSTR * 4);
    int*   ctrl    = (int*)alloc(64);
    float* ppS     = (float*)alloc((size_t)2 * QN * 4);
    float* ppD     = (float*)alloc((size_t)2 * QN * 4);
    f16*   We1T    = (f16*)alloc((size_t)NT * DH * D * 2);
    f16*   Wr1Tf   = (f16*)alloc((size_t)2048 * 1024 * 2);
    float* br1f    = (float*)alloc((size_t)2048 * 4);
    float* w2f     = (float*)alloc((size_t)2048 * 8 * 4);
    if (off > ws_size) {
        hipMemsetAsync(d_out, 0, (size_t)out_size * 4, stream);
        return;
    }

    k_cvt <<<dim3(4096), dim3(256), 0, stream>>>(We1, We1T);
    k_cvtR<<<dim3(512),  dim3(256), 0, stream>>>(Wr1s, Wr1d, Wr1Tf);
    k_fuse<<<dim3(1),    dim3(256), 0, stream>>>(br1s, br1d, Wr2s, Wr2d, br1f, w2f);
    k_prev<<<dim3(4097), dim3(256), 0, stream>>>(We2, w_sum, w_diff, be2, bs, bd,
                                                 v_sum, v_diff, c_sum, c_diff);
    for (int q = 0; q < NPASS; q++) {
        int tok0 = q * QN;
        k_enc<<<dim3(QN / 64), dim3(256), 0, stream>>>(a, b, W_in, b_in, ln_g, ln_b, x, xh, tok0);
        k_rtrm<<<dim3(QN / 64 * 8), dim3(256), 0, stream>>>(xh, Wr1Tf, br1f, w2f, part);
        hipMemsetAsync(ctrl, 0, 64, stream);
        k_amx2<<<dim3(QN / 256), dim3(256), 0, stream>>>(part, br2s, br2d, tasks, ctrl, redo);
        k_redo<<<dim3(32, 8, 2), dim3(256), 0, stream>>>(x, Wr1s, br1s, Wr2s, Wr1d, br1d, Wr2d,
                                                         redo, ctrl, rlogp);
        k_amx3<<<dim3(16), dim3(256), 0, stream>>>(rlogp, redo, br2s, br2d, tasks, ctrl);
        k_expm<<<dim3(512), dim3(256), 0, stream>>>(xh, We1T, be1, v_sum, v_diff,
                                                    c_sum, c_diff, tasks, ctrl, ppS, ppD);
        k_fin<<<dim3(QN / 256), dim3(256), 0, stream>>>(ppS, ppD, out, tok0);
    }
}

// Round 5
// 3531.103 us; speedup vs baseline: 4.4530x; 1.1880x over previous
//
#include <hip/hip_runtime.h>
#include <math.h>

// ============================================================================
// PureTriXButterfly — R5.
// - NEW k_sched: data-dependent load balancer. Flattens all expert jobs
//   (e, ch, row-tile) in fixed order and deals contiguous runs to the 8 XCDs
//   (~J/8 each). Fixes R3/R4's static e->XCD pinning, which confined the
//   largest expert (routing is skewed) to one XCD: k_expm stayed 528us with
//   occupancy 5.8% while 7 XCDs idled.
// - k_expm: consumes the per-XCD job list (bid&7 = XCD, bid>>3 = slot).
//   Math identical to R4 (passed, absmax 7.8e-3).
// - Everything else unchanged from R4.
// ============================================================================

#define BT 65536
#define QN 16384
#define NPASS 4
#define D 1024
#define NT 8
#define DH 2048
#define TSTR (2*QN)
#define RCAP 4096
#define DELTA 0.025f
#define XJCAP 96     // max jobs per XCD (J <= ~512, ceil(J/8) <= 64)

typedef _Float16 f16;
typedef _Float16 f16x8 __attribute__((ext_vector_type(8)));
typedef _Float16 f16x4 __attribute__((ext_vector_type(4)));
typedef float f32x16 __attribute__((ext_vector_type(16)));

__device__ __forceinline__ float gelu_f(float v) {
    return 0.5f * v * (1.0f + erff(v * 0.70710678118654752440f));
}

// fast exact-GELU via A&S 7.1.26 erf (|eps| <= 1.5e-7)
__device__ __forceinline__ float gelu_fast(float x) {
    float ax = fabsf(x) * 0.70710678118654752440f;
    float t = __builtin_amdgcn_rcpf(1.0f + 0.3275911f * ax);
    float p = t * (0.254829592f + t * (-0.284496736f + t * (1.421413741f +
              t * (-1.453152027f + t * 1.061405429f))));
    float er = 1.0f - p * __expf(-ax * ax);
    er = copysignf(er, x);
    return 0.5f * x * (1.0f + er);
}

// ---------------------------------------------------------------------------
__global__ __launch_bounds__(256) void k_prev(
    const float* __restrict__ We2, const float* __restrict__ w_sum,
    const float* __restrict__ w_diff, const float* __restrict__ be2,
    const float* __restrict__ bs, const float* __restrict__ bd,
    float* __restrict__ v_sum, float* __restrict__ v_diff,
    float* __restrict__ c_sum, float* __restrict__ c_diff)
{
    int bid = blockIdx.x;
    if (bid < 4096) {
        int row  = bid * 4 + (threadIdx.x >> 6);
        int lane = threadIdx.x & 63;
        const float* r = We2 + (size_t)row * D;
        float s1 = 0.f, s2 = 0.f;
        #pragma unroll
        for (int i = 0; i < 4; i++) {
            int o4 = (lane + 64 * i) * 4;
            float4 w = *(const float4*)(r + o4);
            float4 u = *(const float4*)(w_sum + o4);
            float4 v = *(const float4*)(w_diff + o4);
            s1 += w.x*u.x + w.y*u.y + w.z*u.z + w.w*u.w;
            s2 += w.x*v.x + w.y*v.y + w.z*v.z + w.w*v.w;
        }
        #pragma unroll
        for (int m = 32; m >= 1; m >>= 1) {
            s1 += __shfl_xor(s1, m, 64);
            s2 += __shfl_xor(s2, m, 64);
        }
        if (lane == 0) { v_sum[row] = s1; v_diff[row] = s2; }
    } else {
        int t = threadIdx.x;
        if (t < 8) {
            float s = 0.f; const float* r = be2 + t * D;
            for (int k = 0; k < D; k++) s += r[k] * w_sum[k];
            c_sum[t] = s + bs[0];
        } else if (t < 16) {
            int tt = t - 8;
            float s = 0.f; const float* r = be2 + tt * D;
            for (int k = 0; k < D; k++) s += r[k] * w_diff[k];
            c_diff[tt] = s + bd[0];
        }
    }
}

// ---------------------------------------------------------------------------
__global__ __launch_bounds__(256) void k_cvt(
    const float* __restrict__ We1, f16* __restrict__ We1T)
{
    __shared__ float tile[64][65];
    int b = blockIdx.x;
    int e = b >> 9, rem = b & 511;
    int kt = rem >> 5, nt = rem & 31;
    int tid = threadIdx.x;
    const float* src = We1 + ((size_t)e * D + kt * 64) * DH + nt * 64;
    #pragma unroll
    for (int i = 0; i < 16; i++) {
        int idx = tid + 256 * i;
        int kk = idx >> 6, nn = idx & 63;
        tile[kk][nn] = src[(size_t)kk * DH + nn];
    }
    __syncthreads();
    f16* dst = We1T + ((size_t)e * DH + nt * 64) * D + kt * 64;
    #pragma unroll
    for (int i = 0; i < 16; i++) {
        int idx = tid + 256 * i;
        int nn = idx >> 6, kk = idx & 63;
        dst[(size_t)nn * D + kk] = (f16)tile[kk][nn];
    }
}

// ---------------------------------------------------------------------------
__global__ __launch_bounds__(256) void k_cvtR(
    const float* __restrict__ Wr1s, const float* __restrict__ Wr1d,
    f16* __restrict__ Wr1Tf)
{
    __shared__ float tile[64][65];
    int b = blockIdx.x;                  // 512
    int z = b >> 8, rem = b & 255;
    int kt = rem >> 4, nt2 = rem & 15;
    int tid = threadIdx.x;
    const float* W = z ? Wr1d : Wr1s;
    const float* src = W + (size_t)(kt * 64) * 1024 + nt2 * 64;
    #pragma unroll
    for (int i = 0; i < 16; i++) {
        int idx = tid + 256 * i;
        int kk = idx >> 6, nn = idx & 63;
        tile[kk][nn] = src[(size_t)kk * 1024 + nn];
    }
    __syncthreads();
    f16* dst = Wr1Tf + (size_t)(z * 1024 + nt2 * 64) * 1024 + kt * 64;
    #pragma unroll
    for (int i = 0; i < 16; i++) {
        int idx = tid + 256 * i;
        int nn = idx >> 6, kk = idx & 63;
        dst[(size_t)nn * 1024 + kk] = (f16)tile[kk][nn];
    }
}

// ---------------------------------------------------------------------------
__global__ __launch_bounds__(256) void k_fuse(
    const float* __restrict__ br1s, const float* __restrict__ br1d,
    const float* __restrict__ Wr2s, const float* __restrict__ Wr2d,
    float* __restrict__ br1f, float* __restrict__ w2f)
{
    int tid = threadIdx.x;
    for (int n = tid; n < 2048; n += 256) {
        br1f[n] = (n < 1024) ? br1s[n] : br1d[n - 1024];
        const float* src = (n < 1024) ? (Wr2s + (size_t)n * 8)
                                      : (Wr2d + (size_t)(n - 1024) * 8);
        #pragma unroll
        for (int o = 0; o < 8; o++) w2f[(size_t)n * 8 + o] = src[o];
    }
}

// ---------------------------------------------------------------------------
__global__ __launch_bounds__(256) void k_enc(
    const float* __restrict__ a, const float* __restrict__ b,
    const float* __restrict__ W_in, const float* __restrict__ b_in,
    const float* __restrict__ ln_g, const float* __restrict__ ln_b,
    float* __restrict__ x, f16* __restrict__ xh, int tok0)
{
    __shared__ float x0[64][24];
    __shared__ float red[8];
    int tid = threadIdx.x;
    float4 Wc[24];
    #pragma unroll
    for (int f = 0; f < 24; f++) Wc[f] = *(const float4*)(W_in + f * D + tid * 4);
    float4 bi = *(const float4*)(b_in + tid * 4);
    float4 gg = *(const float4*)(ln_g + tid * 4);
    float4 bb = *(const float4*)(ln_b + tid * 4);
    int base = tok0 + blockIdx.x * 64;

    for (int idx = tid; idx < 64 * 12; idx += 256) {
        int t = idx / 12, q = idx - t * 12;
        int fr = q % 6;
        float in = (q < 6) ? a[base + t] : b[base + t];
        float ang = (in * 0.39269908169872414f) * (float)(1 << fr);
        int off = (q < 6) ? 0 : 12;
        x0[t][off + fr]     = sinf(ang);
        x0[t][off + 6 + fr] = cosf(ang);
    }
    __syncthreads();

    int lane = tid & 63, wid = tid >> 6;
    for (int t = 0; t < 64; t++) {
        float4 p = bi;
        #pragma unroll
        for (int f = 0; f < 24; f++) {
            float xv = x0[t][f];
            p.x += xv * Wc[f].x; p.y += xv * Wc[f].y;
            p.z += xv * Wc[f].z; p.w += xv * Wc[f].w;
        }
        float s1 = p.x + p.y + p.z + p.w;
        float s2 = p.x*p.x + p.y*p.y + p.z*p.z + p.w*p.w;
        #pragma unroll
        for (int m = 32; m >= 1; m >>= 1) {
            s1 += __shfl_xor(s1, m, 64);
            s2 += __shfl_xor(s2, m, 64);
        }
        if (lane == 0) { red[wid] = s1; red[4 + wid] = s2; }
        __syncthreads();
        float mean = (red[0] + red[1] + red[2] + red[3]) * (1.f / 1024.f);
        float ms   = (red[4] + red[5] + red[6] + red[7]) * (1.f / 1024.f);
        float inv  = 1.f / sqrtf(ms - mean * mean + 1e-5f);
        float4 o;
        o.x = gelu_f((p.x - mean) * inv * gg.x + bb.x);
        o.y = gelu_f((p.y - mean) * inv * gg.y + bb.y);
        o.z = gelu_f((p.z - mean) * inv * gg.z + bb.z);
        o.w = gelu_f((p.w - mean) * inv * gg.w + bb.w);
        size_t row = (size_t)(blockIdx.x * 64 + t);
        *(float4*)(x + row * D + tid * 4) = o;
        f16x4 h; h[0] = (f16)o.x; h[1] = (f16)o.y; h[2] = (f16)o.z; h[3] = (f16)o.w;
        *(f16x4*)(xh + row * D + tid * 4) = h;
        __syncthreads();
    }
}

// ---------------------------------------------------------------------------
// Fused router, fp16 MFMA (unchanged from R4).
// ---------------------------------------------------------------------------
__global__ __launch_bounds__(256) void k_rtrm(
    const f16* __restrict__ xh, const f16* __restrict__ Wr1Tf,
    const float* __restrict__ br1f, const float* __restrict__ w2f,
    float* __restrict__ part)
{
    __shared__ char smem[40960] __attribute__((aligned(16)));
    int bid = blockIdx.x;
    int ntile = bid & 7;
    int ttile = bid >> 3;
    int tid = threadIdx.x;
    int lane = tid & 63, wid = tid >> 6;
    int hi = lane >> 5, l31 = lane & 31;
    int sg = tid >> 3, sc = tid & 7;

    const char* xb = (const char*)xh + (size_t)(ttile * 64) * 2048;
    const char* wb = (const char*)Wr1Tf + (size_t)(ntile * 256) * 2048;

    int axor = (l31 & 7) << 4;
    int kx[4];
    #pragma unroll
    for (int ks = 0; ks < 4; ks++) kx[ks] = (ks * 32 + hi * 16) ^ axor;
    int arow[2], brow[2];
    #pragma unroll
    for (int mi = 0; mi < 2; mi++) arow[mi] = (wid * 64 + mi * 32 + l31) * 128;
    #pragma unroll
    for (int ni = 0; ni < 2; ni++) brow[ni] = 32768 + (ni * 32 + l31) * 128;

    f32x16 acc[2][2];
    #pragma unroll
    for (int mi = 0; mi < 2; mi++)
        #pragma unroll
        for (int ni = 0; ni < 2; ni++) acc[mi][ni] = (f32x16)(0.0f);

    int swz = (sc * 16) ^ ((sg & 7) << 4);
    for (int k0 = 0; k0 < 1024; k0 += 64) {
        __syncthreads();
        #pragma unroll
        for (int i = 0; i < 8; i++) {
            int row = i * 32 + sg;
            int4 v = *(const int4*)(wb + (size_t)row * 2048 + k0 * 2 + sc * 16);
            *(int4*)(smem + row * 128 + swz) = v;
        }
        #pragma unroll
        for (int i = 0; i < 2; i++) {
            int row = i * 32 + sg;
            int4 v = *(const int4*)(xb + (size_t)row * 2048 + k0 * 2 + sc * 16);
            *(int4*)(smem + 32768 + row * 128 + swz) = v;
        }
        __syncthreads();
        #pragma unroll
        for (int ks = 0; ks < 4; ks++) {
            f16x8 a0 = *(const f16x8*)(smem + arow[0] + kx[ks]);
            f16x8 a1 = *(const f16x8*)(smem + arow[1] + kx[ks]);
            f16x8 b0 = *(const f16x8*)(smem + brow[0] + kx[ks]);
            f16x8 b1 = *(const f16x8*)(smem + brow[1] + kx[ks]);
            acc[0][0] = __builtin_amdgcn_mfma_f32_32x32x16_f16(a0, b0, acc[0][0], 0, 0, 0);
            acc[0][1] = __builtin_amdgcn_mfma_f32_32x32x16_f16(a0, b1, acc[0][1], 0, 0, 0);
            acc[1][0] = __builtin_amdgcn_mfma_f32_32x32x16_f16(a1, b0, acc[1][0], 0, 0, 0);
            acc[1][1] = __builtin_amdgcn_mfma_f32_32x32x16_f16(a1, b1, acc[1][1], 0, 0, 0);
        }
    }

    float lp[2][8] = {};
    #pragma unroll
    for (int mi = 0; mi < 2; mi++) {
        #pragma unroll
        for (int r = 0; r < 16; r++) {
            int nl = wid * 64 + mi * 32 + (r & 3) + 8 * (r >> 2) + 4 * hi;
            int gn = ntile * 256 + nl;
            float b1 = br1f[gn];
            float4 wa = *(const float4*)(w2f + (size_t)gn * 8);
            float4 wc = *(const float4*)(w2f + (size_t)gn * 8 + 4);
            float h0 = gelu_fast(acc[mi][0][r] + b1);
            float h1 = gelu_fast(acc[mi][1][r] + b1);
            lp[0][0] += h0*wa.x; lp[0][1] += h0*wa.y;
            lp[0][2] += h0*wa.z; lp[0][3] += h0*wa.w;
            lp[0][4] += h0*wc.x; lp[0][5] += h0*wc.y;
            lp[0][6] += h0*wc.z; lp[0][7] += h0*wc.w;
            lp[1][0] += h1*wa.x; lp[1][1] += h1*wa.y;
            lp[1][2] += h1*wa.z; lp[1][3] += h1*wa.w;
            lp[1][4] += h1*wc.x; lp[1][5] += h1*wc.y;
            lp[1][6] += h1*wc.z; lp[1][7] += h1*wc.w;
        }
    }
    #pragma unroll
    for (int ni = 0; ni < 2; ni++)
        #pragma unroll
        for (int o = 0; o < 8; o++)
            lp[ni][o] += __shfl_xor(lp[ni][o], 32, 64);
    __syncthreads();
    float* redf = (float*)smem;
    if (hi == 0) {
        #pragma unroll
        for (int ni = 0; ni < 2; ni++)
            #pragma unroll
            for (int o = 0; o < 8; o++)
                redf[(wid * 64 + ni * 32 + l31) * 8 + o] = lp[ni][o];
    }
    __syncthreads();
    for (int idx = tid; idx < 512; idx += 256) {
        int tok = idx >> 3, o = idx & 7;
        float s = ((redf[(0 * 64 + tok) * 8 + o]  + redf[(1 * 64 + tok) * 8 + o])
                 +  redf[(2 * 64 + tok) * 8 + o]) + redf[(3 * 64 + tok) * 8 + o];
        part[((size_t)(ttile * 64 + tok) * 8 + ntile) * 8 + o] = s;
    }
}

// ---------------------------------------------------------------------------
__device__ __forceinline__ void emit_tasks(int tok, int ts, int td,
                                           int* tasks, int* cnts)
{
    if (ts == td) {
        int s = atomicAdd(&cnts[ts], 1);
        tasks[ts * TSTR + s] = tok | (3 << 17);
    } else {
        int s1 = atomicAdd(&cnts[ts], 1);
        tasks[ts * TSTR + s1] = tok | (1 << 17);
        int s2 = atomicAdd(&cnts[td], 1);
        tasks[td * TSTR + s2] = tok | (2 << 17);
    }
}

__global__ __launch_bounds__(256) void k_amx2(
    const float* __restrict__ part, const float* __restrict__ b2s,
    const float* __restrict__ b2d, int* __restrict__ tasks,
    int* __restrict__ ctrl, int* __restrict__ redo)
{
    int i = blockIdx.x * 256 + threadIdx.x;
    const float* p = part + (size_t)i * 64;
    float Ls[8], Ld[8];
    #pragma unroll
    for (int o = 0; o < 8; o++) { Ls[o] = b2s[o]; Ld[o] = b2d[o]; }
    #pragma unroll
    for (int nt = 0; nt < 4; nt++)
        #pragma unroll
        for (int o = 0; o < 8; o++) Ls[o] += p[nt * 8 + o];
    #pragma unroll
    for (int nt = 4; nt < 8; nt++)
        #pragma unroll
        for (int o = 0; o < 8; o++) Ld[o] += p[nt * 8 + o];

    int as = 0; float m1s = Ls[0];
    #pragma unroll
    for (int o = 1; o < 8; o++) if (Ls[o] > m1s) { m1s = Ls[o]; as = o; }
    float m2s = -1e30f;
    #pragma unroll
    for (int o = 0; o < 8; o++) if (o != as && Ls[o] > m2s) m2s = Ls[o];
    int ad = 0; float m1d = Ld[0];
    #pragma unroll
    for (int o = 1; o < 8; o++) if (Ld[o] > m1d) { m1d = Ld[o]; ad = o; }
    float m2d = -1e30f;
    #pragma unroll
    for (int o = 0; o < 8; o++) if (o != ad && Ld[o] > m2d) m2d = Ld[o];

    if ((m1s - m2s) < DELTA || (m1d - m2d) < DELTA) {
        int s = atomicAdd(&ctrl[8], 1);
        if (s < RCAP) { redo[s] = i; return; }
    }
    emit_tasks(i, as, ad, tasks, ctrl);
}

// ---------------------------------------------------------------------------
__global__ __launch_bounds__(256) void k_redo(
    const float* __restrict__ x,
    const float* __restrict__ Wr1s, const float* __restrict__ br1s,
    const float* __restrict__ Wr2s,
    const float* __restrict__ Wr1d, const float* __restrict__ br1d,
    const float* __restrict__ Wr2d,
    const int* __restrict__ redo, const int* __restrict__ ctrl,
    float* __restrict__ rlogp)
{
    int rcnt = min(ctrl[8], RCAP);
    int nt = blockIdx.y, z = blockIdx.z;
    const float* Wr1 = z ? Wr1d : Wr1s;
    const float* br1 = z ? br1d : br1s;
    const float* Wr2 = z ? Wr2d : Wr2s;
    __shared__ float As[64][72];
    __shared__ float Bs[64][132];
    __shared__ int tokR[64];
    int tid = threadIdx.x;
    int tr = tid >> 5, tc = tid & 31;

    for (int mc = blockIdx.x; mc * 64 < rcnt; mc += gridDim.x) {
        __syncthreads();
        if (tid < 64) tokR[tid] = redo[min(mc * 64 + tid, rcnt - 1)];
        __syncthreads();
        float acc[8][4] = {};
        const float* wb = Wr1 + nt * 128;
        for (int k0 = 0; k0 < D; k0 += 64) {
            __syncthreads();
            {
                int row = tid >> 2, q = tid & 3;
                const float* xr = x + (size_t)tokR[row] * D + k0;
                #pragma unroll
                for (int i = 0; i < 4; i++) {
                    int f4i = q + 4 * i;
                    float4 v = *(const float4*)(xr + f4i * 4);
                    int k = f4i * 4;
                    As[k][row] = v.x; As[k+1][row] = v.y;
                    As[k+2][row] = v.z; As[k+3][row] = v.w;
                }
            }
            {
                #pragma unroll
                for (int i = 0; i < 8; i++) {
                    int idx = tid + 256 * i;
                    int k = idx >> 5, nq = idx & 31;
                    float4 v = *(const float4*)(wb + (size_t)(k0 + k) * D + nq * 4);
                    *(float4*)&Bs[k][nq * 4] = v;
                }
            }
            __syncthreads();
            #pragma unroll 4
            for (int kk = 0; kk < 64; kk++) {
                float4 a0 = *(const float4*)&As[kk][tr * 8];
                float4 a1 = *(const float4*)&As[kk][tr * 8 + 4];
                float4 bv = *(const float4*)&Bs[kk][tc * 4];
                float ar[8] = {a0.x,a0.y,a0.z,a0.w,a1.x,a1.y,a1.z,a1.w};
                #pragma unroll
                for (int i = 0; i < 8; i++) {
                    acc[i][0] += ar[i] * bv.x;
                    acc[i][1] += ar[i] * bv.y;
                    acc[i][2] += ar[i] * bv.z;
                    acc[i][3] += ar[i] * bv.w;
                }
            }
        }
        float lp[8][8] = {};
        #pragma unroll
        for (int j = 0; j < 4; j++) {
            int col = nt * 128 + tc * 4 + j;
            float b1 = br1[col];
            float w2[8];
            #pragma unroll
            for (int o = 0; o < 8; o++) w2[o] = Wr2[col * 8 + o];
            #pragma unroll
            for (int i = 0; i < 8; i++) {
                float h = gelu_f(acc[i][j] + b1);
                #pragma unroll
                for (int o = 0; o < 8; o++) lp[i][o] += h * w2[o];
            }
        }
        #pragma unroll
        for (int m = 16; m >= 1; m >>= 1) {
            #pragma unroll
            for (int i = 0; i < 8; i++)
                #pragma unroll
                for (int o = 0; o < 8; o++)
                    lp[i][o] += __shfl_xor(lp[i][o], m, 64);
        }
        if (tc == 0) {
            #pragma unroll
            for (int i = 0; i < 8; i++) {
                int slot = mc * 64 + tr * 8 + i;
                if (slot < rcnt) {
                    float* p = rlogp + ((size_t)slot * 8 + nt) * 16 + z * 8;
                    #pragma unroll
                    for (int o = 0; o < 8; o++) p[o] = lp[i][o];
                }
            }
        }
    }
}

// ---------------------------------------------------------------------------
__global__ __launch_bounds__(256) void k_amx3(
    const float* __restrict__ rlogp, const int* __restrict__ redo,
    const float* __restrict__ b2s, const float* __restrict__ b2d,
    int* __restrict__ tasks, int* __restrict__ ctrl)
{
    int rcnt = min(ctrl[8], RCAP);
    for (int s = blockIdx.x * 256 + threadIdx.x; s < rcnt; s += gridDim.x * 256) {
        int tok = redo[s];
        float L[16] = {};
        for (int nt = 0; nt < 8; nt++) {
            const float* p = rlogp + ((size_t)s * 8 + nt) * 16;
            #pragma unroll
            for (int o = 0; o < 16; o++) L[o] += p[o];
        }
        float Ls[8], Ld[8];
        #pragma unroll
        for (int o = 0; o < 8; o++) { Ls[o] = L[o] + b2s[o]; Ld[o] = L[8 + o] + b2d[o]; }
        int ts = 0; float bv = Ls[0];
        #pragma unroll
        for (int o = 1; o < 8; o++) if (Ls[o] > bv) { bv = Ls[o]; ts = o; }
        int td = 0; bv = Ld[0];
        #pragma unroll
        for (int o = 1; o < 8; o++) if (Ld[o] > bv) { bv = Ld[o]; td = o; }
        emit_tasks(tok, ts, td, tasks, ctrl);
    }
}

// ---------------------------------------------------------------------------
// Job scheduler: flatten (e, ch, rt) jobs in fixed order, deal contiguous
// runs to 8 XCDs (~J/8 each). xjob[x*XJCAP + i] = e | ch<<3 | rt<<4;
// xjob[8*XJCAP + x] = count for XCD x.
// ---------------------------------------------------------------------------
__global__ void k_sched(const int* __restrict__ ctrl, int* __restrict__ xjob)
{
    if (threadIdx.x != 0) return;
    int ntile[8], J = 0;
    for (int e = 0; e < 8; e++) {
        ntile[e] = (ctrl[e] + 127) >> 7;
        J += 2 * ntile[e];
    }
    int target = (J + 7) >> 3;
    int x = 0, fill = 0;
    int cnt[8] = {0,0,0,0,0,0,0,0};
    for (int e = 0; e < 8; e++) {
        for (int ch = 0; ch < 2; ch++) {
            for (int rt = 0; rt < ntile[e]; rt++) {
                if (fill == target && x < 7) { x++; fill = 0; }
                xjob[x * XJCAP + fill] = e | (ch << 3) | (rt << 4);
                fill++;
                cnt[x] = fill;
            }
        }
    }
    for (int i = 0; i < 8; i++) xjob[8 * XJCAP + i] = cnt[i];
}

// ---------------------------------------------------------------------------
// Expert GEMM, fp16 MFMA. Jobs from the balanced per-XCD lists:
// xcd = bid&7, slot = bid>>3 (stride 64). Math identical to R4.
// ---------------------------------------------------------------------------
__global__ __launch_bounds__(256) void k_expm(
    const f16* __restrict__ xh, const f16* __restrict__ We1T,
    const float* __restrict__ be1, const float* __restrict__ v_sum,
    const float* __restrict__ v_diff, const float* __restrict__ c_sum,
    const float* __restrict__ c_diff, const int* __restrict__ tasks,
    const int* __restrict__ counts, const int* __restrict__ xjob,
    float* __restrict__ ppS, float* __restrict__ ppD)
{
    int xcd  = blockIdx.x & 7;
    int slot = blockIdx.x >> 3;          // 0..63
    int nj = xjob[8 * XJCAP + xcd];

    __shared__ char smem[49152] __attribute__((aligned(16)));
    __shared__ int tokL[128];
    __shared__ int flgL[128];
    __shared__ float redS[2][128];
    __shared__ float redD[2][128];

    int tid = threadIdx.x;
    int lane = tid & 63;
    int wid  = tid >> 6;
    int wr = wid >> 1, wc = wid & 1;
    int hi = lane >> 5, l31 = lane & 31;
    int sg = tid >> 3, sc = tid & 7;
    int stoff = sg * 128 + ((sc * 16) ^ ((sg & 7) << 4));

    const char* xh_b = (const char*)xh;

    int axor = (l31 & 7) << 4;
    int kx[4];
    #pragma unroll
    for (int ks = 0; ks < 4; ks++) kx[ks] = (ks * 32 + hi * 16) ^ axor;
    int arow[2], nrow[4];
    #pragma unroll
    for (int mi = 0; mi < 2; mi++) arow[mi] = (wr * 64 + mi * 32 + l31) * 128;
    #pragma unroll
    for (int ni = 0; ni < 4; ni++) nrow[ni] = 16384 + (wc * 128 + ni * 32 + l31) * 128;

    for (int j = slot; j < nj; j += 64) {
        int jv = xjob[xcd * XJCAP + j];
        int e  = jv & 7;
        int ch = (jv >> 3) & 1;
        int rt = jv >> 4;
        int cnt = counts[e];
        int r0 = rt * 128;
        const char* we1t_e = (const char*)(We1T + (size_t)e * DH * D);
        size_t bs_off = (size_t)sg * (D * 2) + sc * 16;

        __syncthreads();
        if (tid < 128) {
            int idx = r0 + tid;
            int tv = tasks[e * TSTR + min(idx, cnt - 1)];
            tokL[tid] = tv & 0xFFFF;
            flgL[tid] = (idx < cnt) ? ((tv >> 17) & 3) : 0;
        }
        __syncthreads();
        size_t asrc_off[4];
        #pragma unroll
        for (int i = 0; i < 4; i++)
            asrc_off[i] = (size_t)tokL[i * 32 + sg] * (D * 2) + sc * 16;

        float ss[2][16] = {}, sd[2][16] = {};

        for (int n0 = ch * 1024; n0 < ch * 1024 + 1024; n0 += 256) {
            f32x16 acc[2][4];
            #pragma unroll
            for (int mi = 0; mi < 2; mi++)
                #pragma unroll
                for (int ni = 0; ni < 4; ni++)
                    acc[mi][ni] = (f32x16)(0.0f);

            const char* bsrc0 = we1t_e + (size_t)n0 * (D * 2) + bs_off;

            for (int k0 = 0; k0 < D; k0 += 64) {
                __syncthreads();
                #pragma unroll
                for (int i = 0; i < 4; i++) {
                    int4 v = *(const int4*)(xh_b + asrc_off[i] + k0 * 2);
                    *(int4*)(smem + i * 4096 + stoff) = v;
                }
                #pragma unroll
                for (int i = 0; i < 8; i++) {
                    int4 v = *(const int4*)(bsrc0 + (size_t)i * 32 * (D * 2) + k0 * 2);
                    *(int4*)(smem + 16384 + i * 4096 + stoff) = v;
                }
                __syncthreads();
                #pragma unroll
                for (int ks = 0; ks < 4; ks++) {
                    f16x8 a0 = *(const f16x8*)(smem + arow[0] + kx[ks]);
                    f16x8 a1 = *(const f16x8*)(smem + arow[1] + kx[ks]);
                    #pragma unroll
                    for (int ni = 0; ni < 4; ni++) {
                        f16x8 bf = *(const f16x8*)(smem + nrow[ni] + kx[ks]);
                        acc[0][ni] = __builtin_amdgcn_mfma_f32_32x32x16_f16(a0, bf, acc[0][ni], 0, 0, 0);
                        acc[1][ni] = __builtin_amdgcn_mfma_f32_32x32x16_f16(a1, bf, acc[1][ni], 0, 0, 0);
                    }
                }
            }
            #pragma unroll
            for (int ni = 0; ni < 4; ni++) {
                int col = n0 + wc * 128 + ni * 32 + l31;
                float b1 = be1[e * DH + col];
                float vs = v_sum[(size_t)e * DH + col];
                float vd = v_diff[(size_t)e * DH + col];
                #pragma unroll
                for (int mi = 0; mi < 2; mi++) {
                    #pragma unroll
                    for (int r = 0; r < 16; r++) {
                        float h = gelu_fast(acc[mi][ni][r] + b1);
                        ss[mi][r] += h * vs;
                        sd[mi][r] += h * vd;
                    }
                }
            }
        }

        #pragma unroll
        for (int m = 16; m >= 1; m >>= 1) {
            #pragma unroll
            for (int mi = 0; mi < 2; mi++)
                #pragma unroll
                for (int r = 0; r < 16; r++) {
                    ss[mi][r] += __shfl_xor(ss[mi][r], m, 64);
                    sd[mi][r] += __shfl_xor(sd[mi][r], m, 64);
                }
        }
        if (l31 == 0) {
            #pragma unroll
            for (int mi = 0; mi < 2; mi++)
                #pragma unroll
                for (int r = 0; r < 16; r++) {
                    int row = wr * 64 + mi * 32 + (r & 3) + 8 * (r >> 2) + 4 * hi;
                    redS[wc][row] = ss[mi][r];
                    redD[wc][row] = sd[mi][r];
                }
        }
        __syncthreads();
        if (tid < 128) {
            int idx = r0 + tid;
            if (idx < cnt) {
                int fl = flgL[tid];
                int tok = tokL[tid];
                float s = redS[0][tid] + redS[1][tid];
                float d = redD[0][tid] + redD[1][tid];
                if (ch == 0) { s += c_sum[e]; d += c_diff[e]; }
                if (fl & 1) ppS[ch * QN + tok] = s;
                if (fl & 2) ppD[ch * QN + tok] = d;
            }
        }
    }
}

// ---------------------------------------------------------------------------
__global__ __launch_bounds__(256) void k_fin(
    const float* __restrict__ ppS, const float* __restrict__ ppD,
    float* __restrict__ out, int tok0)
{
    int i = blockIdx.x * 256 + threadIdx.x;
    out[tok0 + i]      = ppS[i] + ppS[QN + i];
    out[BT + tok0 + i] = ppD[i] + ppD[QN + i];
}

// ---------------------------------------------------------------------------
extern "C" void kernel_launch(void* const* d_in, const int* in_sizes, int n_in,
                              void* d_out, int out_size, void* d_ws, size_t ws_size,
                              hipStream_t stream)
{
    const float* a      = (const float*)d_in[0];
    const float* b      = (const float*)d_in[1];
    const float* W_in   = (const float*)d_in[2];
    const float* b_in   = (const float*)d_in[3];
    const float* ln_g   = (const float*)d_in[4];
    const float* ln_b   = (const float*)d_in[5];
    const float* Wr1s   = (const float*)d_in[6];
    const float* br1s   = (const float*)d_in[7];
    const float* Wr2s   = (const float*)d_in[8];
    const float* br2s   = (const float*)d_in[9];
    const float* Wr1d   = (const float*)d_in[10];
    const float* br1d   = (const float*)d_in[11];
    const float* Wr2d   = (const float*)d_in[12];
    const float* br2d   = (const float*)d_in[13];
    const float* We1    = (const float*)d_in[14];
    const float* be1    = (const float*)d_in[15];
    const float* We2    = (const float*)d_in[16];
    const float* be2    = (const float*)d_in[17];
    const float* w_sum  = (const float*)d_in[18];
    const float* bs     = (const float*)d_in[19];
    const float* w_diff = (const float*)d_in[20];
    const float* bd     = (const float*)d_in[21];
    float* out = (float*)d_out;

    char* w = (char*)d_ws;
    size_t off = 0;
    auto alloc = [&](size_t bytes) -> char* {
        char* p = w + off;
        off = (off + bytes + 255) & ~(size_t)255;
        return p;
    };
    float* v_sum   = (float*)alloc((size_t)NT * DH * 4);
    float* v_diff  = (float*)alloc((size_t)NT * DH * 4);
    float* c_sum   = (float*)alloc(64);
    float* c_diff  = (float*)alloc(64);
    float* x       = (float*)alloc((size_t)QN * D * 4);
    f16*   xh      = (f16*)alloc((size_t)QN * D * 2);
    float* part    = (float*)alloc((size_t)QN * 64 * 4);
    float* rlogp   = (float*)alloc((size_t)RCAP * 8 * 16 * 4);
    int*   redo    = (int*)alloc((size_t)QN * 4);
    int*   tasks   = (int*)alloc((size_t)NT * TSTR * 4);
    int*   ctrl    = (int*)alloc(64);
    int*   xjob    = (int*)alloc((size_t)(8 * XJCAP + 8) * 4);
    float* ppS     = (float*)alloc((size_t)2 * QN * 4);
    float* ppD     = (float*)alloc((size_t)2 * QN * 4);
    f16*   We1T    = (f16*)alloc((size_t)NT * DH * D * 2);
    f16*   Wr1Tf   = (f16*)alloc((size_t)2048 * 1024 * 2);
    float* br1f    = (float*)alloc((size_t)2048 * 4);
    float* w2f     = (float*)alloc((size_t)2048 * 8 * 4);
    if (off > ws_size) {
        hipMemsetAsync(d_out, 0, (size_t)out_size * 4, stream);
        return;
    }

    k_cvt <<<dim3(4096), dim3(256), 0, stream>>>(We1, We1T);
    k_cvtR<<<dim3(512),  dim3(256), 0, stream>>>(Wr1s, Wr1d, Wr1Tf);
    k_fuse<<<dim3(1),    dim3(256), 0, stream>>>(br1s, br1d, Wr2s, Wr2d, br1f, w2f);
    k_prev<<<dim3(4097), dim3(256), 0, stream>>>(We2, w_sum, w_diff, be2, bs, bd,
                                                 v_sum, v_diff, c_sum, c_diff);
    for (int q = 0; q < NPASS; q++) {
        int tok0 = q * QN;
        k_enc<<<dim3(QN / 64), dim3(256), 0, stream>>>(a, b, W_in, b_in, ln_g, ln_b, x, xh, tok0);
        k_rtrm<<<dim3(QN / 64 * 8), dim3(256), 0, stream>>>(xh, Wr1Tf, br1f, w2f, part);
        hipMemsetAsync(ctrl, 0, 64, stream);
        k_amx2<<<dim3(QN / 256), dim3(256), 0, stream>>>(part, br2s, br2d, tasks, ctrl, redo);
        k_redo<<<dim3(32, 8, 2), dim3(256), 0, stream>>>(x, Wr1s, br1s, Wr2s, Wr1d, br1d, Wr2d,
                                                         redo, ctrl, rlogp);
        k_amx3<<<dim3(16), dim3(256), 0, stream>>>(rlogp, redo, br2s, br2d, tasks, ctrl);
        k_sched<<<dim3(1), dim3(64), 0, stream>>>(ctrl, xjob);
        k_expm<<<dim3(512), dim3(256), 0, stream>>>(xh, We1T, be1, v_sum, v_diff,
                                                    c_sum, c_diff, tasks, ctrl, xjob, ppS, ppD);
        k_fin<<<dim3(QN / 256), dim3(256), 0, stream>>>(ppS, ppD, out, tok0);
    }
}

// Round 6
// 2902.052 us; speedup vs baseline: 5.4183x; 1.2168x over previous
//
#include <hip/hip_runtime.h>
#include <math.h>

// ============================================================================
// PureTriXButterfly — R6.
// - Dynamic pass count: qn = largest of {64K,32K,16K} whose workspace fits.
//   Single pass removes 4x launch serialization, quadruples grid parallelism.
// - k_expm: M=64 jobs, acc[4] (64 VGPR), __launch_bounds__(256,3) -> 3
//   waves/SIMD; staging via global_load_lds(16B) with pre-swizzled GLOBAL
//   source + linear LDS dest (involution: LDS[row][s]=G[row][s^(row&7)]).
// - k_rtrm: same gload_lds staging, launch_bounds (256,3).
// - k_sched: parallelized; M=64 tiles; RCAP 8192.
// - Routing semantics unchanged (fp16+margin redo; R3-R5 passed, 7.8e-3).
// ============================================================================

#define BT 65536
#define D 1024
#define NT 8
#define DH 2048
#define RCAP 8192
#define DELTA 0.025f
#define XJCAP 768

typedef _Float16 f16;
typedef _Float16 f16x8 __attribute__((ext_vector_type(8)));
typedef _Float16 f16x4 __attribute__((ext_vector_type(4)));
typedef float f32x16 __attribute__((ext_vector_type(16)));

__device__ __forceinline__ float gelu_f(float v) {
    return 0.5f * v * (1.0f + erff(v * 0.70710678118654752440f));
}

// fast exact-GELU via A&S 7.1.26 erf (|eps| <= 1.5e-7)
__device__ __forceinline__ float gelu_fast(float x) {
    float ax = fabsf(x) * 0.70710678118654752440f;
    float t = __builtin_amdgcn_rcpf(1.0f + 0.3275911f * ax);
    float p = t * (0.254829592f + t * (-0.284496736f + t * (1.421413741f +
              t * (-1.453152027f + t * 1.061405429f))));
    float er = 1.0f - p * __expf(-ax * ax);
    er = copysignf(er, x);
    return 0.5f * x * (1.0f + er);
}

__device__ __forceinline__ void gload16(const void* g, void* l) {
    __builtin_amdgcn_global_load_lds(
        (const __attribute__((address_space(1))) void*)g,
        (__attribute__((address_space(3))) void*)l, 16, 0, 0);
}

// ---------------------------------------------------------------------------
__global__ __launch_bounds__(256) void k_prev(
    const float* __restrict__ We2, const float* __restrict__ w_sum,
    const float* __restrict__ w_diff, const float* __restrict__ be2,
    const float* __restrict__ bs, const float* __restrict__ bd,
    float* __restrict__ v_sum, float* __restrict__ v_diff,
    float* __restrict__ c_sum, float* __restrict__ c_diff)
{
    int bid = blockIdx.x;
    if (bid < 4096) {
        int row  = bid * 4 + (threadIdx.x >> 6);
        int lane = threadIdx.x & 63;
        const float* r = We2 + (size_t)row * D;
        float s1 = 0.f, s2 = 0.f;
        #pragma unroll
        for (int i = 0; i < 4; i++) {
            int o4 = (lane + 64 * i) * 4;
            float4 w = *(const float4*)(r + o4);
            float4 u = *(const float4*)(w_sum + o4);
            float4 v = *(const float4*)(w_diff + o4);
            s1 += w.x*u.x + w.y*u.y + w.z*u.z + w.w*u.w;
            s2 += w.x*v.x + w.y*v.y + w.z*v.z + w.w*v.w;
        }
        #pragma unroll
        for (int m = 32; m >= 1; m >>= 1) {
            s1 += __shfl_xor(s1, m, 64);
            s2 += __shfl_xor(s2, m, 64);
        }
        if (lane == 0) { v_sum[row] = s1; v_diff[row] = s2; }
    } else {
        int t = threadIdx.x;
        if (t < 8) {
            float s = 0.f; const float* r = be2 + t * D;
            for (int k = 0; k < D; k++) s += r[k] * w_sum[k];
            c_sum[t] = s + bs[0];
        } else if (t < 16) {
            int tt = t - 8;
            float s = 0.f; const float* r = be2 + tt * D;
            for (int k = 0; k < D; k++) s += r[k] * w_diff[k];
            c_diff[tt] = s + bd[0];
        }
    }
}

// ---------------------------------------------------------------------------
__global__ __launch_bounds__(256) void k_cvt(
    const float* __restrict__ We1, f16* __restrict__ We1T)
{
    __shared__ float tile[64][65];
    int b = blockIdx.x;
    int e = b >> 9, rem = b & 511;
    int kt = rem >> 5, nt = rem & 31;
    int tid = threadIdx.x;
    const float* src = We1 + ((size_t)e * D + kt * 64) * DH + nt * 64;
    #pragma unroll
    for (int i = 0; i < 16; i++) {
        int idx = tid + 256 * i;
        int kk = idx >> 6, nn = idx & 63;
        tile[kk][nn] = src[(size_t)kk * DH + nn];
    }
    __syncthreads();
    f16* dst = We1T + ((size_t)e * DH + nt * 64) * D + kt * 64;
    #pragma unroll
    for (int i = 0; i < 16; i++) {
        int idx = tid + 256 * i;
        int nn = idx >> 6, kk = idx & 63;
        dst[(size_t)nn * D + kk] = (f16)tile[kk][nn];
    }
}

// ---------------------------------------------------------------------------
__global__ __launch_bounds__(256) void k_cvtR(
    const float* __restrict__ Wr1s, const float* __restrict__ Wr1d,
    f16* __restrict__ Wr1Tf)
{
    __shared__ float tile[64][65];
    int b = blockIdx.x;                  // 512
    int z = b >> 8, rem = b & 255;
    int kt = rem >> 4, nt2 = rem & 15;
    int tid = threadIdx.x;
    const float* W = z ? Wr1d : Wr1s;
    const float* src = W + (size_t)(kt * 64) * 1024 + nt2 * 64;
    #pragma unroll
    for (int i = 0; i < 16; i++) {
        int idx = tid + 256 * i;
        int kk = idx >> 6, nn = idx & 63;
        tile[kk][nn] = src[(size_t)kk * 1024 + nn];
    }
    __syncthreads();
    f16* dst = Wr1Tf + (size_t)(z * 1024 + nt2 * 64) * 1024 + kt * 64;
    #pragma unroll
    for (int i = 0; i < 16; i++) {
        int idx = tid + 256 * i;
        int nn = idx >> 6, kk = idx & 63;
        dst[(size_t)nn * 1024 + kk] = (f16)tile[kk][nn];
    }
}

// ---------------------------------------------------------------------------
__global__ __launch_bounds__(256) void k_fuse(
    const float* __restrict__ br1s, const float* __restrict__ br1d,
    const float* __restrict__ Wr2s, const float* __restrict__ Wr2d,
    float* __restrict__ br1f, float* __restrict__ w2f)
{
    int tid = threadIdx.x;
    for (int n = tid; n < 2048; n += 256) {
        br1f[n] = (n < 1024) ? br1s[n] : br1d[n - 1024];
        const float* src = (n < 1024) ? (Wr2s + (size_t)n * 8)
                                      : (Wr2d + (size_t)(n - 1024) * 8);
        #pragma unroll
        for (int o = 0; o < 8; o++) w2f[(size_t)n * 8 + o] = src[o];
    }
}

// ---------------------------------------------------------------------------
__global__ __launch_bounds__(256) void k_enc(
    const float* __restrict__ a, const float* __restrict__ b,
    const float* __restrict__ W_in, const float* __restrict__ b_in,
    const float* __restrict__ ln_g, const float* __restrict__ ln_b,
    float* __restrict__ x, f16* __restrict__ xh, int tok0)
{
    __shared__ float x0[64][24];
    __shared__ float red[8];
    int tid = threadIdx.x;
    float4 Wc[24];
    #pragma unroll
    for (int f = 0; f < 24; f++) Wc[f] = *(const float4*)(W_in + f * D + tid * 4);
    float4 bi = *(const float4*)(b_in + tid * 4);
    float4 gg = *(const float4*)(ln_g + tid * 4);
    float4 bb = *(const float4*)(ln_b + tid * 4);
    int base = tok0 + blockIdx.x * 64;

    for (int idx = tid; idx < 64 * 12; idx += 256) {
        int t = idx / 12, q = idx - t * 12;
        int fr = q % 6;
        float in = (q < 6) ? a[base + t] : b[base + t];
        float ang = (in * 0.39269908169872414f) * (float)(1 << fr);
        int off = (q < 6) ? 0 : 12;
        x0[t][off + fr]     = sinf(ang);
        x0[t][off + 6 + fr] = cosf(ang);
    }
    __syncthreads();

    int lane = tid & 63, wid = tid >> 6;
    for (int t = 0; t < 64; t++) {
        float4 p = bi;
        #pragma unroll
        for (int f = 0; f < 24; f++) {
            float xv = x0[t][f];
            p.x += xv * Wc[f].x; p.y += xv * Wc[f].y;
            p.z += xv * Wc[f].z; p.w += xv * Wc[f].w;
        }
        float s1 = p.x + p.y + p.z + p.w;
        float s2 = p.x*p.x + p.y*p.y + p.z*p.z + p.w*p.w;
        #pragma unroll
        for (int m = 32; m >= 1; m >>= 1) {
            s1 += __shfl_xor(s1, m, 64);
            s2 += __shfl_xor(s2, m, 64);
        }
        if (lane == 0) { red[wid] = s1; red[4 + wid] = s2; }
        __syncthreads();
        float mean = (red[0] + red[1] + red[2] + red[3]) * (1.f / 1024.f);
        float ms   = (red[4] + red[5] + red[6] + red[7]) * (1.f / 1024.f);
        float inv  = 1.f / sqrtf(ms - mean * mean + 1e-5f);
        float4 o;
        o.x = gelu_f((p.x - mean) * inv * gg.x + bb.x);
        o.y = gelu_f((p.y - mean) * inv * gg.y + bb.y);
        o.z = gelu_f((p.z - mean) * inv * gg.z + bb.z);
        o.w = gelu_f((p.w - mean) * inv * gg.w + bb.w);
        size_t row = (size_t)(blockIdx.x * 64 + t);
        *(float4*)(x + row * D + tid * 4) = o;
        f16x4 h; h[0] = (f16)o.x; h[1] = (f16)o.y; h[2] = (f16)o.z; h[3] = (f16)o.w;
        *(f16x4*)(xh + row * D + tid * 4) = h;
        __syncthreads();
    }
}

// ---------------------------------------------------------------------------
// Fused router, fp16 MFMA. Block = 64 tokens x 256 n, K=1024, gload_lds
// staging (pre-swizzled global source, linear LDS dest).
// ---------------------------------------------------------------------------
__global__ __launch_bounds__(256, 3) void k_rtrm(
    const f16* __restrict__ xh, const f16* __restrict__ Wr1Tf,
    const float* __restrict__ br1f, const float* __restrict__ w2f,
    float* __restrict__ part)
{
    __shared__ char smem[40960] __attribute__((aligned(16)));
    int bid = blockIdx.x;
    int ntile = bid & 7;
    int ttile = bid >> 3;
    int tid = threadIdx.x;
    int lane = tid & 63, wid = tid >> 6;
    int hi = lane >> 5, l31 = lane & 31;
    int sg = tid >> 3, sc = tid & 7;

    const char* xb = (const char*)xh + (size_t)(ttile * 64) * 2048;
    const char* wb = (const char*)Wr1Tf + (size_t)(ntile * 256) * 2048;
    size_t goff = (size_t)sg * 2048 + (size_t)((sc * 16) ^ ((sg & 7) << 4));

    int axor = (l31 & 7) << 4;
    int kx[4];
    #pragma unroll
    for (int ks = 0; ks < 4; ks++) kx[ks] = (ks * 32 + hi * 16) ^ axor;
    int arow[2], brow[2];
    #pragma unroll
    for (int mi = 0; mi < 2; mi++) arow[mi] = (wid * 64 + mi * 32 + l31) * 128;
    #pragma unroll
    for (int ni = 0; ni < 2; ni++) brow[ni] = 32768 + (ni * 32 + l31) * 128;

    f32x16 acc[2][2];
    #pragma unroll
    for (int mi = 0; mi < 2; mi++)
        #pragma unroll
        for (int ni = 0; ni < 2; ni++) acc[mi][ni] = (f32x16)(0.0f);

    for (int k0 = 0; k0 < 1024; k0 += 64) {
        __syncthreads();
        #pragma unroll
        for (int i = 0; i < 8; i++)
            gload16(wb + (size_t)i * 32 * 2048 + k0 * 2 + goff,
                    smem + i * 4096 + wid * 1024);
        #pragma unroll
        for (int i = 0; i < 2; i++)
            gload16(xb + (size_t)i * 32 * 2048 + k0 * 2 + goff,
                    smem + 32768 + i * 4096 + wid * 1024);
        __syncthreads();
        #pragma unroll
        for (int ks = 0; ks < 4; ks++) {
            f16x8 a0 = *(const f16x8*)(smem + arow[0] + kx[ks]);
            f16x8 a1 = *(const f16x8*)(smem + arow[1] + kx[ks]);
            f16x8 b0 = *(const f16x8*)(smem + brow[0] + kx[ks]);
            f16x8 b1 = *(const f16x8*)(smem + brow[1] + kx[ks]);
            acc[0][0] = __builtin_amdgcn_mfma_f32_32x32x16_f16(a0, b0, acc[0][0], 0, 0, 0);
            acc[0][1] = __builtin_amdgcn_mfma_f32_32x32x16_f16(a0, b1, acc[0][1], 0, 0, 0);
            acc[1][0] = __builtin_amdgcn_mfma_f32_32x32x16_f16(a1, b0, acc[1][0], 0, 0, 0);
            acc[1][1] = __builtin_amdgcn_mfma_f32_32x32x16_f16(a1, b1, acc[1][1], 0, 0, 0);
        }
    }

    float lp[2][8] = {};
    #pragma unroll
    for (int mi = 0; mi < 2; mi++) {
        #pragma unroll
        for (int r = 0; r < 16; r++) {
            int nl = wid * 64 + mi * 32 + (r & 3) + 8 * (r >> 2) + 4 * hi;
            int gn = ntile * 256 + nl;
            float b1 = br1f[gn];
            float4 wa = *(const float4*)(w2f + (size_t)gn * 8);
            float4 wc = *(const float4*)(w2f + (size_t)gn * 8 + 4);
            float h0 = gelu_fast(acc[mi][0][r] + b1);
            float h1 = gelu_fast(acc[mi][1][r] + b1);
            lp[0][0] += h0*wa.x; lp[0][1] += h0*wa.y;
            lp[0][2] += h0*wa.z; lp[0][3] += h0*wa.w;
            lp[0][4] += h0*wc.x; lp[0][5] += h0*wc.y;
            lp[0][6] += h0*wc.z; lp[0][7] += h0*wc.w;
            lp[1][0] += h1*wa.x; lp[1][1] += h1*wa.y;
            lp[1][2] += h1*wa.z; lp[1][3] += h1*wa.w;
            lp[1][4] += h1*wc.x; lp[1][5] += h1*wc.y;
            lp[1][6] += h1*wc.z; lp[1][7] += h1*wc.w;
        }
    }
    #pragma unroll
    for (int ni = 0; ni < 2; ni++)
        #pragma unroll
        for (int o = 0; o < 8; o++)
            lp[ni][o] += __shfl_xor(lp[ni][o], 32, 64);
    __syncthreads();
    float* redf = (float*)smem;
    if (hi == 0) {
        #pragma unroll
        for (int ni = 0; ni < 2; ni++)
            #pragma unroll
            for (int o = 0; o < 8; o++)
                redf[(wid * 64 + ni * 32 + l31) * 8 + o] = lp[ni][o];
    }
    __syncthreads();
    for (int idx = tid; idx < 512; idx += 256) {
        int tok = idx >> 3, o = idx & 7;
        float s = ((redf[(0 * 64 + tok) * 8 + o]  + redf[(1 * 64 + tok) * 8 + o])
                 +  redf[(2 * 64 + tok) * 8 + o]) + redf[(3 * 64 + tok) * 8 + o];
        part[((size_t)(ttile * 64 + tok) * 8 + ntile) * 8 + o] = s;
    }
}

// ---------------------------------------------------------------------------
__device__ __forceinline__ void emit_tasks(int tok, int ts, int td,
                                           int* tasks, int* cnts, int tstr)
{
    if (ts == td) {
        int s = atomicAdd(&cnts[ts], 1);
        tasks[ts * tstr + s] = tok | (3 << 17);
    } else {
        int s1 = atomicAdd(&cnts[ts], 1);
        tasks[ts * tstr + s1] = tok | (1 << 17);
        int s2 = atomicAdd(&cnts[td], 1);
        tasks[td * tstr + s2] = tok | (2 << 17);
    }
}

__global__ __launch_bounds__(256) void k_amx2(
    const float* __restrict__ part, const float* __restrict__ b2s,
    const float* __restrict__ b2d, int* __restrict__ tasks,
    int* __restrict__ ctrl, int* __restrict__ redo, int tstr)
{
    int i = blockIdx.x * 256 + threadIdx.x;
    const float* p = part + (size_t)i * 64;
    float Ls[8], Ld[8];
    #pragma unroll
    for (int o = 0; o < 8; o++) { Ls[o] = b2s[o]; Ld[o] = b2d[o]; }
    #pragma unroll
    for (int nt = 0; nt < 4; nt++)
        #pragma unroll
        for (int o = 0; o < 8; o++) Ls[o] += p[nt * 8 + o];
    #pragma unroll
    for (int nt = 4; nt < 8; nt++)
        #pragma unroll
        for (int o = 0; o < 8; o++) Ld[o] += p[nt * 8 + o];

    int as = 0; float m1s = Ls[0];
    #pragma unroll
    for (int o = 1; o < 8; o++) if (Ls[o] > m1s) { m1s = Ls[o]; as = o; }
    float m2s = -1e30f;
    #pragma unroll
    for (int o = 0; o < 8; o++) if (o != as && Ls[o] > m2s) m2s = Ls[o];
    int ad = 0; float m1d = Ld[0];
    #pragma unroll
    for (int o = 1; o < 8; o++) if (Ld[o] > m1d) { m1d = Ld[o]; ad = o; }
    float m2d = -1e30f;
    #pragma unroll
    for (int o = 0; o < 8; o++) if (o != ad && Ld[o] > m2d) m2d = Ld[o];

    if ((m1s - m2s) < DELTA || (m1d - m2d) < DELTA) {
        int s = atomicAdd(&ctrl[8], 1);
        if (s < RCAP) { redo[s] = i; return; }
    }
    emit_tasks(i, as, ad, tasks, ctrl, tstr);
}

// ---------------------------------------------------------------------------
__global__ __launch_bounds__(256) void k_redo(
    const float* __restrict__ x,
    const float* __restrict__ Wr1s, const float* __restrict__ br1s,
    const float* __restrict__ Wr2s,
    const float* __restrict__ Wr1d, const float* __restrict__ br1d,
    const float* __restrict__ Wr2d,
    const int* __restrict__ redo, const int* __restrict__ ctrl,
    float* __restrict__ rlogp)
{
    int rcnt = min(ctrl[8], RCAP);
    int nt = blockIdx.y, z = blockIdx.z;
    const float* Wr1 = z ? Wr1d : Wr1s;
    const float* br1 = z ? br1d : br1s;
    const float* Wr2 = z ? Wr2d : Wr2s;
    __shared__ float As[64][72];
    __shared__ float Bs[64][132];
    __shared__ int tokR[64];
    int tid = threadIdx.x;
    int tr = tid >> 5, tc = tid & 31;

    for (int mc = blockIdx.x; mc * 64 < rcnt; mc += gridDim.x) {
        __syncthreads();
        if (tid < 64) tokR[tid] = redo[min(mc * 64 + tid, rcnt - 1)];
        __syncthreads();
        float acc[8][4] = {};
        const float* wb = Wr1 + nt * 128;
        for (int k0 = 0; k0 < D; k0 += 64) {
            __syncthreads();
            {
                int row = tid >> 2, q = tid & 3;
                const float* xr = x + (size_t)tokR[row] * D + k0;
                #pragma unroll
                for (int i = 0; i < 4; i++) {
                    int f4i = q + 4 * i;
                    float4 v = *(const float4*)(xr + f4i * 4);
                    int k = f4i * 4;
                    As[k][row] = v.x; As[k+1][row] = v.y;
                    As[k+2][row] = v.z; As[k+3][row] = v.w;
                }
            }
            {
                #pragma unroll
                for (int i = 0; i < 8; i++) {
                    int idx = tid + 256 * i;
                    int k = idx >> 5, nq = idx & 31;
                    float4 v = *(const float4*)(wb + (size_t)(k0 + k) * D + nq * 4);
                    *(float4*)&Bs[k][nq * 4] = v;
                }
            }
            __syncthreads();
            #pragma unroll 4
            for (int kk = 0; kk < 64; kk++) {
                float4 a0 = *(const float4*)&As[kk][tr * 8];
                float4 a1 = *(const float4*)&As[kk][tr * 8 + 4];
                float4 bv = *(const float4*)&Bs[kk][tc * 4];
                float ar[8] = {a0.x,a0.y,a0.z,a0.w,a1.x,a1.y,a1.z,a1.w};
                #pragma unroll
                for (int i = 0; i < 8; i++) {
                    acc[i][0] += ar[i] * bv.x;
                    acc[i][1] += ar[i] * bv.y;
                    acc[i][2] += ar[i] * bv.z;
                    acc[i][3] += ar[i] * bv.w;
                }
            }
        }
        float lp[8][8] = {};
        #pragma unroll
        for (int j = 0; j < 4; j++) {
            int col = nt * 128 + tc * 4 + j;
            float b1 = br1[col];
            float w2[8];
            #pragma unroll
            for (int o = 0; o < 8; o++) w2[o] = Wr2[col * 8 + o];
            #pragma unroll
            for (int i = 0; i < 8; i++) {
                float h = gelu_f(acc[i][j] + b1);
                #pragma unroll
                for (int o = 0; o < 8; o++) lp[i][o] += h * w2[o];
            }
        }
        #pragma unroll
        for (int m = 16; m >= 1; m >>= 1) {
            #pragma unroll
            for (int i = 0; i < 8; i++)
                #pragma unroll
                for (int o = 0; o < 8; o++)
                    lp[i][o] += __shfl_xor(lp[i][o], m, 64);
        }
        if (tc == 0) {
            #pragma unroll
            for (int i = 0; i < 8; i++) {
                int slot = mc * 64 + tr * 8 + i;
                if (slot < rcnt) {
                    float* p = rlogp + ((size_t)slot * 8 + nt) * 16 + z * 8;
                    #pragma unroll
                    for (int o = 0; o < 8; o++) p[o] = lp[i][o];
                }
            }
        }
    }
}

// ---------------------------------------------------------------------------
__global__ __launch_bounds__(256) void k_amx3(
    const float* __restrict__ rlogp, const int* __restrict__ redo,
    const float* __restrict__ b2s, const float* __restrict__ b2d,
    int* __restrict__ tasks, int* __restrict__ ctrl, int tstr)
{
    int rcnt = min(ctrl[8], RCAP);
    for (int s = blockIdx.x * 256 + threadIdx.x; s < rcnt; s += gridDim.x * 256) {
        int tok = redo[s];
        float L[16] = {};
        for (int nt = 0; nt < 8; nt++) {
            const float* p = rlogp + ((size_t)s * 8 + nt) * 16;
            #pragma unroll
            for (int o = 0; o < 16; o++) L[o] += p[o];
        }
        float Ls[8], Ld[8];
        #pragma unroll
        for (int o = 0; o < 8; o++) { Ls[o] = L[o] + b2s[o]; Ld[o] = L[8 + o] + b2d[o]; }
        int ts = 0; float bv = Ls[0];
        #pragma unroll
        for (int o = 1; o < 8; o++) if (Ls[o] > bv) { bv = Ls[o]; ts = o; }
        int td = 0; bv = Ld[0];
        #pragma unroll
        for (int o = 1; o < 8; o++) if (Ld[o] > bv) { bv = Ld[o]; td = o; }
        emit_tasks(tok, ts, td, tasks, ctrl, tstr);
    }
}

// ---------------------------------------------------------------------------
// Job scheduler (parallel): flatten (e, ch, rt64) jobs in fixed order, deal
// contiguous runs of ceil(J/8) to the 8 XCDs.
// ---------------------------------------------------------------------------
__global__ void k_sched(const int* __restrict__ ctrl, int* __restrict__ xjob)
{
    __shared__ int seg[17];
    __shared__ int Jt[2];
    int tid = threadIdx.x;
    if (tid == 0) {
        int o = 0;
        for (int e = 0; e < 8; e++) {
            int nt2 = (ctrl[e] + 63) >> 6;
            seg[e * 2]     = o; o += nt2;
            seg[e * 2 + 1] = o; o += nt2;
        }
        seg[16] = o;
        Jt[0] = o; Jt[1] = (o + 7) >> 3;
    }
    __syncthreads();
    int J = Jt[0], target = Jt[1];
    for (int g = tid; g < J; g += blockDim.x) {
        int s = 0;
        while (s < 15 && seg[s + 1] <= g) s++;
        int e = s >> 1, ch = s & 1, rt = g - seg[s];
        int x = g / target; if (x > 7) x = 7;
        int pos = g - x * target;
        xjob[x * XJCAP + pos] = e | (ch << 3) | (rt << 4);
    }
    if (tid < 8) {
        int c = J - tid * target;
        if (c < 0) c = 0;
        if (c > target) c = target;
        xjob[8 * XJCAP + tid] = c;
    }
}

// ---------------------------------------------------------------------------
// Expert GEMM, fp16 MFMA. Job = 64 gathered rows x 1024 n-half. Per-wave
// tile 32 rows x 128 cols (acc[4] = 64 VGPR) -> launch_bounds(256,3) gives
// 3 blocks/CU. Staging via global_load_lds (pre-swizzled global source).
// ---------------------------------------------------------------------------
__global__ __launch_bounds__(256, 3) void k_expm(
    const f16* __restrict__ xh, const f16* __restrict__ We1T,
    const float* __restrict__ be1, const float* __restrict__ v_sum,
    const float* __restrict__ v_diff, const float* __restrict__ c_sum,
    const float* __restrict__ c_diff, const int* __restrict__ tasks,
    const int* __restrict__ counts, const int* __restrict__ xjob,
    float* __restrict__ ppS, float* __restrict__ ppD, int qn)
{
    int xcd  = blockIdx.x & 7;
    int slot = blockIdx.x >> 3;          // 0..255
    int nj = xjob[8 * XJCAP + xcd];
    int tstr = 2 * qn;

    __shared__ char smem[40960] __attribute__((aligned(16)));  // A 8K | B 32K
    __shared__ int tokL[64];
    __shared__ int flgL[64];
    __shared__ float redS[2][64];
    __shared__ float redD[2][64];

    int tid = threadIdx.x;
    int lane = tid & 63;
    int wid  = tid >> 6;
    int wr = wid >> 1, wc = wid & 1;
    int hi = lane >> 5, l31 = lane & 31;
    int sg = tid >> 3, sc = tid & 7;
    size_t goffc = (size_t)((sc * 16) ^ ((sg & 7) << 4));
    size_t b_off = (size_t)sg * 2048 + goffc;

    const char* xh_b = (const char*)xh;

    int axor = (l31 & 7) << 4;
    int kx[4];
    #pragma unroll
    for (int ks = 0; ks < 4; ks++) kx[ks] = (ks * 32 + hi * 16) ^ axor;
    int arow = (wr * 32 + l31) * 128;
    int nrow[4];
    #pragma unroll
    for (int ni = 0; ni < 4; ni++) nrow[ni] = 8192 + (wc * 128 + ni * 32 + l31) * 128;

    for (int j = slot; j < nj; j += 256) {
        int jv = xjob[xcd * XJCAP + j];
        int e  = jv & 7;
        int ch = (jv >> 3) & 1;
        int rt = jv >> 4;
        int cnt = counts[e];
        int r0 = rt * 64;
        const char* we1t_e = (const char*)(We1T + (size_t)e * DH * D);

        __syncthreads();
        if (tid < 64) {
            int idx = r0 + tid;
            int tv = tasks[e * tstr + min(idx, cnt - 1)];
            tokL[tid] = tv & 0xFFFF;
            flgL[tid] = (idx < cnt) ? ((tv >> 17) & 3) : 0;
        }
        __syncthreads();
        size_t asrc[2];
        #pragma unroll
        for (int i = 0; i < 2; i++)
            asrc[i] = (size_t)tokL[i * 32 + sg] * 2048 + goffc;

        float ss[16] = {}, sd[16] = {};

        for (int n0 = ch * 1024; n0 < ch * 1024 + 1024; n0 += 256) {
            f32x16 acc[4];
            #pragma unroll
            for (int ni = 0; ni < 4; ni++) acc[ni] = (f32x16)(0.0f);
            const char* bsrc = we1t_e + (size_t)n0 * 2048 + b_off;

            for (int k0 = 0; k0 < D; k0 += 64) {
                __syncthreads();
                gload16(xh_b + asrc[0] + k0 * 2, smem + wid * 1024);
                gload16(xh_b + asrc[1] + k0 * 2, smem + 4096 + wid * 1024);
                #pragma unroll
                for (int i = 0; i < 8; i++)
                    gload16(bsrc + (size_t)i * 32 * 2048 + k0 * 2,
                            smem + 8192 + i * 4096 + wid * 1024);
                __syncthreads();
                #pragma unroll
                for (int ks = 0; ks < 4; ks++) {
                    f16x8 av = *(const f16x8*)(smem + arow + kx[ks]);
                    #pragma unroll
                    for (int ni = 0; ni < 4; ni++) {
                        f16x8 bf = *(const f16x8*)(smem + nrow[ni] + kx[ks]);
                        acc[ni] = __builtin_amdgcn_mfma_f32_32x32x16_f16(av, bf, acc[ni], 0, 0, 0);
                    }
                }
            }
            #pragma unroll
            for (int ni = 0; ni < 4; ni++) {
                int col = n0 + wc * 128 + ni * 32 + l31;
                float b1 = be1[e * DH + col];
                float vs = v_sum[(size_t)e * DH + col];
                float vd = v_diff[(size_t)e * DH + col];
                #pragma unroll
                for (int r = 0; r < 16; r++) {
                    float h = gelu_fast(acc[ni][r] + b1);
                    ss[r] += h * vs;
                    sd[r] += h * vd;
                }
            }
        }

        #pragma unroll
        for (int m = 16; m >= 1; m >>= 1) {
            #pragma unroll
            for (int r = 0; r < 16; r++) {
                ss[r] += __shfl_xor(ss[r], m, 64);
                sd[r] += __shfl_xor(sd[r], m, 64);
            }
        }
        if (l31 == 0) {
            #pragma unroll
            for (int r = 0; r < 16; r++) {
                int row = wr * 32 + (r & 3) + 8 * (r >> 2) + 4 * hi;
                redS[wc][row] = ss[r];
                redD[wc][row] = sd[r];
            }
        }
        __syncthreads();
        if (tid < 64) {
            int idx = r0 + tid;
            if (idx < cnt) {
                int fl = flgL[tid];
                int tok = tokL[tid];
                float s = redS[0][tid] + redS[1][tid];
                float d = redD[0][tid] + redD[1][tid];
                if (ch == 0) { s += c_sum[e]; d += c_diff[e]; }
                if (fl & 1) ppS[ch * qn + tok] = s;
                if (fl & 2) ppD[ch * qn + tok] = d;
            }
        }
    }
}

// ---------------------------------------------------------------------------
__global__ __launch_bounds__(256) void k_fin(
    const float* __restrict__ ppS, const float* __restrict__ ppD,
    float* __restrict__ out, int tok0, int qn)
{
    int i = blockIdx.x * 256 + threadIdx.x;
    out[tok0 + i]      = ppS[i] + ppS[qn + i];
    out[BT + tok0 + i] = ppD[i] + ppD[qn + i];
}

// ---------------------------------------------------------------------------
extern "C" void kernel_launch(void* const* d_in, const int* in_sizes, int n_in,
                              void* d_out, int out_size, void* d_ws, size_t ws_size,
                              hipStream_t stream)
{
    const float* a      = (const float*)d_in[0];
    const float* b      = (const float*)d_in[1];
    const float* W_in   = (const float*)d_in[2];
    const float* b_in   = (const float*)d_in[3];
    const float* ln_g   = (const float*)d_in[4];
    const float* ln_b   = (const float*)d_in[5];
    const float* Wr1s   = (const float*)d_in[6];
    const float* br1s   = (const float*)d_in[7];
    const float* Wr2s   = (const float*)d_in[8];
    const float* br2s   = (const float*)d_in[9];
    const float* Wr1d   = (const float*)d_in[10];
    const float* br1d   = (const float*)d_in[11];
    const float* Wr2d   = (const float*)d_in[12];
    const float* br2d   = (const float*)d_in[13];
    const float* We1    = (const float*)d_in[14];
    const float* be1    = (const float*)d_in[15];
    const float* We2    = (const float*)d_in[16];
    const float* be2    = (const float*)d_in[17];
    const float* w_sum  = (const float*)d_in[18];
    const float* bs     = (const float*)d_in[19];
    const float* w_diff = (const float*)d_in[20];
    const float* bd     = (const float*)d_in[21];
    float* out = (float*)d_out;

    // pick largest qn whose workspace plan fits
    auto plan = [&](size_t qn) -> size_t {
        size_t o = 0;
        auto al = [&](size_t bytes) { o = (o + bytes + 255) & ~(size_t)255; };
        al((size_t)NT * DH * 4); al((size_t)NT * DH * 4); al(64); al(64);
        al(qn * D * 4); al(qn * D * 2); al(qn * 64 * 4);
        al((size_t)RCAP * 128 * 4); al(qn * 4); al((size_t)NT * 2 * qn * 4);
        al(64); al((size_t)(8 * XJCAP + 8) * 4);
        al(2 * qn * 4); al(2 * qn * 4);
        al((size_t)NT * DH * D * 2); al((size_t)2048 * 1024 * 2);
        al(2048 * 4); al(2048 * 8 * 4);
        return o;
    };
    int qn = 65536;
    while (qn > 16384 && plan((size_t)qn) > ws_size) qn >>= 1;
    if (plan((size_t)qn) > ws_size) {
        hipMemsetAsync(d_out, 0, (size_t)out_size * 4, stream);
        return;
    }
    int npass = BT / qn;
    int tstr = 2 * qn;

    char* w = (char*)d_ws;
    size_t off = 0;
    auto alloc = [&](size_t bytes) -> char* {
        char* p = w + off;
        off = (off + bytes + 255) & ~(size_t)255;
        return p;
    };
    float* v_sum   = (float*)alloc((size_t)NT * DH * 4);
    float* v_diff  = (float*)alloc((size_t)NT * DH * 4);
    float* c_sum   = (float*)alloc(64);
    float* c_diff  = (float*)alloc(64);
    float* x       = (float*)alloc((size_t)qn * D * 4);
    f16*   xh      = (f16*)alloc((size_t)qn * D * 2);
    float* part    = (float*)alloc((size_t)qn * 64 * 4);
    float* rlogp   = (float*)alloc((size_t)RCAP * 128 * 4);
    int*   redo    = (int*)alloc((size_t)qn * 4);
    int*   tasks   = (int*)alloc((size_t)NT * 2 * qn * 4);
    int*   ctrl    = (int*)alloc(64);
    int*   xjob    = (int*)alloc((size_t)(8 * XJCAP + 8) * 4);
    float* ppS     = (float*)alloc((size_t)2 * qn * 4);
    float* ppD     = (float*)alloc((size_t)2 * qn * 4);
    f16*   We1T    = (f16*)alloc((size_t)NT * DH * D * 2);
    f16*   Wr1Tf   = (f16*)alloc((size_t)2048 * 1024 * 2);
    float* br1f    = (float*)alloc((size_t)2048 * 4);
    float* w2f     = (float*)alloc((size_t)2048 * 8 * 4);

    k_cvt <<<dim3(4096), dim3(256), 0, stream>>>(We1, We1T);
    k_cvtR<<<dim3(512),  dim3(256), 0, stream>>>(Wr1s, Wr1d, Wr1Tf);
    k_fuse<<<dim3(1),    dim3(256), 0, stream>>>(br1s, br1d, Wr2s, Wr2d, br1f, w2f);
    k_prev<<<dim3(4097), dim3(256), 0, stream>>>(We2, w_sum, w_diff, be2, bs, bd,
                                                 v_sum, v_diff, c_sum, c_diff);
    for (int q = 0; q < npass; q++) {
        int tok0 = q * qn;
        k_enc<<<dim3(qn / 64), dim3(256), 0, stream>>>(a, b, W_in, b_in, ln_g, ln_b, x, xh, tok0);
        k_rtrm<<<dim3(qn / 64 * 8), dim3(256), 0, stream>>>(xh, Wr1Tf, br1f, w2f, part);
        hipMemsetAsync(ctrl, 0, 64, stream);
        k_amx2<<<dim3(qn / 256), dim3(256), 0, stream>>>(part, br2s, br2d, tasks, ctrl, redo, tstr);
        k_redo<<<dim3(64, 8, 2), dim3(256), 0, stream>>>(x, Wr1s, br1s, Wr2s, Wr1d, br1d, Wr2d,
                                                         redo, ctrl, rlogp);
        k_amx3<<<dim3(16), dim3(256), 0, stream>>>(rlogp, redo, br2s, br2d, tasks, ctrl, tstr);
        k_sched<<<dim3(1), dim3(256), 0, stream>>>(ctrl, xjob);
        k_expm<<<dim3(2048), dim3(256), 0, stream>>>(xh, We1T, be1, v_sum, v_diff,
                                                     c_sum, c_diff, tasks, ctrl, xjob,
                                                     ppS, ppD, qn);
        k_fin<<<dim3(qn / 256), dim3(256), 0, stream>>>(ppS, ppD, out, tok0, qn);
    }
}

// Round 7
// 2474.229 us; speedup vs baseline: 6.3551x; 1.1729x over previous
//
#include <hip/hip_runtime.h>
#include <math.h>

// ============================================================================
// PureTriXButterfly — R7.
// - k_expm: reverted to R5-proven geometry (M=128 rows/job, reg-staging,
//   FETCH ~270MB, 305us) — R6's M=64 + gload_lds halved B-reuse and went
//   HBM-bound (FETCH 592MB, 505us). Keeps R5/R6 balanced xjob scheduler.
// - k_redo: DELTA 0.025->0.010 (>=10 sigma of fp16 logit error) and split
//   per-router redo lists (token marginal in one router no longer recomputes
//   the other; both-marginal resolved via adx cross-link). ~4x less work.
// - Routing semantics unchanged otherwise (fp16+margin redo; R3-R6 passed).
// ============================================================================

#define BT 65536
#define D 1024
#define NT 8
#define DH 2048
#define RCAP 8192
#define DELTA 0.010f
#define XJCAP 768

typedef _Float16 f16;
typedef _Float16 f16x8 __attribute__((ext_vector_type(8)));
typedef _Float16 f16x4 __attribute__((ext_vector_type(4)));
typedef float f32x16 __attribute__((ext_vector_type(16)));

__device__ __forceinline__ float gelu_f(float v) {
    return 0.5f * v * (1.0f + erff(v * 0.70710678118654752440f));
}

// fast exact-GELU via A&S 7.1.26 erf (|eps| <= 1.5e-7)
__device__ __forceinline__ float gelu_fast(float x) {
    float ax = fabsf(x) * 0.70710678118654752440f;
    float t = __builtin_amdgcn_rcpf(1.0f + 0.3275911f * ax);
    float p = t * (0.254829592f + t * (-0.284496736f + t * (1.421413741f +
              t * (-1.453152027f + t * 1.061405429f))));
    float er = 1.0f - p * __expf(-ax * ax);
    er = copysignf(er, x);
    return 0.5f * x * (1.0f + er);
}

__device__ __forceinline__ void gload16(const void* g, void* l) {
    __builtin_amdgcn_global_load_lds(
        (const __attribute__((address_space(1))) void*)g,
        (__attribute__((address_space(3))) void*)l, 16, 0, 0);
}

// ---------------------------------------------------------------------------
__global__ __launch_bounds__(256) void k_prev(
    const float* __restrict__ We2, const float* __restrict__ w_sum,
    const float* __restrict__ w_diff, const float* __restrict__ be2,
    const float* __restrict__ bs, const float* __restrict__ bd,
    float* __restrict__ v_sum, float* __restrict__ v_diff,
    float* __restrict__ c_sum, float* __restrict__ c_diff)
{
    int bid = blockIdx.x;
    if (bid < 4096) {
        int row  = bid * 4 + (threadIdx.x >> 6);
        int lane = threadIdx.x & 63;
        const float* r = We2 + (size_t)row * D;
        float s1 = 0.f, s2 = 0.f;
        #pragma unroll
        for (int i = 0; i < 4; i++) {
            int o4 = (lane + 64 * i) * 4;
            float4 w = *(const float4*)(r + o4);
            float4 u = *(const float4*)(w_sum + o4);
            float4 v = *(const float4*)(w_diff + o4);
            s1 += w.x*u.x + w.y*u.y + w.z*u.z + w.w*u.w;
            s2 += w.x*v.x + w.y*v.y + w.z*v.z + w.w*v.w;
        }
        #pragma unroll
        for (int m = 32; m >= 1; m >>= 1) {
            s1 += __shfl_xor(s1, m, 64);
            s2 += __shfl_xor(s2, m, 64);
        }
        if (lane == 0) { v_sum[row] = s1; v_diff[row] = s2; }
    } else {
        int t = threadIdx.x;
        if (t < 8) {
            float s = 0.f; const float* r = be2 + t * D;
            for (int k = 0; k < D; k++) s += r[k] * w_sum[k];
            c_sum[t] = s + bs[0];
        } else if (t < 16) {
            int tt = t - 8;
            float s = 0.f; const float* r = be2 + tt * D;
            for (int k = 0; k < D; k++) s += r[k] * w_diff[k];
            c_diff[tt] = s + bd[0];
        }
    }
}

// ---------------------------------------------------------------------------
__global__ __launch_bounds__(256) void k_cvt(
    const float* __restrict__ We1, f16* __restrict__ We1T)
{
    __shared__ float tile[64][65];
    int b = blockIdx.x;
    int e = b >> 9, rem = b & 511;
    int kt = rem >> 5, nt = rem & 31;
    int tid = threadIdx.x;
    const float* src = We1 + ((size_t)e * D + kt * 64) * DH + nt * 64;
    #pragma unroll
    for (int i = 0; i < 16; i++) {
        int idx = tid + 256 * i;
        int kk = idx >> 6, nn = idx & 63;
        tile[kk][nn] = src[(size_t)kk * DH + nn];
    }
    __syncthreads();
    f16* dst = We1T + ((size_t)e * DH + nt * 64) * D + kt * 64;
    #pragma unroll
    for (int i = 0; i < 16; i++) {
        int idx = tid + 256 * i;
        int nn = idx >> 6, kk = idx & 63;
        dst[(size_t)nn * D + kk] = (f16)tile[kk][nn];
    }
}

// ---------------------------------------------------------------------------
__global__ __launch_bounds__(256) void k_cvtR(
    const float* __restrict__ Wr1s, const float* __restrict__ Wr1d,
    f16* __restrict__ Wr1Tf)
{
    __shared__ float tile[64][65];
    int b = blockIdx.x;                  // 512
    int z = b >> 8, rem = b & 255;
    int kt = rem >> 4, nt2 = rem & 15;
    int tid = threadIdx.x;
    const float* W = z ? Wr1d : Wr1s;
    const float* src = W + (size_t)(kt * 64) * 1024 + nt2 * 64;
    #pragma unroll
    for (int i = 0; i < 16; i++) {
        int idx = tid + 256 * i;
        int kk = idx >> 6, nn = idx & 63;
        tile[kk][nn] = src[(size_t)kk * 1024 + nn];
    }
    __syncthreads();
    f16* dst = Wr1Tf + (size_t)(z * 1024 + nt2 * 64) * 1024 + kt * 64;
    #pragma unroll
    for (int i = 0; i < 16; i++) {
        int idx = tid + 256 * i;
        int nn = idx >> 6, kk = idx & 63;
        dst[(size_t)nn * 1024 + kk] = (f16)tile[kk][nn];
    }
}

// ---------------------------------------------------------------------------
__global__ __launch_bounds__(256) void k_fuse(
    const float* __restrict__ br1s, const float* __restrict__ br1d,
    const float* __restrict__ Wr2s, const float* __restrict__ Wr2d,
    float* __restrict__ br1f, float* __restrict__ w2f)
{
    int tid = threadIdx.x;
    for (int n = tid; n < 2048; n += 256) {
        br1f[n] = (n < 1024) ? br1s[n] : br1d[n - 1024];
        const float* src = (n < 1024) ? (Wr2s + (size_t)n * 8)
                                      : (Wr2d + (size_t)(n - 1024) * 8);
        #pragma unroll
        for (int o = 0; o < 8; o++) w2f[(size_t)n * 8 + o] = src[o];
    }
}

// ---------------------------------------------------------------------------
__global__ __launch_bounds__(256) void k_enc(
    const float* __restrict__ a, const float* __restrict__ b,
    const float* __restrict__ W_in, const float* __restrict__ b_in,
    const float* __restrict__ ln_g, const float* __restrict__ ln_b,
    float* __restrict__ x, f16* __restrict__ xh, int tok0)
{
    __shared__ float x0[64][24];
    __shared__ float red[8];
    int tid = threadIdx.x;
    float4 Wc[24];
    #pragma unroll
    for (int f = 0; f < 24; f++) Wc[f] = *(const float4*)(W_in + f * D + tid * 4);
    float4 bi = *(const float4*)(b_in + tid * 4);
    float4 gg = *(const float4*)(ln_g + tid * 4);
    float4 bb = *(const float4*)(ln_b + tid * 4);
    int base = tok0 + blockIdx.x * 64;

    for (int idx = tid; idx < 64 * 12; idx += 256) {
        int t = idx / 12, q = idx - t * 12;
        int fr = q % 6;
        float in = (q < 6) ? a[base + t] : b[base + t];
        float ang = (in * 0.39269908169872414f) * (float)(1 << fr);
        int off = (q < 6) ? 0 : 12;
        x0[t][off + fr]     = sinf(ang);
        x0[t][off + 6 + fr] = cosf(ang);
    }
    __syncthreads();

    int lane = tid & 63, wid = tid >> 6;
    for (int t = 0; t < 64; t++) {
        float4 p = bi;
        #pragma unroll
        for (int f = 0; f < 24; f++) {
            float xv = x0[t][f];
            p.x += xv * Wc[f].x; p.y += xv * Wc[f].y;
            p.z += xv * Wc[f].z; p.w += xv * Wc[f].w;
        }
        float s1 = p.x + p.y + p.z + p.w;
        float s2 = p.x*p.x + p.y*p.y + p.z*p.z + p.w*p.w;
        #pragma unroll
        for (int m = 32; m >= 1; m >>= 1) {
            s1 += __shfl_xor(s1, m, 64);
            s2 += __shfl_xor(s2, m, 64);
        }
        if (lane == 0) { red[wid] = s1; red[4 + wid] = s2; }
        __syncthreads();
        float mean = (red[0] + red[1] + red[2] + red[3]) * (1.f / 1024.f);
        float ms   = (red[4] + red[5] + red[6] + red[7]) * (1.f / 1024.f);
        float inv  = 1.f / sqrtf(ms - mean * mean + 1e-5f);
        float4 o;
        o.x = gelu_f((p.x - mean) * inv * gg.x + bb.x);
        o.y = gelu_f((p.y - mean) * inv * gg.y + bb.y);
        o.z = gelu_f((p.z - mean) * inv * gg.z + bb.z);
        o.w = gelu_f((p.w - mean) * inv * gg.w + bb.w);
        size_t row = (size_t)(blockIdx.x * 64 + t);
        *(float4*)(x + row * D + tid * 4) = o;
        f16x4 h; h[0] = (f16)o.x; h[1] = (f16)o.y; h[2] = (f16)o.z; h[3] = (f16)o.w;
        *(f16x4*)(xh + row * D + tid * 4) = h;
        __syncthreads();
    }
}

// ---------------------------------------------------------------------------
// Fused router, fp16 MFMA (R6 version, gload_lds staging).
// ---------------------------------------------------------------------------
__global__ __launch_bounds__(256, 3) void k_rtrm(
    const f16* __restrict__ xh, const f16* __restrict__ Wr1Tf,
    const float* __restrict__ br1f, const float* __restrict__ w2f,
    float* __restrict__ part)
{
    __shared__ char smem[40960] __attribute__((aligned(16)));
    int bid = blockIdx.x;
    int ntile = bid & 7;
    int ttile = bid >> 3;
    int tid = threadIdx.x;
    int lane = tid & 63, wid = tid >> 6;
    int hi = lane >> 5, l31 = lane & 31;
    int sg = tid >> 3, sc = tid & 7;

    const char* xb = (const char*)xh + (size_t)(ttile * 64) * 2048;
    const char* wb = (const char*)Wr1Tf + (size_t)(ntile * 256) * 2048;
    size_t goff = (size_t)sg * 2048 + (size_t)((sc * 16) ^ ((sg & 7) << 4));

    int axor = (l31 & 7) << 4;
    int kx[4];
    #pragma unroll
    for (int ks = 0; ks < 4; ks++) kx[ks] = (ks * 32 + hi * 16) ^ axor;
    int arow[2], brow[2];
    #pragma unroll
    for (int mi = 0; mi < 2; mi++) arow[mi] = (wid * 64 + mi * 32 + l31) * 128;
    #pragma unroll
    for (int ni = 0; ni < 2; ni++) brow[ni] = 32768 + (ni * 32 + l31) * 128;

    f32x16 acc[2][2];
    #pragma unroll
    for (int mi = 0; mi < 2; mi++)
        #pragma unroll
        for (int ni = 0; ni < 2; ni++) acc[mi][ni] = (f32x16)(0.0f);

    for (int k0 = 0; k0 < 1024; k0 += 64) {
        __syncthreads();
        #pragma unroll
        for (int i = 0; i < 8; i++)
            gload16(wb + (size_t)i * 32 * 2048 + k0 * 2 + goff,
                    smem + i * 4096 + wid * 1024);
        #pragma unroll
        for (int i = 0; i < 2; i++)
            gload16(xb + (size_t)i * 32 * 2048 + k0 * 2 + goff,
                    smem + 32768 + i * 4096 + wid * 1024);
        __syncthreads();
        #pragma unroll
        for (int ks = 0; ks < 4; ks++) {
            f16x8 a0 = *(const f16x8*)(smem + arow[0] + kx[ks]);
            f16x8 a1 = *(const f16x8*)(smem + arow[1] + kx[ks]);
            f16x8 b0 = *(const f16x8*)(smem + brow[0] + kx[ks]);
            f16x8 b1 = *(const f16x8*)(smem + brow[1] + kx[ks]);
            acc[0][0] = __builtin_amdgcn_mfma_f32_32x32x16_f16(a0, b0, acc[0][0], 0, 0, 0);
            acc[0][1] = __builtin_amdgcn_mfma_f32_32x32x16_f16(a0, b1, acc[0][1], 0, 0, 0);
            acc[1][0] = __builtin_amdgcn_mfma_f32_32x32x16_f16(a1, b0, acc[1][0], 0, 0, 0);
            acc[1][1] = __builtin_amdgcn_mfma_f32_32x32x16_f16(a1, b1, acc[1][1], 0, 0, 0);
        }
    }

    float lp[2][8] = {};
    #pragma unroll
    for (int mi = 0; mi < 2; mi++) {
        #pragma unroll
        for (int r = 0; r < 16; r++) {
            int nl = wid * 64 + mi * 32 + (r & 3) + 8 * (r >> 2) + 4 * hi;
            int gn = ntile * 256 + nl;
            float b1 = br1f[gn];
            float4 wa = *(const float4*)(w2f + (size_t)gn * 8);
            float4 wc = *(const float4*)(w2f + (size_t)gn * 8 + 4);
            float h0 = gelu_fast(acc[mi][0][r] + b1);
            float h1 = gelu_fast(acc[mi][1][r] + b1);
            lp[0][0] += h0*wa.x; lp[0][1] += h0*wa.y;
            lp[0][2] += h0*wa.z; lp[0][3] += h0*wa.w;
            lp[0][4] += h0*wc.x; lp[0][5] += h0*wc.y;
            lp[0][6] += h0*wc.z; lp[0][7] += h0*wc.w;
            lp[1][0] += h1*wa.x; lp[1][1] += h1*wa.y;
            lp[1][2] += h1*wa.z; lp[1][3] += h1*wa.w;
            lp[1][4] += h1*wc.x; lp[1][5] += h1*wc.y;
            lp[1][6] += h1*wc.z; lp[1][7] += h1*wc.w;
        }
    }
    #pragma unroll
    for (int ni = 0; ni < 2; ni++)
        #pragma unroll
        for (int o = 0; o < 8; o++)
            lp[ni][o] += __shfl_xor(lp[ni][o], 32, 64);
    __syncthreads();
    float* redf = (float*)smem;
    if (hi == 0) {
        #pragma unroll
        for (int ni = 0; ni < 2; ni++)
            #pragma unroll
            for (int o = 0; o < 8; o++)
                redf[(wid * 64 + ni * 32 + l31) * 8 + o] = lp[ni][o];
    }
    __syncthreads();
    for (int idx = tid; idx < 512; idx += 256) {
        int tok = idx >> 3, o = idx & 7;
        float s = ((redf[(0 * 64 + tok) * 8 + o]  + redf[(1 * 64 + tok) * 8 + o])
                 +  redf[(2 * 64 + tok) * 8 + o]) + redf[(3 * 64 + tok) * 8 + o];
        part[((size_t)(ttile * 64 + tok) * 8 + ntile) * 8 + o] = s;
    }
}

// ---------------------------------------------------------------------------
__device__ __forceinline__ void emit_tasks(int tok, int ts, int td,
                                           int* tasks, int* cnts, int tstr)
{
    if (ts == td) {
        int s = atomicAdd(&cnts[ts], 1);
        tasks[ts * tstr + s] = tok | (3 << 17);
    } else {
        int s1 = atomicAdd(&cnts[ts], 1);
        tasks[ts * tstr + s1] = tok | (1 << 17);
        int s2 = atomicAdd(&cnts[td], 1);
        tasks[td * tstr + s2] = tok | (2 << 17);
    }
}

// ---------------------------------------------------------------------------
// Argmax + margin. Confident -> emit; marginal router -> its redo list.
// ctrl[0..7]=expert counts, ctrl[8]=redoS count, ctrl[9]=redoD count.
// redoS entry: tok | fp16_ad<<17 | dMarg<<20 ; redoD: tok | fp16_as<<17 | sMarg<<20.
// ---------------------------------------------------------------------------
__global__ __launch_bounds__(256) void k_amx2(
    const float* __restrict__ part, const float* __restrict__ b2s,
    const float* __restrict__ b2d, int* __restrict__ tasks,
    int* __restrict__ ctrl, int* __restrict__ redoS, int* __restrict__ redoD,
    int tstr)
{
    int i = blockIdx.x * 256 + threadIdx.x;
    const float* p = part + (size_t)i * 64;
    float Ls[8], Ld[8];
    #pragma unroll
    for (int o = 0; o < 8; o++) { Ls[o] = b2s[o]; Ld[o] = b2d[o]; }
    #pragma unroll
    for (int nt = 0; nt < 4; nt++)
        #pragma unroll
        for (int o = 0; o < 8; o++) Ls[o] += p[nt * 8 + o];
    #pragma unroll
    for (int nt = 4; nt < 8; nt++)
        #pragma unroll
        for (int o = 0; o < 8; o++) Ld[o] += p[nt * 8 + o];

    int as = 0; float m1s = Ls[0];
    #pragma unroll
    for (int o = 1; o < 8; o++) if (Ls[o] > m1s) { m1s = Ls[o]; as = o; }
    float m2s = -1e30f;
    #pragma unroll
    for (int o = 0; o < 8; o++) if (o != as && Ls[o] > m2s) m2s = Ls[o];
    int ad = 0; float m1d = Ld[0];
    #pragma unroll
    for (int o = 1; o < 8; o++) if (Ld[o] > m1d) { m1d = Ld[o]; ad = o; }
    float m2d = -1e30f;
    #pragma unroll
    for (int o = 0; o < 8; o++) if (o != ad && Ld[o] > m2d) m2d = Ld[o];

    bool sM = (m1s - m2s) < DELTA;
    bool dM = (m1d - m2d) < DELTA;
    if (!sM && !dM) { emit_tasks(i, as, ad, tasks, ctrl, tstr); return; }
    int posS = -1, posD = -1;
    if (sM) { posS = atomicAdd(&ctrl[8], 1); if (posS >= RCAP) { sM = false; posS = -1; } }
    if (dM) { posD = atomicAdd(&ctrl[9], 1); if (posD >= RCAP) { dM = false; posD = -1; } }
    if (!sM && !dM) { emit_tasks(i, as, ad, tasks, ctrl, tstr); return; }
    if (sM) redoS[posS] = i | (ad << 17) | ((dM ? 1 : 0) << 20);
    if (dM) redoD[posD] = i | (as << 17) | ((sM ? 1 : 0) << 20);
}

// ---------------------------------------------------------------------------
// Exact fp32 router recompute; z=0 -> sum router over redoS, z=1 -> diff
// router over redoD. Writes rlogp{S,D}[slot][nt*8+o].
// ---------------------------------------------------------------------------
__global__ __launch_bounds__(256) void k_redo(
    const float* __restrict__ x,
    const float* __restrict__ Wr1s, const float* __restrict__ br1s,
    const float* __restrict__ Wr2s,
    const float* __restrict__ Wr1d, const float* __restrict__ br1d,
    const float* __restrict__ Wr2d,
    const int* __restrict__ redoS, const int* __restrict__ redoD,
    const int* __restrict__ ctrl,
    float* __restrict__ rlogpS, float* __restrict__ rlogpD)
{
    int nt = blockIdx.y, z = blockIdx.z;
    int rcnt = min(ctrl[8 + z], RCAP);
    const float* Wr1 = z ? Wr1d : Wr1s;
    const float* br1 = z ? br1d : br1s;
    const float* Wr2 = z ? Wr2d : Wr2s;
    const int* list = z ? redoD : redoS;
    float* rlogp = z ? rlogpD : rlogpS;
    __shared__ float As[64][72];
    __shared__ float Bs[64][132];
    __shared__ int tokR[64];
    int tid = threadIdx.x;
    int tr = tid >> 5, tc = tid & 31;

    for (int mc = blockIdx.x; mc * 64 < rcnt; mc += gridDim.x) {
        __syncthreads();
        if (tid < 64) tokR[tid] = list[min(mc * 64 + tid, rcnt - 1)] & 0xFFFF;
        __syncthreads();
        float acc[8][4] = {};
        const float* wb = Wr1 + nt * 128;
        for (int k0 = 0; k0 < D; k0 += 64) {
            __syncthreads();
            {
                int row = tid >> 2, q = tid & 3;
                const float* xr = x + (size_t)tokR[row] * D + k0;
                #pragma unroll
                for (int i = 0; i < 4; i++) {
                    int f4i = q + 4 * i;
                    float4 v = *(const float4*)(xr + f4i * 4);
                    int k = f4i * 4;
                    As[k][row] = v.x; As[k+1][row] = v.y;
                    As[k+2][row] = v.z; As[k+3][row] = v.w;
                }
            }
            {
                #pragma unroll
                for (int i = 0; i < 8; i++) {
                    int idx = tid + 256 * i;
                    int k = idx >> 5, nq = idx & 31;
                    float4 v = *(const float4*)(wb + (size_t)(k0 + k) * D + nq * 4);
                    *(float4*)&Bs[k][nq * 4] = v;
                }
            }
            __syncthreads();
            #pragma unroll 4
            for (int kk = 0; kk < 64; kk++) {
                float4 a0 = *(const float4*)&As[kk][tr * 8];
                float4 a1 = *(const float4*)&As[kk][tr * 8 + 4];
                float4 bv = *(const float4*)&Bs[kk][tc * 4];
                float ar[8] = {a0.x,a0.y,a0.z,a0.w,a1.x,a1.y,a1.z,a1.w};
                #pragma unroll
                for (int i = 0; i < 8; i++) {
                    acc[i][0] += ar[i] * bv.x;
                    acc[i][1] += ar[i] * bv.y;
                    acc[i][2] += ar[i] * bv.z;
                    acc[i][3] += ar[i] * bv.w;
                }
            }
        }
        float lp[8][8] = {};
        #pragma unroll
        for (int j = 0; j < 4; j++) {
            int col = nt * 128 + tc * 4 + j;
            float b1 = br1[col];
            float w2[8];
            #pragma unroll
            for (int o = 0; o < 8; o++) w2[o] = Wr2[col * 8 + o];
            #pragma unroll
            for (int i = 0; i < 8; i++) {
                float h = gelu_f(acc[i][j] + b1);
                #pragma unroll
                for (int o = 0; o < 8; o++) lp[i][o] += h * w2[o];
            }
        }
        #pragma unroll
        for (int m = 16; m >= 1; m >>= 1) {
            #pragma unroll
            for (int i = 0; i < 8; i++)
                #pragma unroll
                for (int o = 0; o < 8; o++)
                    lp[i][o] += __shfl_xor(lp[i][o], m, 64);
        }
        if (tc == 0) {
            #pragma unroll
            for (int i = 0; i < 8; i++) {
                int slot = mc * 64 + tr * 8 + i;
                if (slot < rcnt) {
                    float* p = rlogp + (size_t)slot * 64 + nt * 8;
                    #pragma unroll
                    for (int o = 0; o < 8; o++) p[o] = lp[i][o];
                }
            }
        }
    }
}

// ---------------------------------------------------------------------------
// D-list argmax: exact td -> adx[tok]; emit if sum side was confident.
// ---------------------------------------------------------------------------
__global__ __launch_bounds__(256) void k_amx3d(
    const float* __restrict__ rlogpD, const int* __restrict__ redoD,
    const float* __restrict__ b2d, int* __restrict__ tasks,
    int* __restrict__ ctrl, int* __restrict__ adx, int tstr)
{
    int rcnt = min(ctrl[9], RCAP);
    for (int s = blockIdx.x * 256 + threadIdx.x; s < rcnt; s += gridDim.x * 256) {
        int entry = redoD[s];
        int tok = entry & 0xFFFF;
        float L[8] = {};
        for (int nt = 0; nt < 8; nt++) {
            const float* p = rlogpD + (size_t)s * 64 + nt * 8;
            #pragma unroll
            for (int o = 0; o < 8; o++) L[o] += p[o];
        }
        #pragma unroll
        for (int o = 0; o < 8; o++) L[o] += b2d[o];
        int td = 0; float bv = L[0];
        #pragma unroll
        for (int o = 1; o < 8; o++) if (L[o] > bv) { bv = L[o]; td = o; }
        adx[tok] = td;
        if (!((entry >> 20) & 1))
            emit_tasks(tok, (entry >> 17) & 7, td, tasks, ctrl, tstr);
    }
}

// ---------------------------------------------------------------------------
// S-list argmax: exact ts; td from adx (if diff was marginal) else fp16.
// ---------------------------------------------------------------------------
__global__ __launch_bounds__(256) void k_amx3s(
    const float* __restrict__ rlogpS, const int* __restrict__ redoS,
    const float* __restrict__ b2s, int* __restrict__ tasks,
    int* __restrict__ ctrl, const int* __restrict__ adx, int tstr)
{
    int rcnt = min(ctrl[8], RCAP);
    for (int s = blockIdx.x * 256 + threadIdx.x; s < rcnt; s += gridDim.x * 256) {
        int entry = redoS[s];
        int tok = entry & 0xFFFF;
        float L[8] = {};
        for (int nt = 0; nt < 8; nt++) {
            const float* p = rlogpS + (size_t)s * 64 + nt * 8;
            #pragma unroll
            for (int o = 0; o < 8; o++) L[o] += p[o];
        }
        #pragma unroll
        for (int o = 0; o < 8; o++) L[o] += b2s[o];
        int ts = 0; float bv = L[0];
        #pragma unroll
        for (int o = 1; o < 8; o++) if (L[o] > bv) { bv = L[o]; ts = o; }
        int td = ((entry >> 20) & 1) ? adx[tok] : ((entry >> 17) & 7);
        emit_tasks(tok, ts, td, tasks, ctrl, tstr);
    }
}

// ---------------------------------------------------------------------------
// Job scheduler (parallel): flatten (e, ch, rt128) jobs in fixed order, deal
// contiguous runs of ceil(J/8) to the 8 XCDs.
// ---------------------------------------------------------------------------
__global__ void k_sched(const int* __restrict__ ctrl, int* __restrict__ xjob)
{
    __shared__ int seg[17];
    __shared__ int Jt[2];
    int tid = threadIdx.x;
    if (tid == 0) {
        int o = 0;
        for (int e = 0; e < 8; e++) {
            int nt2 = (ctrl[e] + 127) >> 7;
            seg[e * 2]     = o; o += nt2;
            seg[e * 2 + 1] = o; o += nt2;
        }
        seg[16] = o;
        Jt[0] = o; Jt[1] = (o + 7) >> 3;
    }
    __syncthreads();
    int J = Jt[0], target = Jt[1];
    for (int g = tid; g < J; g += blockDim.x) {
        int s = 0;
        while (s < 15 && seg[s + 1] <= g) s++;
        int e = s >> 1, ch = s & 1, rt = g - seg[s];
        int x = g / target; if (x > 7) x = 7;
        int pos = g - x * target;
        xjob[x * XJCAP + pos] = e | (ch << 3) | (rt << 4);
    }
    if (tid < 8) {
        int c = J - tid * target;
        if (c < 0) c = 0;
        if (c > target) c = target;
        xjob[8 * XJCAP + tid] = c;
    }
}

// ---------------------------------------------------------------------------
// Expert GEMM, fp16 MFMA — R5-proven geometry (M=128 rows/job, reg staging),
// jobs from balanced per-XCD lists (xcd = bid&7, slot = bid>>3).
// ---------------------------------------------------------------------------
__global__ __launch_bounds__(256) void k_expm(
    const f16* __restrict__ xh, const f16* __restrict__ We1T,
    const float* __restrict__ be1, const float* __restrict__ v_sum,
    const float* __restrict__ v_diff, const float* __restrict__ c_sum,
    const float* __restrict__ c_diff, const int* __restrict__ tasks,
    const int* __restrict__ counts, const int* __restrict__ xjob,
    float* __restrict__ ppS, float* __restrict__ ppD, int qn)
{
    int xcd  = blockIdx.x & 7;
    int slot = blockIdx.x >> 3;
    int nj = xjob[8 * XJCAP + xcd];
    int tstr = 2 * qn;

    __shared__ char smem[49152] __attribute__((aligned(16)));
    __shared__ int tokL[128];
    __shared__ int flgL[128];
    __shared__ float redS[2][128];
    __shared__ float redD[2][128];

    int tid = threadIdx.x;
    int lane = tid & 63;
    int wid  = tid >> 6;
    int wr = wid >> 1, wc = wid & 1;
    int hi = lane >> 5, l31 = lane & 31;
    int sg = tid >> 3, sc = tid & 7;
    int stoff = sg * 128 + ((sc * 16) ^ ((sg & 7) << 4));

    const char* xh_b = (const char*)xh;

    int axor = (l31 & 7) << 4;
    int kx[4];
    #pragma unroll
    for (int ks = 0; ks < 4; ks++) kx[ks] = (ks * 32 + hi * 16) ^ axor;
    int arow[2], nrow[4];
    #pragma unroll
    for (int mi = 0; mi < 2; mi++) arow[mi] = (wr * 64 + mi * 32 + l31) * 128;
    #pragma unroll
    for (int ni = 0; ni < 4; ni++) nrow[ni] = 16384 + (wc * 128 + ni * 32 + l31) * 128;

    for (int j = slot; j < nj; j += 256) {
        int jv = xjob[xcd * XJCAP + j];
        int e  = jv & 7;
        int ch = (jv >> 3) & 1;
        int rt = jv >> 4;
        int cnt = counts[e];
        int r0 = rt * 128;
        const char* we1t_e = (const char*)(We1T + (size_t)e * DH * D);
        size_t bs_off = (size_t)sg * (D * 2) + sc * 16;

        __syncthreads();
        if (tid < 128) {
            int idx = r0 + tid;
            int tv = tasks[e * tstr + min(idx, cnt - 1)];
            tokL[tid] = tv & 0xFFFF;
            flgL[tid] = (idx < cnt) ? ((tv >> 17) & 3) : 0;
        }
        __syncthreads();
        size_t asrc_off[4];
        #pragma unroll
        for (int i = 0; i < 4; i++)
            asrc_off[i] = (size_t)tokL[i * 32 + sg] * (D * 2) + sc * 16;

        float ss[2][16] = {}, sd[2][16] = {};

        for (int n0 = ch * 1024; n0 < ch * 1024 + 1024; n0 += 256) {
            f32x16 acc[2][4];
            #pragma unroll
            for (int mi = 0; mi < 2; mi++)
                #pragma unroll
                for (int ni = 0; ni < 4; ni++)
                    acc[mi][ni] = (f32x16)(0.0f);

            const char* bsrc0 = we1t_e + (size_t)n0 * (D * 2) + bs_off;

            for (int k0 = 0; k0 < D; k0 += 64) {
                __syncthreads();
                #pragma unroll
                for (int i = 0; i < 4; i++) {
                    int4 v = *(const int4*)(xh_b + asrc_off[i] + k0 * 2);
                    *(int4*)(smem + i * 4096 + stoff) = v;
                }
                #pragma unroll
                for (int i = 0; i < 8; i++) {
                    int4 v = *(const int4*)(bsrc0 + (size_t)i * 32 * (D * 2) + k0 * 2);
                    *(int4*)(smem + 16384 + i * 4096 + stoff) = v;
                }
                __syncthreads();
                #pragma unroll
                for (int ks = 0; ks < 4; ks++) {
                    f16x8 a0 = *(const f16x8*)(smem + arow[0] + kx[ks]);
                    f16x8 a1 = *(const f16x8*)(smem + arow[1] + kx[ks]);
                    #pragma unroll
                    for (int ni = 0; ni < 4; ni++) {
                        f16x8 bf = *(const f16x8*)(smem + nrow[ni] + kx[ks]);
                        acc[0][ni] = __builtin_amdgcn_mfma_f32_32x32x16_f16(a0, bf, acc[0][ni], 0, 0, 0);
                        acc[1][ni] = __builtin_amdgcn_mfma_f32_32x32x16_f16(a1, bf, acc[1][ni], 0, 0, 0);
                    }
                }
            }
            #pragma unroll
            for (int ni = 0; ni < 4; ni++) {
                int col = n0 + wc * 128 + ni * 32 + l31;
                float b1 = be1[e * DH + col];
                float vs = v_sum[(size_t)e * DH + col];
                float vd = v_diff[(size_t)e * DH + col];
                #pragma unroll
                for (int mi = 0; mi < 2; mi++) {
                    #pragma unroll
                    for (int r = 0; r < 16; r++) {
                        float h = gelu_fast(acc[mi][ni][r] + b1);
                        ss[mi][r] += h * vs;
                        sd[mi][r] += h * vd;
                    }
                }
            }
        }

        #pragma unroll
        for (int m = 16; m >= 1; m >>= 1) {
            #pragma unroll
            for (int mi = 0; mi < 2; mi++)
                #pragma unroll
                for (int r = 0; r < 16; r++) {
                    ss[mi][r] += __shfl_xor(ss[mi][r], m, 64);
                    sd[mi][r] += __shfl_xor(sd[mi][r], m, 64);
                }
        }
        if (l31 == 0) {
            #pragma unroll
            for (int mi = 0; mi < 2; mi++)
                #pragma unroll
                for (int r = 0; r < 16; r++) {
                    int row = wr * 64 + mi * 32 + (r & 3) + 8 * (r >> 2) + 4 * hi;
                    redS[wc][row] = ss[mi][r];
                    redD[wc][row] = sd[mi][r];
                }
        }
        __syncthreads();
        if (tid < 128) {
            int idx = r0 + tid;
            if (idx < cnt) {
                int fl = flgL[tid];
                int tok = tokL[tid];
                float s = redS[0][tid] + redS[1][tid];
                float d = redD[0][tid] + redD[1][tid];
                if (ch == 0) { s += c_sum[e]; d += c_diff[e]; }
                if (fl & 1) ppS[ch * qn + tok] = s;
                if (fl & 2) ppD[ch * qn + tok] = d;
            }
        }
    }
}

// ---------------------------------------------------------------------------
__global__ __launch_bounds__(256) void k_fin(
    const float* __restrict__ ppS, const float* __restrict__ ppD,
    float* __restrict__ out, int tok0, int qn)
{
    int i = blockIdx.x * 256 + threadIdx.x;
    out[tok0 + i]      = ppS[i] + ppS[qn + i];
    out[BT + tok0 + i] = ppD[i] + ppD[qn + i];
}

// ---------------------------------------------------------------------------
extern "C" void kernel_launch(void* const* d_in, const int* in_sizes, int n_in,
                              void* d_out, int out_size, void* d_ws, size_t ws_size,
                              hipStream_t stream)
{
    const float* a      = (const float*)d_in[0];
    const float* b      = (const float*)d_in[1];
    const float* W_in   = (const float*)d_in[2];
    const float* b_in   = (const float*)d_in[3];
    const float* ln_g   = (const float*)d_in[4];
    const float* ln_b   = (const float*)d_in[5];
    const float* Wr1s   = (const float*)d_in[6];
    const float* br1s   = (const float*)d_in[7];
    const float* Wr2s   = (const float*)d_in[8];
    const float* br2s   = (const float*)d_in[9];
    const float* Wr1d   = (const float*)d_in[10];
    const float* br1d   = (const float*)d_in[11];
    const float* Wr2d   = (const float*)d_in[12];
    const float* br2d   = (const float*)d_in[13];
    const float* We1    = (const float*)d_in[14];
    const float* be1    = (const float*)d_in[15];
    const float* We2    = (const float*)d_in[16];
    const float* be2    = (const float*)d_in[17];
    const float* w_sum  = (const float*)d_in[18];
    const float* bs     = (const float*)d_in[19];
    const float* w_diff = (const float*)d_in[20];
    const float* bd     = (const float*)d_in[21];
    float* out = (float*)d_out;

    // pick largest qn whose workspace plan fits
    auto plan = [&](size_t qn) -> size_t {
        size_t o = 0;
        auto al = [&](size_t bytes) { o = (o + bytes + 255) & ~(size_t)255; };
        al((size_t)NT * DH * 4); al((size_t)NT * DH * 4); al(64); al(64);
        al(qn * D * 4); al(qn * D * 2); al(qn * 64 * 4);
        al((size_t)RCAP * 64 * 4); al((size_t)RCAP * 64 * 4);
        al((size_t)RCAP * 4); al((size_t)RCAP * 4); al(qn * 4);
        al((size_t)NT * 2 * qn * 4);
        al(64); al((size_t)(8 * XJCAP + 8) * 4);
        al(2 * qn * 4); al(2 * qn * 4);
        al((size_t)NT * DH * D * 2); al((size_t)2048 * 1024 * 2);
        al(2048 * 4); al(2048 * 8 * 4);
        return o;
    };
    int qn = 65536;
    while (qn > 16384 && plan((size_t)qn) > ws_size) qn >>= 1;
    if (plan((size_t)qn) > ws_size) {
        hipMemsetAsync(d_out, 0, (size_t)out_size * 4, stream);
        return;
    }
    int npass = BT / qn;
    int tstr = 2 * qn;

    char* w = (char*)d_ws;
    size_t off = 0;
    auto alloc = [&](size_t bytes) -> char* {
        char* p = w + off;
        off = (off + bytes + 255) & ~(size_t)255;
        return p;
    };
    float* v_sum   = (float*)alloc((size_t)NT * DH * 4);
    float* v_diff  = (float*)alloc((size_t)NT * DH * 4);
    float* c_sum   = (float*)alloc(64);
    float* c_diff  = (float*)alloc(64);
    float* x       = (float*)alloc((size_t)qn * D * 4);
    f16*   xh      = (f16*)alloc((size_t)qn * D * 2);
    float* part    = (float*)alloc((size_t)qn * 64 * 4);
    float* rlogpS  = (float*)alloc((size_t)RCAP * 64 * 4);
    float* rlogpD  = (float*)alloc((size_t)RCAP * 64 * 4);
    int*   redoS   = (int*)alloc((size_t)RCAP * 4);
    int*   redoD   = (int*)alloc((size_t)RCAP * 4);
    int*   adx     = (int*)alloc((size_t)qn * 4);
    int*   tasks   = (int*)alloc((size_t)NT * 2 * qn * 4);
    int*   ctrl    = (int*)alloc(64);
    int*   xjob    = (int*)alloc((size_t)(8 * XJCAP + 8) * 4);
    float* ppS     = (float*)alloc((size_t)2 * qn * 4);
    float* ppD     = (float*)alloc((size_t)2 * qn * 4);
    f16*   We1T    = (f16*)alloc((size_t)NT * DH * D * 2);
    f16*   Wr1Tf   = (f16*)alloc((size_t)2048 * 1024 * 2);
    float* br1f    = (float*)alloc((size_t)2048 * 4);
    float* w2f     = (float*)alloc((size_t)2048 * 8 * 4);

    k_cvt <<<dim3(4096), dim3(256), 0, stream>>>(We1, We1T);
    k_cvtR<<<dim3(512),  dim3(256), 0, stream>>>(Wr1s, Wr1d, Wr1Tf);
    k_fuse<<<dim3(1),    dim3(256), 0, stream>>>(br1s, br1d, Wr2s, Wr2d, br1f, w2f);
    k_prev<<<dim3(4097), dim3(256), 0, stream>>>(We2, w_sum, w_diff, be2, bs, bd,
                                                 v_sum, v_diff, c_sum, c_diff);
    for (int q = 0; q < npass; q++) {
        int tok0 = q * qn;
        k_enc<<<dim3(qn / 64), dim3(256), 0, stream>>>(a, b, W_in, b_in, ln_g, ln_b, x, xh, tok0);
        k_rtrm<<<dim3(qn / 64 * 8), dim3(256), 0, stream>>>(xh, Wr1Tf, br1f, w2f, part);
        hipMemsetAsync(ctrl, 0, 64, stream);
        k_amx2<<<dim3(qn / 256), dim3(256), 0, stream>>>(part, br2s, br2d, tasks, ctrl,
                                                         redoS, redoD, tstr);
        k_redo<<<dim3(32, 8, 2), dim3(256), 0, stream>>>(x, Wr1s, br1s, Wr2s, Wr1d, br1d, Wr2d,
                                                         redoS, redoD, ctrl, rlogpS, rlogpD);
        k_amx3d<<<dim3(16), dim3(256), 0, stream>>>(rlogpD, redoD, br2d, tasks, ctrl, adx, tstr);
        k_amx3s<<<dim3(16), dim3(256), 0, stream>>>(rlogpS, redoS, br2s, tasks, ctrl, adx, tstr);
        k_sched<<<dim3(1), dim3(256), 0, stream>>>(ctrl, xjob);
        k_expm<<<dim3(2048), dim3(256), 0, stream>>>(xh, We1T, be1, v_sum, v_diff,
                                                     c_sum, c_diff, tasks, ctrl, xjob,
                                                     ppS, ppD, qn);
        k_fin<<<dim3(qn / 256), dim3(256), 0, stream>>>(ppS, ppD, out, tok0, qn);
    }
}